// Round 1
// baseline (1417.247 us; speedup 1.0000x reference)
//
#include <hip/hip_runtime.h>
#include <hip/hip_bf16.h>

namespace {

constexpr int D    = 256;
constexpr int H    = 8;
constexpr int DH   = 32;
constexpr int L    = 4;
constexpr int P    = 4;
constexpr int B    = 32;
constexpr int LQ   = 300;
constexpr int NQ   = B * LQ;      // 9600
constexpr int S    = 3840;
constexpr int MS   = B * S;       // 122880
constexpr int DFFN = 1024;

// ---------------------------------------------------------------------------
// Generic tiled fp32 GEMM: C[M,N] = A[M,K] @ W[K,N] + bias  (optional relu,
// optional bf16 output). All M,N multiples of 64; K multiple of 16.
// ---------------------------------------------------------------------------
template<bool OUT_BF16, bool RELU>
__global__ __launch_bounds__(256) void gemm_f32(
    const float* __restrict__ A, const float* __restrict__ W,
    const float* __restrict__ bias, void* __restrict__ Cv,
    int M, int K, int N)
{
  __shared__ float As[16][65];   // +1 pad breaks store conflicts
  __shared__ float Ws[16][64];
  const int tid = threadIdx.x;
  const int tx = tid & 15, ty = tid >> 4;
  const int m0 = blockIdx.y * 64, n0 = blockIdx.x * 64;
  float acc[4][4] = {};
  for (int k0 = 0; k0 < K; k0 += 16) {
#pragma unroll
    for (int i = 0; i < 4; ++i) {
      int e = tid + 256 * i;
      int r = e >> 4, kk = e & 15;
      As[kk][r] = A[(size_t)(m0 + r) * K + (k0 + kk)];
    }
#pragma unroll
    for (int i = 0; i < 4; ++i) {
      int e = tid + 256 * i;
      int kk = e >> 6, c = e & 63;
      Ws[kk][c] = W[(size_t)(k0 + kk) * N + (n0 + c)];
    }
    __syncthreads();
#pragma unroll
    for (int kk = 0; kk < 16; ++kk) {
      const float a0 = As[kk][ty * 4 + 0];
      const float a1 = As[kk][ty * 4 + 1];
      const float a2 = As[kk][ty * 4 + 2];
      const float a3 = As[kk][ty * 4 + 3];
      const float4 w = *reinterpret_cast<const float4*>(&Ws[kk][tx * 4]);
      acc[0][0] += a0 * w.x; acc[0][1] += a0 * w.y; acc[0][2] += a0 * w.z; acc[0][3] += a0 * w.w;
      acc[1][0] += a1 * w.x; acc[1][1] += a1 * w.y; acc[1][2] += a1 * w.z; acc[1][3] += a1 * w.w;
      acc[2][0] += a2 * w.x; acc[2][1] += a2 * w.y; acc[2][2] += a2 * w.z; acc[2][3] += a2 * w.w;
      acc[3][0] += a3 * w.x; acc[3][1] += a3 * w.y; acc[3][2] += a3 * w.z; acc[3][3] += a3 * w.w;
    }
    __syncthreads();
  }
#pragma unroll
  for (int i = 0; i < 4; ++i) {
    const int row = m0 + ty * 4 + i;
    const int col = n0 + tx * 4;
    float4 v;
    float* vv = &v.x;
#pragma unroll
    for (int j = 0; j < 4; ++j) {
      float x = acc[i][j] + bias[col + j];
      if (RELU) x = fmaxf(x, 0.f);
      vv[j] = x;
    }
    if constexpr (OUT_BF16) {
      __hip_bfloat16* Cb = (__hip_bfloat16*)Cv;
      const size_t base = (size_t)row * N + col;
      Cb[base + 0] = __float2bfloat16(v.x);
      Cb[base + 1] = __float2bfloat16(v.y);
      Cb[base + 2] = __float2bfloat16(v.z);
      Cb[base + 3] = __float2bfloat16(v.w);
    } else {
      float* Cf = (float*)Cv;
      *reinterpret_cast<float4*>(&Cf[(size_t)row * N + col]) = v;
    }
  }
}

// ---------------------------------------------------------------------------
// Self-attention: one block per (b,h). K,V head-slices staged in LDS; one
// thread per query row does online softmax over 300 keys.
// qh/kh/vh layout: (B*LQ, 256) with col = h*32 + d.
// ---------------------------------------------------------------------------
__global__ __launch_bounds__(320) void mha_kernel(
    const float* __restrict__ qh, const float* __restrict__ kh,
    const float* __restrict__ vh, float* __restrict__ out)
{
  __shared__ float Ks[LQ][DH];   // 37.5 KB
  __shared__ float Vs[LQ][DH];   // 37.5 KB
  const int b = blockIdx.x >> 3, h = blockIdx.x & 7;
  const float* kbase = kh + (size_t)b * LQ * D + h * DH;
  const float* vbase = vh + (size_t)b * LQ * D + h * DH;
  for (int e = threadIdx.x; e < LQ * DH; e += 320) {
    const int r = e >> 5, d = e & 31;
    Ks[r][d] = kbase[(size_t)r * D + d];
    Vs[r][d] = vbase[(size_t)r * D + d];
  }
  __syncthreads();
  const int t = threadIdx.x;
  if (t < LQ) {
    const float* qrow = qh + (size_t)(b * LQ + t) * D + h * DH;
    float q[DH];
#pragma unroll
    for (int d = 0; d < DH; ++d) q[d] = qrow[d] * 0.17677669529663689f;  // 1/sqrt(32)
    float m = -1e30f, ssum = 0.f;
    float o[DH] = {};
    for (int k = 0; k < LQ; ++k) {
      float s = 0.f;
#pragma unroll
      for (int d = 0; d < DH; ++d) s += q[d] * Ks[k][d];
      if (s > m) {
        const float corr = __expf(m - s);
        ssum *= corr;
#pragma unroll
        for (int d = 0; d < DH; ++d) o[d] *= corr;
        m = s;
      }
      const float p = __expf(s - m);
      ssum += p;
#pragma unroll
      for (int d = 0; d < DH; ++d) o[d] += p * Vs[k][d];
    }
    const float inv = 1.f / ssum;
    float* orow = out + (size_t)(b * LQ + t) * D + h * DH;
#pragma unroll
    for (int d = 0; d < DH; ++d) orow[d] = o[d] * inv;
  }
}

// ---------------------------------------------------------------------------
// Deformable sampling. 32 lanes = one (b,q,h); 8 units per block.
// offb/attb layout: (NQ, 128) col = h*16 + l*4 + p.
// value layout: (B*S, 256) bf16, col = h*32 + d.
// ---------------------------------------------------------------------------
template<bool BOUNDARY>
__global__ __launch_bounds__(256) void deform_sample(
    const float* __restrict__ offb, const float* __restrict__ attb,
    const float* __restrict__ ref, const __hip_bfloat16* __restrict__ value,
    float* __restrict__ out)
{
  const int u = blockIdx.x * 8 + (threadIdx.x >> 5);
  const int d = threadIdx.x & 31;
  const int h = u & 7;
  const int bq = u >> 3;                 // b*LQ + q
  const int b = bq / LQ;
  const float* offp = offb + (size_t)bq * 128 + h * 16;
  const float* attp = attb + (size_t)bq * 128 + h * 16;

  float att[16];
  float amax = -1e30f;
#pragma unroll
  for (int i = 0; i < 16; ++i) { att[i] = attp[i]; amax = fmaxf(amax, att[i]); }
  float asum = 0.f;
#pragma unroll
  for (int i = 0; i < 16; ++i) { att[i] = __expf(att[i] - amax); asum += att[i]; }
  const float ainv = 1.f / asum;

  const float* refp = ref + (size_t)bq * L * 2;
  const int lens[4]   = {2048, 1024, 512, 256};
  const int starts[4] = {0, 2048, 3072, 3584};
  float o = 0.f;
#pragma unroll
  for (int l = 0; l < L; ++l) {
    const float center = refp[l * 2 + 0];
    const float width  = refp[l * 2 + 1];
    const int T = lens[l], s0 = starts[l];
    const __hip_bfloat16* vb = value + (size_t)(b * S + s0) * D + h * DH + d;
#pragma unroll
    for (int p = 0; p < P; ++p) {
      float anchor = center;
      if (BOUNDARY) anchor += (p < P / 2 ? -0.5f : 0.5f) * width;
      const float loc = anchor + offp[l * 4 + p] * width * 0.125f;  // off/P*width*0.5
      const float x = loc * (float)T - 0.5f;
      const float x0 = floorf(x);
      const float w = x - x0;
      const int i0 = (int)x0;
      const int i1 = i0 + 1;
      float g0 = 0.f, g1 = 0.f;
      if (i0 >= 0 && i0 < T) g0 = __bfloat162float(vb[(size_t)i0 * D]);
      if (i1 >= 0 && i1 < T) g1 = __bfloat162float(vb[(size_t)i1 * D]);
      o += att[l * 4 + p] * ainv * (g0 * (1.f - w) + g1 * w);
    }
  }
  out[(size_t)bq * D + h * DH + d] = o;
}

// ---------------------------------------------------------------------------
// out = LN(x + res) * g + b ; one wave per 256-wide row. out may alias res.
// ---------------------------------------------------------------------------
__global__ __launch_bounds__(256) void add_ln(
    const float* __restrict__ x, const float* __restrict__ res,
    const float* __restrict__ g, const float* __restrict__ bb,
    float* __restrict__ out)
{
  const int row = blockIdx.x * 4 + (threadIdx.x >> 6);
  const int lane = threadIdx.x & 63;
  const float* xr = x + (size_t)row * D;
  const float* rr = res + (size_t)row * D;
  float v[4];
  float s = 0.f;
#pragma unroll
  for (int i = 0; i < 4; ++i) { v[i] = xr[lane + 64 * i] + rr[lane + 64 * i]; s += v[i]; }
#pragma unroll
  for (int off = 32; off > 0; off >>= 1) s += __shfl_xor(s, off, 64);
  const float mean = s * (1.f / D);
  float vs = 0.f;
#pragma unroll
  for (int i = 0; i < 4; ++i) { const float dd = v[i] - mean; vs += dd * dd; }
#pragma unroll
  for (int off = 32; off > 0; off >>= 1) vs += __shfl_xor(vs, off, 64);
  const float rstd = rsqrtf(vs * (1.f / D) + 1e-5f);
  float* orow = out + (size_t)row * D;
#pragma unroll
  for (int i = 0; i < 4; ++i)
    orow[lane + 64 * i] = (v[i] - mean) * rstd * g[lane + 64 * i] + bb[lane + 64 * i];
}

__global__ __launch_bounds__(256) void add_vec(
    const float* __restrict__ a, const float* __restrict__ b,
    float* __restrict__ c, int n4)
{
  const int i = blockIdx.x * 256 + threadIdx.x;
  if (i < n4) {
    const float4 va = reinterpret_cast<const float4*>(a)[i];
    const float4 vb = reinterpret_cast<const float4*>(b)[i];
    float4 vc;
    vc.x = va.x + vb.x; vc.y = va.y + vb.y; vc.z = va.z + vb.z; vc.w = va.w + vb.w;
    reinterpret_cast<float4*>(c)[i] = vc;
  }
}

}  // namespace

extern "C" void kernel_launch(void* const* d_in, const int* in_sizes, int n_in,
                              void* d_out, int out_size, void* d_ws, size_t ws_size,
                              hipStream_t stream)
{
  const float* tgt   = (const float*)d_in[0];
  const float* qpos  = (const float*)d_in[1];
  const float* ref   = (const float*)d_in[2];
  const float* src   = (const float*)d_in[3];
  // d_in[4]=temporal_lengths (int64), d_in[5]=level_start_index (int64): hardcoded
  const float* sa_qw = (const float*)d_in[6];
  const float* sa_kw = (const float*)d_in[7];
  const float* sa_vw = (const float*)d_in[8];
  const float* sa_ow = (const float*)d_in[9];
  const float* ff1_w = (const float*)d_in[10];
  const float* ff2_w = (const float*)d_in[11];
  const float* sa_qb = (const float*)d_in[12];
  const float* sa_kb = (const float*)d_in[13];
  const float* sa_vb = (const float*)d_in[14];
  const float* sa_ob = (const float*)d_in[15];
  const float* ff1_b = (const float*)d_in[16];
  const float* ff2_b = (const float*)d_in[17];
  const float* ca_off_w  = (const float*)d_in[18];
  const float* ca_off_b  = (const float*)d_in[19];
  const float* ca_attn_w = (const float*)d_in[20];
  const float* ca_attn_b = (const float*)d_in[21];
  const float* ca_val_w  = (const float*)d_in[22];
  const float* ca_val_b  = (const float*)d_in[23];
  const float* ca_out_w  = (const float*)d_in[24];
  const float* ca_out_b  = (const float*)d_in[25];
  const float* se_off_w  = (const float*)d_in[26];
  const float* se_off_b  = (const float*)d_in[27];
  const float* se_attn_w = (const float*)d_in[28];
  const float* se_attn_b = (const float*)d_in[29];
  const float* se_val_w  = (const float*)d_in[30];
  const float* se_val_b  = (const float*)d_in[31];
  const float* se_out_w  = (const float*)d_in[32];
  const float* se_out_b  = (const float*)d_in[33];
  const float* ln1_g  = (const float*)d_in[34];
  const float* ln1_b  = (const float*)d_in[35];
  const float* lnse_g = (const float*)d_in[36];
  const float* lnse_b = (const float*)d_in[37];
  const float* ln2_g  = (const float*)d_in[38];
  const float* ln2_b  = (const float*)d_in[39];
  const float* ln3_g  = (const float*)d_in[40];
  const float* ln3_b  = (const float*)d_in[41];

  const size_t ND = (size_t)NQ * D;  // 2457600 floats
  float* ws   = (float*)d_ws;
  float* qbuf = ws + 0 * ND;
  float* qh   = ws + 1 * ND;
  float* kh   = ws + 2 * ND;
  float* vh   = ws + 3 * ND;
  float* t2   = ws + 4 * ND;
  float* cur  = ws + 5 * ND;
  float* smp  = ws + 6 * ND;
  __hip_bfloat16* V = (__hip_bfloat16*)(ws + 7 * ND);            // MS*D bf16
  float* ffh  = ws + 7 * ND + (size_t)MS * D / 2;                // NQ*DFFN
  float* offb = ffh + (size_t)NQ * DFFN;                         // NQ*128
  float* attb = offb + (size_t)NQ * 128;                         // NQ*128

  const int n4 = (int)(ND / 4);            // 614400 = 2400*256
  const dim3 g64x64(4, NQ / 64);           // 9600x256-ish GEMMs

  // ---- self-attention ----
  add_vec<<<2400, 256, 0, stream>>>(tgt, qpos, qbuf, n4);
  gemm_f32<false, false><<<g64x64, 256, 0, stream>>>(qbuf, sa_qw, sa_qb, qh, NQ, D, D);
  gemm_f32<false, false><<<g64x64, 256, 0, stream>>>(qbuf, sa_kw, sa_kb, kh, NQ, D, D);
  gemm_f32<false, false><<<g64x64, 256, 0, stream>>>(tgt,  sa_vw, sa_vb, vh, NQ, D, D);
  mha_kernel<<<B * H, 320, 0, stream>>>(qh, kh, vh, smp);
  gemm_f32<false, false><<<g64x64, 256, 0, stream>>>(smp, sa_ow, sa_ob, t2, NQ, D, D);
  add_ln<<<NQ / 4, 256, 0, stream>>>(t2, tgt, ln2_g, ln2_b, cur);

  // ---- deformable cross-attn (ca, boundary=False) ----
  add_vec<<<2400, 256, 0, stream>>>(cur, qpos, qbuf, n4);
  gemm_f32<true, false><<<dim3(4, MS / 64), 256, 0, stream>>>(src, ca_val_w, ca_val_b, V, MS, D, D);
  gemm_f32<false, false><<<dim3(2, NQ / 64), 256, 0, stream>>>(qbuf, ca_off_w,  ca_off_b,  offb, NQ, D, 128);
  gemm_f32<false, false><<<dim3(2, NQ / 64), 256, 0, stream>>>(qbuf, ca_attn_w, ca_attn_b, attb, NQ, D, 128);
  deform_sample<false><<<NQ, 256, 0, stream>>>(offb, attb, ref, V, smp);
  gemm_f32<false, false><<<g64x64, 256, 0, stream>>>(smp, ca_out_w, ca_out_b, t2, NQ, D, D);
  add_ln<<<NQ / 4, 256, 0, stream>>>(t2, cur, ln1_g, ln1_b, cur);

  // ---- deformable cross-attn (se, boundary=True) ----
  add_vec<<<2400, 256, 0, stream>>>(cur, qpos, qbuf, n4);
  gemm_f32<true, false><<<dim3(4, MS / 64), 256, 0, stream>>>(src, se_val_w, se_val_b, V, MS, D, D);
  gemm_f32<false, false><<<dim3(2, NQ / 64), 256, 0, stream>>>(qbuf, se_off_w,  se_off_b,  offb, NQ, D, 128);
  gemm_f32<false, false><<<dim3(2, NQ / 64), 256, 0, stream>>>(qbuf, se_attn_w, se_attn_b, attb, NQ, D, 128);
  deform_sample<true><<<NQ, 256, 0, stream>>>(offb, attb, ref, V, smp);
  gemm_f32<false, false><<<g64x64, 256, 0, stream>>>(smp, se_out_w, se_out_b, t2, NQ, D, D);
  add_ln<<<NQ / 4, 256, 0, stream>>>(t2, cur, lnse_g, lnse_b, cur);

  // ---- FFN ----
  gemm_f32<false, true><<<dim3(DFFN / 64, NQ / 64), 256, 0, stream>>>(cur, ff1_w, ff1_b, ffh, NQ, D, DFFN);
  gemm_f32<false, false><<<g64x64, 256, 0, stream>>>(ffh, ff2_w, ff2_b, t2, NQ, DFFN, D);
  add_ln<<<NQ / 4, 256, 0, stream>>>(t2, cur, ln3_g, ln3_b, (float*)d_out);
}

// Round 2
// 846.422 us; speedup vs baseline: 1.6744x; 1.6744x over previous
//
#include <hip/hip_runtime.h>
#include <hip/hip_bf16.h>

namespace {

typedef unsigned short u16;
typedef unsigned int u32;

constexpr int D    = 256;
constexpr int H    = 8;
constexpr int DH   = 32;
constexpr int L    = 4;
constexpr int P    = 4;
constexpr int B    = 32;
constexpr int LQ   = 300;
constexpr int NQ   = B * LQ;      // 9600
constexpr int S    = 3840;
constexpr int MS   = B * S;       // 122880
constexpr int DFFN = 1024;

typedef __attribute__((ext_vector_type(8))) short bf16x8;
typedef __attribute__((ext_vector_type(4))) float f32x4;

__device__ inline u16 f2b(float x) {
  u32 u = __builtin_bit_cast(u32, x);
  u32 r = (u + 0x7FFFu + ((u >> 16) & 1u)) >> 16;
  return (u16)r;
}
__device__ inline float b2f(u16 v) {
  return __builtin_bit_cast(float, (u32)v << 16);
}
__device__ inline void unpack2(u32 w, float& a, float& b) {
  a = __builtin_bit_cast(float, w << 16);
  b = __builtin_bit_cast(float, w & 0xffff0000u);
}

// ---------------------------------------------------------------------------
// bf16 MFMA GEMM: C[M,N] = A[M,K] @ Bt[N,K]^T + bias. 128x128 tile, BK=64,
// 256 threads = 4 waves (2x2), 16x16x32 MFMA, reg-staged LDS (stride 72).
// M,N multiples of 128; K multiple of 64.
// ---------------------------------------------------------------------------
template<bool OUT_BF16, bool RELU>
__global__ __launch_bounds__(256) void gemm_bf16(
    const u16* __restrict__ A, const u16* __restrict__ Bt,
    const float* __restrict__ bias, void* __restrict__ Cv,
    int M, int K, int N)
{
  constexpr int BM = 128, BN = 128, BK = 64, LDK = 72;
  __shared__ __align__(16) u16 As[BM * LDK];
  __shared__ __align__(16) u16 Bs[BN * LDK];
  const int tid  = threadIdx.x;
  const int lane = tid & 63;
  const int wid  = tid >> 6;
  const int wm = wid >> 1, wn = wid & 1;
  const int m0 = blockIdx.y * BM, n0 = blockIdx.x * BN;

  f32x4 acc[4][4] = {};

  uint4 ra[4], rb[4];
  const int NT = K / BK;

#pragma unroll
  for (int i = 0; i < 4; ++i) {
    const int g = tid + 256 * i;
    const int row = g >> 3, ch = g & 7;
    ra[i] = *(const uint4*)(A  + (size_t)(m0 + row) * K + ch * 8);
    rb[i] = *(const uint4*)(Bt + (size_t)(n0 + row) * K + ch * 8);
  }

  for (int t = 0; t < NT; ++t) {
#pragma unroll
    for (int i = 0; i < 4; ++i) {
      const int g = tid + 256 * i;
      const int row = g >> 3, ch = g & 7;
      *(uint4*)(&As[row * LDK + ch * 8]) = ra[i];
      *(uint4*)(&Bs[row * LDK + ch * 8]) = rb[i];
    }
    __syncthreads();
    if (t + 1 < NT) {
      const int k0 = (t + 1) * BK;
#pragma unroll
      for (int i = 0; i < 4; ++i) {
        const int g = tid + 256 * i;
        const int row = g >> 3, ch = g & 7;
        ra[i] = *(const uint4*)(A  + (size_t)(m0 + row) * K + k0 + ch * 8);
        rb[i] = *(const uint4*)(Bt + (size_t)(n0 + row) * K + k0 + ch * 8);
      }
    }
#pragma unroll
    for (int kk = 0; kk < 2; ++kk) {
      bf16x8 af[4], bfr[4];
      const int krd = kk * 32 + (lane >> 4) * 8;
      const int ra0 = (wm * 64 + (lane & 15)) * LDK + krd;
      const int rb0 = (wn * 64 + (lane & 15)) * LDK + krd;
#pragma unroll
      for (int m = 0; m < 4; ++m) af[m]  = *(const bf16x8*)(&As[ra0 + m * 16 * LDK]);
#pragma unroll
      for (int n = 0; n < 4; ++n) bfr[n] = *(const bf16x8*)(&Bs[rb0 + n * 16 * LDK]);
#pragma unroll
      for (int m = 0; m < 4; ++m)
#pragma unroll
        for (int n = 0; n < 4; ++n)
          acc[m][n] = __builtin_amdgcn_mfma_f32_16x16x32_bf16(af[m], bfr[n], acc[m][n], 0, 0, 0);
    }
    __syncthreads();
  }

  const int cr = (lane >> 4) * 4;
  const int cc = lane & 15;
#pragma unroll
  for (int n = 0; n < 4; ++n) {
    const int gc = n0 + wn * 64 + n * 16 + cc;
    const float bv = bias[gc];
#pragma unroll
    for (int m = 0; m < 4; ++m) {
      const int gr0 = m0 + wm * 64 + m * 16 + cr;
#pragma unroll
      for (int r = 0; r < 4; ++r) {
        float x = acc[m][n][r] + bv;
        if (RELU) x = fmaxf(x, 0.f);
        if (OUT_BF16) ((u16*)Cv)[(size_t)(gr0 + r) * N + gc] = f2b(x);
        else          ((float*)Cv)[(size_t)(gr0 + r) * N + gc] = x;
      }
    }
  }
}

// ---------------------------------------------------------------------------
// Batched weight transpose+convert: W(K,N) f32 -> Wt(N,K) bf16, 32x32 tiles.
// ---------------------------------------------------------------------------
struct WSpec { const float* w; u16* wt; int K, N, blk0; };
struct WPack { WSpec s[14]; };

__global__ __launch_bounds__(256) void wt_transpose(WPack p) {
  __shared__ float tile[32][33];
  const int b = blockIdx.x;
  int i = 0;
#pragma unroll
  for (int j = 1; j < 14; ++j) if (b >= p.s[j].blk0) i = j;
  const float* w = p.s[i].w;
  u16* wt = p.s[i].wt;
  const int K = p.s[i].K, N = p.s[i].N;
  const int lb = b - p.s[i].blk0;
  const int ntN = N >> 5;
  const int tk = lb / ntN, tn = lb - tk * ntN;
  const int r = threadIdx.x >> 5, c = threadIdx.x & 31;
#pragma unroll
  for (int j = 0; j < 4; ++j)
    tile[r + j * 8][c] = w[(size_t)(tk * 32 + r + j * 8) * N + tn * 32 + c];
  __syncthreads();
#pragma unroll
  for (int j = 0; j < 4; ++j)
    wt[(size_t)(tn * 32 + r + j * 8) * K + tk * 32 + c] = f2b(tile[c][r + j * 8]);
}

__global__ __launch_bounds__(256) void cvt_bf16(
    const float* __restrict__ x, u16* __restrict__ y, int n4)
{
  int i = blockIdx.x * 256 + threadIdx.x;
  const int stride = gridDim.x * 256;
  for (; i < n4; i += stride) {
    const float4 v = ((const float4*)x)[i];
    uint2 pk;
    pk.x = (u32)f2b(v.x) | ((u32)f2b(v.y) << 16);
    pk.y = (u32)f2b(v.z) | ((u32)f2b(v.w) << 16);
    ((uint2*)y)[i] = pk;
  }
}

__global__ __launch_bounds__(256) void add_vec_bf16(
    const float* __restrict__ a, const float* __restrict__ b,
    u16* __restrict__ c, int n4)
{
  const int i = blockIdx.x * 256 + threadIdx.x;
  if (i < n4) {
    const float4 va = ((const float4*)a)[i];
    const float4 vb = ((const float4*)b)[i];
    uint2 pk;
    pk.x = (u32)f2b(va.x + vb.x) | ((u32)f2b(va.y + vb.y) << 16);
    pk.y = (u32)f2b(va.z + vb.z) | ((u32)f2b(va.w + vb.w) << 16);
    ((uint2*)c)[i] = pk;
  }
}

// ---------------------------------------------------------------------------
// Self-attention. bf16 in, bf16 out. K,V staged in LDS as f32.
// ---------------------------------------------------------------------------
__global__ __launch_bounds__(320) void mha_kernel(
    const u16* __restrict__ qh, const u16* __restrict__ kh,
    const u16* __restrict__ vh, u16* __restrict__ out)
{
  __shared__ float Ks[LQ][DH];
  __shared__ float Vs[LQ][DH];
  const int b = blockIdx.x >> 3, h = blockIdx.x & 7;
  const u16* kbase = kh + (size_t)b * LQ * D + h * DH;
  const u16* vbase = vh + (size_t)b * LQ * D + h * DH;
  for (int e = threadIdx.x; e < LQ * 4; e += 320) {
    const int r = e >> 2, c = (e & 3) * 8;
    const uint4 kv = *(const uint4*)(kbase + (size_t)r * D + c);
    unpack2(kv.x, Ks[r][c + 0], Ks[r][c + 1]);
    unpack2(kv.y, Ks[r][c + 2], Ks[r][c + 3]);
    unpack2(kv.z, Ks[r][c + 4], Ks[r][c + 5]);
    unpack2(kv.w, Ks[r][c + 6], Ks[r][c + 7]);
    const uint4 vv = *(const uint4*)(vbase + (size_t)r * D + c);
    unpack2(vv.x, Vs[r][c + 0], Vs[r][c + 1]);
    unpack2(vv.y, Vs[r][c + 2], Vs[r][c + 3]);
    unpack2(vv.z, Vs[r][c + 4], Vs[r][c + 5]);
    unpack2(vv.w, Vs[r][c + 6], Vs[r][c + 7]);
  }
  __syncthreads();
  const int t = threadIdx.x;
  if (t < LQ) {
    const u16* qrow = qh + (size_t)(b * LQ + t) * D + h * DH;
    float q[DH];
#pragma unroll
    for (int c4 = 0; c4 < 4; ++c4) {
      const uint4 u = *(const uint4*)(qrow + c4 * 8);
      unpack2(u.x, q[c4 * 8 + 0], q[c4 * 8 + 1]);
      unpack2(u.y, q[c4 * 8 + 2], q[c4 * 8 + 3]);
      unpack2(u.z, q[c4 * 8 + 4], q[c4 * 8 + 5]);
      unpack2(u.w, q[c4 * 8 + 6], q[c4 * 8 + 7]);
    }
#pragma unroll
    for (int d = 0; d < DH; ++d) q[d] *= 0.17677669529663689f;  // 1/sqrt(32)
    float m = -1e30f, ssum = 0.f;
    float o[DH] = {};
    for (int k = 0; k < LQ; ++k) {
      float s = 0.f;
#pragma unroll
      for (int d = 0; d < DH; ++d) s += q[d] * Ks[k][d];
      if (s > m) {
        const float corr = __expf(m - s);
        ssum *= corr;
#pragma unroll
        for (int d = 0; d < DH; ++d) o[d] *= corr;
        m = s;
      }
      const float p = __expf(s - m);
      ssum += p;
#pragma unroll
      for (int d = 0; d < DH; ++d) o[d] += p * Vs[k][d];
    }
    const float inv = 1.f / ssum;
    u16* orow = out + (size_t)(b * LQ + t) * D + h * DH;
#pragma unroll
    for (int d = 0; d < DH; ++d) orow[d] = f2b(o[d] * inv);
  }
}

// ---------------------------------------------------------------------------
// Deformable sampling. 32 lanes = one (b,q,h); 8 units per block.
// ---------------------------------------------------------------------------
template<bool BOUNDARY>
__global__ __launch_bounds__(256) void deform_sample(
    const float* __restrict__ offb, const float* __restrict__ attb,
    const float* __restrict__ ref, const u16* __restrict__ value,
    u16* __restrict__ out)
{
  const int u = blockIdx.x * 8 + (threadIdx.x >> 5);
  const int d = threadIdx.x & 31;
  const int h = u & 7;
  const int bq = u >> 3;
  const int b = bq / LQ;
  const float* offp = offb + (size_t)bq * 128 + h * 16;
  const float* attp = attb + (size_t)bq * 128 + h * 16;

  float att[16];
  float amax = -1e30f;
#pragma unroll
  for (int i = 0; i < 16; ++i) { att[i] = attp[i]; amax = fmaxf(amax, att[i]); }
  float asum = 0.f;
#pragma unroll
  for (int i = 0; i < 16; ++i) { att[i] = __expf(att[i] - amax); asum += att[i]; }
  const float ainv = 1.f / asum;

  const float* refp = ref + (size_t)bq * L * 2;
  const int lens[4]   = {2048, 1024, 512, 256};
  const int starts[4] = {0, 2048, 3072, 3584};
  float o = 0.f;
#pragma unroll
  for (int l = 0; l < L; ++l) {
    const float center = refp[l * 2 + 0];
    const float width  = refp[l * 2 + 1];
    const int T = lens[l], s0 = starts[l];
    const u16* vb = value + (size_t)(b * S + s0) * D + h * DH + d;
#pragma unroll
    for (int p = 0; p < P; ++p) {
      float anchor = center;
      if (BOUNDARY) anchor += (p < P / 2 ? -0.5f : 0.5f) * width;
      const float loc = anchor + offp[l * 4 + p] * width * 0.125f;
      const float x = loc * (float)T - 0.5f;
      const float x0 = floorf(x);
      const float w = x - x0;
      const int i0 = (int)x0;
      const int i1 = i0 + 1;
      float g0 = 0.f, g1 = 0.f;
      if (i0 >= 0 && i0 < T) g0 = b2f(vb[(size_t)i0 * D]);
      if (i1 >= 0 && i1 < T) g1 = b2f(vb[(size_t)i1 * D]);
      o += att[l * 4 + p] * ainv * (g0 * (1.f - w) + g1 * w);
    }
  }
  out[(size_t)bq * D + h * DH + d] = f2b(o);
}

// ---------------------------------------------------------------------------
// out = LN(x + res); optionally also emit bf16 copy.
// ---------------------------------------------------------------------------
template<bool WRITE_BF>
__global__ __launch_bounds__(256) void add_ln(
    const float* __restrict__ x, const float* __restrict__ res,
    const float* __restrict__ g, const float* __restrict__ bb,
    float* __restrict__ out, u16* __restrict__ outb)
{
  const int row = blockIdx.x * 4 + (threadIdx.x >> 6);
  const int lane = threadIdx.x & 63;
  const float* xr = x + (size_t)row * D;
  const float* rr = res + (size_t)row * D;
  float v[4];
  float s = 0.f;
#pragma unroll
  for (int i = 0; i < 4; ++i) { v[i] = xr[lane + 64 * i] + rr[lane + 64 * i]; s += v[i]; }
#pragma unroll
  for (int off = 32; off > 0; off >>= 1) s += __shfl_xor(s, off, 64);
  const float mean = s * (1.f / D);
  float vs = 0.f;
#pragma unroll
  for (int i = 0; i < 4; ++i) { const float dd = v[i] - mean; vs += dd * dd; }
#pragma unroll
  for (int off = 32; off > 0; off >>= 1) vs += __shfl_xor(vs, off, 64);
  const float rstd = rsqrtf(vs * (1.f / D) + 1e-5f);
  float* orow = out + (size_t)row * D;
#pragma unroll
  for (int i = 0; i < 4; ++i) {
    const float y = (v[i] - mean) * rstd * g[lane + 64 * i] + bb[lane + 64 * i];
    orow[lane + 64 * i] = y;
    if (WRITE_BF) outb[(size_t)row * D + lane + 64 * i] = f2b(y);
  }
}

}  // namespace

extern "C" void kernel_launch(void* const* d_in, const int* in_sizes, int n_in,
                              void* d_out, int out_size, void* d_ws, size_t ws_size,
                              hipStream_t stream)
{
  const float* tgt   = (const float*)d_in[0];
  const float* qpos  = (const float*)d_in[1];
  const float* ref   = (const float*)d_in[2];
  const float* src   = (const float*)d_in[3];
  const float* sa_qw = (const float*)d_in[6];
  const float* sa_kw = (const float*)d_in[7];
  const float* sa_vw = (const float*)d_in[8];
  const float* sa_ow = (const float*)d_in[9];
  const float* ff1_w = (const float*)d_in[10];
  const float* ff2_w = (const float*)d_in[11];
  const float* sa_qb = (const float*)d_in[12];
  const float* sa_kb = (const float*)d_in[13];
  const float* sa_vb = (const float*)d_in[14];
  const float* sa_ob = (const float*)d_in[15];
  const float* ff1_b = (const float*)d_in[16];
  const float* ff2_b = (const float*)d_in[17];
  const float* ca_off_w  = (const float*)d_in[18];
  const float* ca_off_b  = (const float*)d_in[19];
  const float* ca_attn_w = (const float*)d_in[20];
  const float* ca_attn_b = (const float*)d_in[21];
  const float* ca_val_w  = (const float*)d_in[22];
  const float* ca_val_b  = (const float*)d_in[23];
  const float* ca_out_w  = (const float*)d_in[24];
  const float* ca_out_b  = (const float*)d_in[25];
  const float* se_off_w  = (const float*)d_in[26];
  const float* se_off_b  = (const float*)d_in[27];
  const float* se_attn_w = (const float*)d_in[28];
  const float* se_attn_b = (const float*)d_in[29];
  const float* se_val_w  = (const float*)d_in[30];
  const float* se_val_b  = (const float*)d_in[31];
  const float* se_out_w  = (const float*)d_in[32];
  const float* se_out_b  = (const float*)d_in[33];
  const float* ln1_g  = (const float*)d_in[34];
  const float* ln1_b  = (const float*)d_in[35];
  const float* lnse_g = (const float*)d_in[36];
  const float* lnse_b = (const float*)d_in[37];
  const float* ln2_g  = (const float*)d_in[38];
  const float* ln2_b  = (const float*)d_in[39];
  const float* ln3_g  = (const float*)d_in[40];
  const float* ln3_b  = (const float*)d_in[41];

  const size_t ND = (size_t)NQ * D;       // 2,457,600
  const size_t MD = (size_t)MS * D;       // 31,457,280

  char* base = (char*)d_ws;
  size_t off = 0;
  auto alloc = [&](size_t bytes) -> void* {
    void* p = base + off;
    off += (bytes + 255) & ~(size_t)255;
    return p;
  };
  u16*  srcb = (u16*)alloc(MD * 2);
  u16*  Vbuf = (u16*)alloc(MD * 2);       // aliases: qh/kh/vh early, ffh late
  u16*  qbuf = (u16*)alloc(ND * 2);
  u16*  smpb = (u16*)alloc(ND * 2);
  u16*  tgtb = (u16*)alloc(ND * 2);
  u16*  curb = (u16*)alloc(ND * 2);
  float* t2  = (float*)alloc(ND * 4);
  float* cur = (float*)alloc(ND * 4);
  float* offbuf = (float*)alloc((size_t)NQ * 128 * 4);
  float* attbuf = (float*)alloc((size_t)NQ * 128 * 4);

  u16* qh = Vbuf;
  u16* kh = Vbuf + ND;
  u16* vh = Vbuf + 2 * ND;
  u16* ffh = Vbuf;                         // used after V is dead

  // transposed bf16 weights
  WPack pk;
  int wi = 0, blk = 0;
  auto addw = [&](const float* w, int K, int N) -> u16* {
    u16* wt = (u16*)alloc((size_t)K * N * 2);
    pk.s[wi].w = w; pk.s[wi].wt = wt; pk.s[wi].K = K; pk.s[wi].N = N; pk.s[wi].blk0 = blk;
    blk += (K / 32) * (N / 32);
    ++wi;
    return wt;
  };
  u16* saq_t = addw(sa_qw, D, D);
  u16* sak_t = addw(sa_kw, D, D);
  u16* sav_t = addw(sa_vw, D, D);
  u16* sao_t = addw(sa_ow, D, D);
  u16* ff1_t = addw(ff1_w, D, DFFN);
  u16* ff2_t = addw(ff2_w, DFFN, D);
  u16* caoff_t = addw(ca_off_w, D, 128);
  u16* caatt_t = addw(ca_attn_w, D, 128);
  u16* caval_t = addw(ca_val_w, D, D);
  u16* caout_t = addw(ca_out_w, D, D);
  u16* seoff_t = addw(se_off_w, D, 128);
  u16* seatt_t = addw(se_attn_w, D, 128);
  u16* seval_t = addw(se_val_w, D, D);
  u16* seout_t = addw(se_out_w, D, D);

  const int n4 = (int)(ND / 4);           // 614400
  const dim3 gNQ(2, NQ / 128);            // N=256 GEMMs over 9600 rows
  const dim3 gMS(2, MS / 128);            // val GEMMs
  const dim3 gOFF(1, NQ / 128);           // N=128 GEMMs
  const dim3 gFF1(DFFN / 128, NQ / 128);

  // prep: weights + bf16 copies of src/tgt
  wt_transpose<<<blk, 256, 0, stream>>>(pk);
  cvt_bf16<<<2048, 256, 0, stream>>>(src, srcb, (int)(MD / 4));
  cvt_bf16<<<1200, 256, 0, stream>>>(tgt, tgtb, n4);

  // ---- self-attention ----
  add_vec_bf16<<<2400, 256, 0, stream>>>(tgt, qpos, qbuf, n4);
  gemm_bf16<true,  false><<<gNQ, 256, 0, stream>>>(qbuf, saq_t, sa_qb, qh, NQ, D, D);
  gemm_bf16<true,  false><<<gNQ, 256, 0, stream>>>(qbuf, sak_t, sa_kb, kh, NQ, D, D);
  gemm_bf16<true,  false><<<gNQ, 256, 0, stream>>>(tgtb, sav_t, sa_vb, vh, NQ, D, D);
  mha_kernel<<<B * H, 320, 0, stream>>>(qh, kh, vh, smpb);
  gemm_bf16<false, false><<<gNQ, 256, 0, stream>>>(smpb, sao_t, sa_ob, t2, NQ, D, D);
  add_ln<true><<<NQ / 4, 256, 0, stream>>>(t2, tgt, ln2_g, ln2_b, cur, curb);

  // ---- deformable cross-attn (ca, boundary=False) ----
  add_vec_bf16<<<2400, 256, 0, stream>>>(cur, qpos, qbuf, n4);
  gemm_bf16<true,  false><<<gMS, 256, 0, stream>>>(srcb, caval_t, ca_val_b, Vbuf, MS, D, D);
  gemm_bf16<false, false><<<gOFF, 256, 0, stream>>>(qbuf, caoff_t, ca_off_b, offbuf, NQ, D, 128);
  gemm_bf16<false, false><<<gOFF, 256, 0, stream>>>(qbuf, caatt_t, ca_attn_b, attbuf, NQ, D, 128);
  deform_sample<false><<<NQ, 256, 0, stream>>>(offbuf, attbuf, ref, Vbuf, smpb);
  gemm_bf16<false, false><<<gNQ, 256, 0, stream>>>(smpb, caout_t, ca_out_b, t2, NQ, D, D);
  add_ln<true><<<NQ / 4, 256, 0, stream>>>(t2, cur, ln1_g, ln1_b, cur, curb);

  // ---- deformable cross-attn (se, boundary=True) ----
  add_vec_bf16<<<2400, 256, 0, stream>>>(cur, qpos, qbuf, n4);
  gemm_bf16<true,  false><<<gMS, 256, 0, stream>>>(srcb, seval_t, se_val_b, Vbuf, MS, D, D);
  gemm_bf16<false, false><<<gOFF, 256, 0, stream>>>(qbuf, seoff_t, se_off_b, offbuf, NQ, D, 128);
  gemm_bf16<false, false><<<gOFF, 256, 0, stream>>>(qbuf, seatt_t, se_attn_b, attbuf, NQ, D, 128);
  deform_sample<true><<<NQ, 256, 0, stream>>>(offbuf, attbuf, ref, Vbuf, smpb);
  gemm_bf16<false, false><<<gNQ, 256, 0, stream>>>(smpb, seout_t, se_out_b, t2, NQ, D, D);
  add_ln<true><<<NQ / 4, 256, 0, stream>>>(t2, cur, lnse_g, lnse_b, cur, curb);

  // ---- FFN ----
  gemm_bf16<true,  true ><<<gFF1, 256, 0, stream>>>(curb, ff1_t, ff1_b, ffh, NQ, D, DFFN);
  gemm_bf16<false, false><<<gNQ, 256, 0, stream>>>(ffh, ff2_t, ff2_b, t2, NQ, DFFN, D);
  add_ln<false><<<NQ / 4, 256, 0, stream>>>(t2, cur, ln3_g, ln3_b, (float*)d_out, nullptr);
}

// Round 3
// 806.026 us; speedup vs baseline: 1.7583x; 1.0501x over previous
//
#include <hip/hip_runtime.h>
#include <hip/hip_bf16.h>

namespace {

typedef unsigned short u16;
typedef unsigned int u32;

constexpr int D    = 256;
constexpr int H    = 8;
constexpr int DH   = 32;
constexpr int L    = 4;
constexpr int P    = 4;
constexpr int B    = 32;
constexpr int LQ   = 300;
constexpr int NQ   = B * LQ;      // 9600
constexpr int S    = 3840;
constexpr int MS   = B * S;       // 122880
constexpr int DFFN = 1024;

typedef __attribute__((ext_vector_type(8))) short bf16x8;
typedef __attribute__((ext_vector_type(4))) float f32x4;

__device__ inline u16 f2b(float x) {
  u32 u = __builtin_bit_cast(u32, x);
  u32 r = (u + 0x7FFFu + ((u >> 16) & 1u)) >> 16;
  return (u16)r;
}
__device__ inline float b2f(u16 v) {
  return __builtin_bit_cast(float, (u32)v << 16);
}
__device__ inline void unpack2(u32 w, float& a, float& b) {
  a = __builtin_bit_cast(float, w << 16);
  b = __builtin_bit_cast(float, w & 0xffff0000u);
}

// ---------------------------------------------------------------------------
// bf16 MFMA GEMM: C[M,N] = A[M,K] @ Bt[N,K]^T + bias. 128x128 tile, BK=64,
// 256 threads = 4 waves (2x2), 16x16x32 MFMA, reg-staged LDS (stride 72).
// ---------------------------------------------------------------------------
template<bool OUT_BF16, bool RELU>
__global__ __launch_bounds__(256) void gemm_bf16(
    const u16* __restrict__ A, const u16* __restrict__ Bt,
    const float* __restrict__ bias, void* __restrict__ Cv,
    int M, int K, int N)
{
  constexpr int BM = 128, BN = 128, BK = 64, LDK = 72;
  __shared__ __align__(16) u16 As[BM * LDK];
  __shared__ __align__(16) u16 Bs[BN * LDK];
  const int tid  = threadIdx.x;
  const int lane = tid & 63;
  const int wid  = tid >> 6;
  const int wm = wid >> 1, wn = wid & 1;
  const int m0 = blockIdx.y * BM, n0 = blockIdx.x * BN;

  f32x4 acc[4][4] = {};

  uint4 ra[4], rb[4];
  const int NT = K / BK;

#pragma unroll
  for (int i = 0; i < 4; ++i) {
    const int g = tid + 256 * i;
    const int row = g >> 3, ch = g & 7;
    ra[i] = *(const uint4*)(A  + (size_t)(m0 + row) * K + ch * 8);
    rb[i] = *(const uint4*)(Bt + (size_t)(n0 + row) * K + ch * 8);
  }

  for (int t = 0; t < NT; ++t) {
#pragma unroll
    for (int i = 0; i < 4; ++i) {
      const int g = tid + 256 * i;
      const int row = g >> 3, ch = g & 7;
      *(uint4*)(&As[row * LDK + ch * 8]) = ra[i];
      *(uint4*)(&Bs[row * LDK + ch * 8]) = rb[i];
    }
    __syncthreads();
    if (t + 1 < NT) {
      const int k0 = (t + 1) * BK;
#pragma unroll
      for (int i = 0; i < 4; ++i) {
        const int g = tid + 256 * i;
        const int row = g >> 3, ch = g & 7;
        ra[i] = *(const uint4*)(A  + (size_t)(m0 + row) * K + k0 + ch * 8);
        rb[i] = *(const uint4*)(Bt + (size_t)(n0 + row) * K + k0 + ch * 8);
      }
    }
#pragma unroll
    for (int kk = 0; kk < 2; ++kk) {
      bf16x8 af[4], bfr[4];
      const int krd = kk * 32 + (lane >> 4) * 8;
      const int ra0 = (wm * 64 + (lane & 15)) * LDK + krd;
      const int rb0 = (wn * 64 + (lane & 15)) * LDK + krd;
#pragma unroll
      for (int m = 0; m < 4; ++m) af[m]  = *(const bf16x8*)(&As[ra0 + m * 16 * LDK]);
#pragma unroll
      for (int n = 0; n < 4; ++n) bfr[n] = *(const bf16x8*)(&Bs[rb0 + n * 16 * LDK]);
#pragma unroll
      for (int m = 0; m < 4; ++m)
#pragma unroll
        for (int n = 0; n < 4; ++n)
          acc[m][n] = __builtin_amdgcn_mfma_f32_16x16x32_bf16(af[m], bfr[n], acc[m][n], 0, 0, 0);
    }
    __syncthreads();
  }

  const int cr = (lane >> 4) * 4;
  const int cc = lane & 15;
#pragma unroll
  for (int n = 0; n < 4; ++n) {
    const int gc = n0 + wn * 64 + n * 16 + cc;
    const float bv = bias[gc];
#pragma unroll
    for (int m = 0; m < 4; ++m) {
      const int gr0 = m0 + wm * 64 + m * 16 + cr;
#pragma unroll
      for (int r = 0; r < 4; ++r) {
        float x = acc[m][n][r] + bv;
        if (RELU) x = fmaxf(x, 0.f);
        if (OUT_BF16) ((u16*)Cv)[(size_t)(gr0 + r) * N + gc] = f2b(x);
        else          ((float*)Cv)[(size_t)(gr0 + r) * N + gc] = x;
      }
    }
  }
}

// ---------------------------------------------------------------------------
// Batched weight transpose+convert: W(K,N) f32 -> Wt(N,K) bf16, 32x32 tiles.
// ---------------------------------------------------------------------------
struct WSpec { const float* w; u16* wt; int K, N, blk0; };
struct WPack { WSpec s[14]; };

__global__ __launch_bounds__(256) void wt_transpose(WPack p) {
  __shared__ float tile[32][33];
  const int b = blockIdx.x;
  int i = 0;
#pragma unroll
  for (int j = 1; j < 14; ++j) if (b >= p.s[j].blk0) i = j;
  const float* w = p.s[i].w;
  u16* wt = p.s[i].wt;
  const int K = p.s[i].K, N = p.s[i].N;
  const int lb = b - p.s[i].blk0;
  const int ntN = N >> 5;
  const int tk = lb / ntN, tn = lb - tk * ntN;
  const int r = threadIdx.x >> 5, c = threadIdx.x & 31;
#pragma unroll
  for (int j = 0; j < 4; ++j)
    tile[r + j * 8][c] = w[(size_t)(tk * 32 + r + j * 8) * N + tn * 32 + c];
  __syncthreads();
#pragma unroll
  for (int j = 0; j < 4; ++j)
    wt[(size_t)(tn * 32 + r + j * 8) * K + tk * 32 + c] = f2b(tile[c][r + j * 8]);
}

__global__ __launch_bounds__(256) void cvt_bf16(
    const float* __restrict__ x, u16* __restrict__ y, int n4)
{
  int i = blockIdx.x * 256 + threadIdx.x;
  const int stride = gridDim.x * 256;
  for (; i < n4; i += stride) {
    const float4 v = ((const float4*)x)[i];
    uint2 pk;
    pk.x = (u32)f2b(v.x) | ((u32)f2b(v.y) << 16);
    pk.y = (u32)f2b(v.z) | ((u32)f2b(v.w) << 16);
    ((uint2*)y)[i] = pk;
  }
}

__global__ __launch_bounds__(256) void add_vec_bf16(
    const float* __restrict__ a, const float* __restrict__ b,
    u16* __restrict__ c, int n4)
{
  const int i = blockIdx.x * 256 + threadIdx.x;
  if (i < n4) {
    const float4 va = ((const float4*)a)[i];
    const float4 vb = ((const float4*)b)[i];
    uint2 pk;
    pk.x = (u32)f2b(va.x + vb.x) | ((u32)f2b(va.y + vb.y) << 16);
    pk.y = (u32)f2b(va.z + vb.z) | ((u32)f2b(va.w + vb.w) << 16);
    ((uint2*)c)[i] = pk;
  }
}

// ---------------------------------------------------------------------------
// Self-attention v2: split-K softmax.
// Grid: (B*H) * 3 segments; block 512 threads = 8 waves.
// Each 4-lane group owns one query; lane kc handles keys [kc*75, kc*75+75).
// K,V staged in LDS chunk-major: [8 chunks][300 keys][4 floats] -> per-j
// ds_read_b128 at immediate offset j*4800B, kc-lanes conflict-free, 16
// same-kc lanes broadcast. exp without max-subtraction (scores O(1) in f32).
// ---------------------------------------------------------------------------
__global__ __launch_bounds__(512) void mha_v2(
    const u16* __restrict__ qh, const u16* __restrict__ kh,
    const u16* __restrict__ vh, u16* __restrict__ out)
{
  __shared__ __align__(16) float Ks[8 * 300 * 4];
  __shared__ __align__(16) float Vs[8 * 300 * 4];
  const int bh  = blockIdx.x & 255;      // b*8+h
  const int seg = blockIdx.x >> 8;       // 0..2
  const int b = bh >> 3, h = bh & 7;
  const u16* kbase = kh + (size_t)b * LQ * D + h * DH;
  const u16* vbase = vh + (size_t)b * LQ * D + h * DH;
  for (int e = threadIdx.x; e < 300 * 8; e += 512) {
    const int r = e >> 3, j = e & 7;
    float4 f;
    const uint2 kv = *(const uint2*)(kbase + (size_t)r * D + j * 4);
    unpack2(kv.x, f.x, f.y);
    unpack2(kv.y, f.z, f.w);
    *(float4*)(&Ks[(j * 300 + r) * 4]) = f;
    const uint2 vv = *(const uint2*)(vbase + (size_t)r * D + j * 4);
    unpack2(vv.x, f.x, f.y);
    unpack2(vv.y, f.z, f.w);
    *(float4*)(&Vs[(j * 300 + r) * 4]) = f;
  }
  __syncthreads();

  const int lane = threadIdx.x & 63;
  const int lq = (threadIdx.x >> 6) * 16 + (lane >> 2);   // 0..127
  const int kc = lane & 3;
  const int q = seg * 128 + lq;
  if (q >= LQ) return;

  const u16* qrow = qh + (size_t)(b * LQ + q) * D + h * DH;
  float qv[DH];
#pragma unroll
  for (int c4 = 0; c4 < 4; ++c4) {
    const uint4 u = *(const uint4*)(qrow + c4 * 8);
    unpack2(u.x, qv[c4 * 8 + 0], qv[c4 * 8 + 1]);
    unpack2(u.y, qv[c4 * 8 + 2], qv[c4 * 8 + 3]);
    unpack2(u.z, qv[c4 * 8 + 4], qv[c4 * 8 + 5]);
    unpack2(u.w, qv[c4 * 8 + 6], qv[c4 * 8 + 7]);
  }
#pragma unroll
  for (int d = 0; d < DH; ++d) qv[d] *= 0.17677669529663689f;  // 1/sqrt(32)

  float o[DH] = {};
  float ssum = 0.f;
  const float* kp = &Ks[kc * 75 * 4];
  const float* vp = &Vs[kc * 75 * 4];
  for (int i = 0; i < 75; ++i) {
    float s = 0.f;
#pragma unroll
    for (int j = 0; j < 8; ++j) {
      const float4 kf = *(const float4*)(kp + i * 4 + j * 1200);
      s += qv[j * 4 + 0] * kf.x + qv[j * 4 + 1] * kf.y
         + qv[j * 4 + 2] * kf.z + qv[j * 4 + 3] * kf.w;
    }
    const float p = __expf(s);
    ssum += p;
#pragma unroll
    for (int j = 0; j < 8; ++j) {
      const float4 vf = *(const float4*)(vp + i * 4 + j * 1200);
      o[j * 4 + 0] += p * vf.x; o[j * 4 + 1] += p * vf.y;
      o[j * 4 + 2] += p * vf.z; o[j * 4 + 3] += p * vf.w;
    }
  }

  // merge across the 4 kc-lanes (all groups uniformly active)
  ssum += __shfl_xor(ssum, 1, 64);
  ssum += __shfl_xor(ssum, 2, 64);
#pragma unroll
  for (int d = 0; d < DH; ++d) {
    o[d] += __shfl_xor(o[d], 1, 64);
    o[d] += __shfl_xor(o[d], 2, 64);
  }
  const float inv = 1.f / ssum;

  u16* orow = out + (size_t)(b * LQ + q) * D + h * DH;
#pragma unroll
  for (int c = 0; c < 4; ++c) {
    if (kc == c) {
      uint4 w;
      w.x = (u32)f2b(o[c * 8 + 0] * inv) | ((u32)f2b(o[c * 8 + 1] * inv) << 16);
      w.y = (u32)f2b(o[c * 8 + 2] * inv) | ((u32)f2b(o[c * 8 + 3] * inv) << 16);
      w.z = (u32)f2b(o[c * 8 + 4] * inv) | ((u32)f2b(o[c * 8 + 5] * inv) << 16);
      w.w = (u32)f2b(o[c * 8 + 6] * inv) | ((u32)f2b(o[c * 8 + 7] * inv) << 16);
      *(uint4*)(orow + c * 8) = w;
    }
  }
}

// ---------------------------------------------------------------------------
// Deformable sampling. 32 lanes = one (b,q,h); 8 units per block.
// ---------------------------------------------------------------------------
template<bool BOUNDARY>
__global__ __launch_bounds__(256) void deform_sample(
    const float* __restrict__ offb, const float* __restrict__ attb,
    const float* __restrict__ ref, const u16* __restrict__ value,
    u16* __restrict__ out)
{
  const int u = blockIdx.x * 8 + (threadIdx.x >> 5);
  const int d = threadIdx.x & 31;
  const int h = u & 7;
  const int bq = u >> 3;
  const int b = bq / LQ;
  const float* offp = offb + (size_t)bq * 128 + h * 16;
  const float* attp = attb + (size_t)bq * 128 + h * 16;

  float att[16];
  float amax = -1e30f;
#pragma unroll
  for (int i = 0; i < 16; ++i) { att[i] = attp[i]; amax = fmaxf(amax, att[i]); }
  float asum = 0.f;
#pragma unroll
  for (int i = 0; i < 16; ++i) { att[i] = __expf(att[i] - amax); asum += att[i]; }
  const float ainv = 1.f / asum;

  const float* refp = ref + (size_t)bq * L * 2;
  const int lens[4]   = {2048, 1024, 512, 256};
  const int starts[4] = {0, 2048, 3072, 3584};
  float o = 0.f;
#pragma unroll
  for (int l = 0; l < L; ++l) {
    const float center = refp[l * 2 + 0];
    const float width  = refp[l * 2 + 1];
    const int T = lens[l], s0 = starts[l];
    const u16* vb = value + (size_t)(b * S + s0) * D + h * DH + d;
#pragma unroll
    for (int p = 0; p < P; ++p) {
      float anchor = center;
      if (BOUNDARY) anchor += (p < P / 2 ? -0.5f : 0.5f) * width;
      const float loc = anchor + offp[l * 4 + p] * width * 0.125f;
      const float x = loc * (float)T - 0.5f;
      const float x0 = floorf(x);
      const float w = x - x0;
      const int i0 = (int)x0;
      const int i1 = i0 + 1;
      float g0 = 0.f, g1 = 0.f;
      if (i0 >= 0 && i0 < T) g0 = b2f(vb[(size_t)i0 * D]);
      if (i1 >= 0 && i1 < T) g1 = b2f(vb[(size_t)i1 * D]);
      o += att[l * 4 + p] * ainv * (g0 * (1.f - w) + g1 * w);
    }
  }
  out[(size_t)bq * D + h * DH + d] = f2b(o);
}

// ---------------------------------------------------------------------------
// out = LN(x + res); optionally also emit bf16 copy.
// ---------------------------------------------------------------------------
template<bool WRITE_BF>
__global__ __launch_bounds__(256) void add_ln(
    const float* __restrict__ x, const float* __restrict__ res,
    const float* __restrict__ g, const float* __restrict__ bb,
    float* __restrict__ out, u16* __restrict__ outb)
{
  const int row = blockIdx.x * 4 + (threadIdx.x >> 6);
  const int lane = threadIdx.x & 63;
  const float* xr = x + (size_t)row * D;
  const float* rr = res + (size_t)row * D;
  float v[4];
  float s = 0.f;
#pragma unroll
  for (int i = 0; i < 4; ++i) { v[i] = xr[lane + 64 * i] + rr[lane + 64 * i]; s += v[i]; }
#pragma unroll
  for (int off = 32; off > 0; off >>= 1) s += __shfl_xor(s, off, 64);
  const float mean = s * (1.f / D);
  float vs = 0.f;
#pragma unroll
  for (int i = 0; i < 4; ++i) { const float dd = v[i] - mean; vs += dd * dd; }
#pragma unroll
  for (int off = 32; off > 0; off >>= 1) vs += __shfl_xor(vs, off, 64);
  const float rstd = rsqrtf(vs * (1.f / D) + 1e-5f);
  float* orow = out + (size_t)row * D;
#pragma unroll
  for (int i = 0; i < 4; ++i) {
    const float y = (v[i] - mean) * rstd * g[lane + 64 * i] + bb[lane + 64 * i];
    orow[lane + 64 * i] = y;
    if (WRITE_BF) outb[(size_t)row * D + lane + 64 * i] = f2b(y);
  }
}

}  // namespace

extern "C" void kernel_launch(void* const* d_in, const int* in_sizes, int n_in,
                              void* d_out, int out_size, void* d_ws, size_t ws_size,
                              hipStream_t stream)
{
  const float* tgt   = (const float*)d_in[0];
  const float* qpos  = (const float*)d_in[1];
  const float* ref   = (const float*)d_in[2];
  const float* src   = (const float*)d_in[3];
  const float* sa_qw = (const float*)d_in[6];
  const float* sa_kw = (const float*)d_in[7];
  const float* sa_vw = (const float*)d_in[8];
  const float* sa_ow = (const float*)d_in[9];
  const float* ff1_w = (const float*)d_in[10];
  const float* ff2_w = (const float*)d_in[11];
  const float* sa_qb = (const float*)d_in[12];
  const float* sa_kb = (const float*)d_in[13];
  const float* sa_vb = (const float*)d_in[14];
  const float* sa_ob = (const float*)d_in[15];
  const float* ff1_b = (const float*)d_in[16];
  const float* ff2_b = (const float*)d_in[17];
  const float* ca_off_w  = (const float*)d_in[18];
  const float* ca_off_b  = (const float*)d_in[19];
  const float* ca_attn_w = (const float*)d_in[20];
  const float* ca_attn_b = (const float*)d_in[21];
  const float* ca_val_w  = (const float*)d_in[22];
  const float* ca_val_b  = (const float*)d_in[23];
  const float* ca_out_w  = (const float*)d_in[24];
  const float* ca_out_b  = (const float*)d_in[25];
  const float* se_off_w  = (const float*)d_in[26];
  const float* se_off_b  = (const float*)d_in[27];
  const float* se_attn_w = (const float*)d_in[28];
  const float* se_attn_b = (const float*)d_in[29];
  const float* se_val_w  = (const float*)d_in[30];
  const float* se_val_b  = (const float*)d_in[31];
  const float* se_out_w  = (const float*)d_in[32];
  const float* se_out_b  = (const float*)d_in[33];
  const float* ln1_g  = (const float*)d_in[34];
  const float* ln1_b  = (const float*)d_in[35];
  const float* lnse_g = (const float*)d_in[36];
  const float* lnse_b = (const float*)d_in[37];
  const float* ln2_g  = (const float*)d_in[38];
  const float* ln2_b  = (const float*)d_in[39];
  const float* ln3_g  = (const float*)d_in[40];
  const float* ln3_b  = (const float*)d_in[41];

  const size_t ND = (size_t)NQ * D;       // 2,457,600
  const size_t MD = (size_t)MS * D;       // 31,457,280

  char* base = (char*)d_ws;
  size_t off = 0;
  auto alloc = [&](size_t bytes) -> void* {
    void* p = base + off;
    off += (bytes + 255) & ~(size_t)255;
    return p;
  };
  u16*  srcb = (u16*)alloc(MD * 2);
  u16*  Vbuf = (u16*)alloc(MD * 2);       // aliases: qh/kh/vh early, ffh late
  u16*  qbuf = (u16*)alloc(ND * 2);
  u16*  smpb = (u16*)alloc(ND * 2);
  u16*  tgtb = (u16*)alloc(ND * 2);
  u16*  curb = (u16*)alloc(ND * 2);
  float* t2  = (float*)alloc(ND * 4);
  float* cur = (float*)alloc(ND * 4);
  float* offbuf = (float*)alloc((size_t)NQ * 128 * 4);
  float* attbuf = (float*)alloc((size_t)NQ * 128 * 4);

  u16* qh = Vbuf;
  u16* kh = Vbuf + ND;
  u16* vh = Vbuf + 2 * ND;
  u16* ffh = Vbuf;                         // used after V is dead

  // transposed bf16 weights
  WPack pk;
  int wi = 0, blk = 0;
  auto addw = [&](const float* w, int K, int N) -> u16* {
    u16* wt = (u16*)alloc((size_t)K * N * 2);
    pk.s[wi].w = w; pk.s[wi].wt = wt; pk.s[wi].K = K; pk.s[wi].N = N; pk.s[wi].blk0 = blk;
    blk += (K / 32) * (N / 32);
    ++wi;
    return wt;
  };
  u16* saq_t = addw(sa_qw, D, D);
  u16* sak_t = addw(sa_kw, D, D);
  u16* sav_t = addw(sa_vw, D, D);
  u16* sao_t = addw(sa_ow, D, D);
  u16* ff1_t = addw(ff1_w, D, DFFN);
  u16* ff2_t = addw(ff2_w, DFFN, D);
  u16* caoff_t = addw(ca_off_w, D, 128);
  u16* caatt_t = addw(ca_attn_w, D, 128);
  u16* caval_t = addw(ca_val_w, D, D);
  u16* caout_t = addw(ca_out_w, D, D);
  u16* seoff_t = addw(se_off_w, D, 128);
  u16* seatt_t = addw(se_attn_w, D, 128);
  u16* seval_t = addw(se_val_w, D, D);
  u16* seout_t = addw(se_out_w, D, D);

  const int n4 = (int)(ND / 4);           // 614400
  const dim3 gNQ(2, NQ / 128);            // N=256 GEMMs over 9600 rows
  const dim3 gMS(2, MS / 128);            // val GEMMs
  const dim3 gOFF(1, NQ / 128);           // N=128 GEMMs
  const dim3 gFF1(DFFN / 128, NQ / 128);

  // prep: weights + bf16 copies of src/tgt
  wt_transpose<<<blk, 256, 0, stream>>>(pk);
  cvt_bf16<<<2048, 256, 0, stream>>>(src, srcb, (int)(MD / 4));
  cvt_bf16<<<1200, 256, 0, stream>>>(tgt, tgtb, n4);

  // ---- self-attention ----
  add_vec_bf16<<<2400, 256, 0, stream>>>(tgt, qpos, qbuf, n4);
  gemm_bf16<true,  false><<<gNQ, 256, 0, stream>>>(qbuf, saq_t, sa_qb, qh, NQ, D, D);
  gemm_bf16<true,  false><<<gNQ, 256, 0, stream>>>(qbuf, sak_t, sa_kb, kh, NQ, D, D);
  gemm_bf16<true,  false><<<gNQ, 256, 0, stream>>>(tgtb, sav_t, sa_vb, vh, NQ, D, D);
  mha_v2<<<B * H * 3, 512, 0, stream>>>(qh, kh, vh, smpb);
  gemm_bf16<false, false><<<gNQ, 256, 0, stream>>>(smpb, sao_t, sa_ob, t2, NQ, D, D);
  add_ln<true><<<NQ / 4, 256, 0, stream>>>(t2, tgt, ln2_g, ln2_b, cur, curb);

  // ---- deformable cross-attn (ca, boundary=False) ----
  add_vec_bf16<<<2400, 256, 0, stream>>>(cur, qpos, qbuf, n4);
  gemm_bf16<true,  false><<<gMS, 256, 0, stream>>>(srcb, caval_t, ca_val_b, Vbuf, MS, D, D);
  gemm_bf16<false, false><<<gOFF, 256, 0, stream>>>(qbuf, caoff_t, ca_off_b, offbuf, NQ, D, 128);
  gemm_bf16<false, false><<<gOFF, 256, 0, stream>>>(qbuf, caatt_t, ca_attn_b, attbuf, NQ, D, 128);
  deform_sample<false><<<NQ, 256, 0, stream>>>(offbuf, attbuf, ref, Vbuf, smpb);
  gemm_bf16<false, false><<<gNQ, 256, 0, stream>>>(smpb, caout_t, ca_out_b, t2, NQ, D, D);
  add_ln<true><<<NQ / 4, 256, 0, stream>>>(t2, cur, ln1_g, ln1_b, cur, curb);

  // ---- deformable cross-attn (se, boundary=True) ----
  add_vec_bf16<<<2400, 256, 0, stream>>>(cur, qpos, qbuf, n4);
  gemm_bf16<true,  false><<<gMS, 256, 0, stream>>>(srcb, seval_t, se_val_b, Vbuf, MS, D, D);
  gemm_bf16<false, false><<<gOFF, 256, 0, stream>>>(qbuf, seoff_t, se_off_b, offbuf, NQ, D, 128);
  gemm_bf16<false, false><<<gOFF, 256, 0, stream>>>(qbuf, seatt_t, se_attn_b, attbuf, NQ, D, 128);
  deform_sample<true><<<NQ, 256, 0, stream>>>(offbuf, attbuf, ref, Vbuf, smpb);
  gemm_bf16<false, false><<<gNQ, 256, 0, stream>>>(smpb, seout_t, se_out_b, t2, NQ, D, D);
  add_ln<true><<<NQ / 4, 256, 0, stream>>>(t2, cur, lnse_g, lnse_b, cur, curb);

  // ---- FFN ----
  gemm_bf16<true,  true ><<<gFF1, 256, 0, stream>>>(curb, ff1_t, ff1_b, ffh, NQ, D, DFFN);
  gemm_bf16<false, false><<<gNQ, 256, 0, stream>>>(ffh, ff2_t, ff2_b, t2, NQ, DFFN, D);
  add_ln<false><<<NQ / 4, 256, 0, stream>>>(t2, cur, ln3_g, ln3_b, (float*)d_out, nullptr);
}

// Round 4
// 613.015 us; speedup vs baseline: 2.3119x; 1.3149x over previous
//
#include <hip/hip_runtime.h>
#include <hip/hip_bf16.h>

namespace {

typedef unsigned short u16;
typedef unsigned int u32;

constexpr int D    = 256;
constexpr int H    = 8;
constexpr int DH   = 32;
constexpr int L    = 4;
constexpr int P    = 4;
constexpr int B    = 32;
constexpr int LQ   = 300;
constexpr int NQ   = B * LQ;      // 9600
constexpr int S    = 3840;
constexpr int MS   = B * S;       // 122880
constexpr int DFFN = 1024;

typedef __attribute__((ext_vector_type(8))) short bf16x8;
typedef __attribute__((ext_vector_type(4))) float f32x4;

__device__ inline u16 f2b(float x) {
  u32 u = __builtin_bit_cast(u32, x);
  u32 r = (u + 0x7FFFu + ((u >> 16) & 1u)) >> 16;
  return (u16)r;
}
__device__ inline float b2f(u16 v) {
  return __builtin_bit_cast(float, (u32)v << 16);
}
__device__ inline void unpack2(u32 w, float& a, float& b) {
  a = __builtin_bit_cast(float, w << 16);
  b = __builtin_bit_cast(float, w & 0xffff0000u);
}

// ---------------------------------------------------------------------------
// bf16 MFMA GEMM: C[M,N] = A[M,K] @ Bt[N,K]^T + bias. 128x128 tile, BK=64,
// 256 threads = 4 waves (2x2), 16x16x32 MFMA, reg-staged LDS (stride 72).
// ---------------------------------------------------------------------------
template<bool OUT_BF16, bool RELU>
__global__ __launch_bounds__(256) void gemm_bf16(
    const u16* __restrict__ A, const u16* __restrict__ Bt,
    const float* __restrict__ bias, void* __restrict__ Cv,
    int M, int K, int N)
{
  constexpr int BM = 128, BN = 128, BK = 64, LDK = 72;
  __shared__ __align__(16) u16 As[BM * LDK];
  __shared__ __align__(16) u16 Bs[BN * LDK];
  const int tid  = threadIdx.x;
  const int lane = tid & 63;
  const int wid  = tid >> 6;
  const int wm = wid >> 1, wn = wid & 1;
  const int m0 = blockIdx.y * BM, n0 = blockIdx.x * BN;

  f32x4 acc[4][4] = {};

  uint4 ra[4], rb[4];
  const int NT = K / BK;

#pragma unroll
  for (int i = 0; i < 4; ++i) {
    const int g = tid + 256 * i;
    const int row = g >> 3, ch = g & 7;
    ra[i] = *(const uint4*)(A  + (size_t)(m0 + row) * K + ch * 8);
    rb[i] = *(const uint4*)(Bt + (size_t)(n0 + row) * K + ch * 8);
  }

  for (int t = 0; t < NT; ++t) {
#pragma unroll
    for (int i = 0; i < 4; ++i) {
      const int g = tid + 256 * i;
      const int row = g >> 3, ch = g & 7;
      *(uint4*)(&As[row * LDK + ch * 8]) = ra[i];
      *(uint4*)(&Bs[row * LDK + ch * 8]) = rb[i];
    }
    __syncthreads();
    if (t + 1 < NT) {
      const int k0 = (t + 1) * BK;
#pragma unroll
      for (int i = 0; i < 4; ++i) {
        const int g = tid + 256 * i;
        const int row = g >> 3, ch = g & 7;
        ra[i] = *(const uint4*)(A  + (size_t)(m0 + row) * K + k0 + ch * 8);
        rb[i] = *(const uint4*)(Bt + (size_t)(n0 + row) * K + k0 + ch * 8);
      }
    }
#pragma unroll
    for (int kk = 0; kk < 2; ++kk) {
      bf16x8 af[4], bfr[4];
      const int krd = kk * 32 + (lane >> 4) * 8;
      const int ra0 = (wm * 64 + (lane & 15)) * LDK + krd;
      const int rb0 = (wn * 64 + (lane & 15)) * LDK + krd;
#pragma unroll
      for (int m = 0; m < 4; ++m) af[m]  = *(const bf16x8*)(&As[ra0 + m * 16 * LDK]);
#pragma unroll
      for (int n = 0; n < 4; ++n) bfr[n] = *(const bf16x8*)(&Bs[rb0 + n * 16 * LDK]);
#pragma unroll
      for (int m = 0; m < 4; ++m)
#pragma unroll
        for (int n = 0; n < 4; ++n)
          acc[m][n] = __builtin_amdgcn_mfma_f32_16x16x32_bf16(af[m], bfr[n], acc[m][n], 0, 0, 0);
    }
    __syncthreads();
  }

  const int cr = (lane >> 4) * 4;
  const int cc = lane & 15;
#pragma unroll
  for (int n = 0; n < 4; ++n) {
    const int gc = n0 + wn * 64 + n * 16 + cc;
    const float bv = bias[gc];
#pragma unroll
    for (int m = 0; m < 4; ++m) {
      const int gr0 = m0 + wm * 64 + m * 16 + cr;
#pragma unroll
      for (int r = 0; r < 4; ++r) {
        float x = acc[m][n][r] + bv;
        if (RELU) x = fmaxf(x, 0.f);
        if (OUT_BF16) ((u16*)Cv)[(size_t)(gr0 + r) * N + gc] = f2b(x);
        else          ((float*)Cv)[(size_t)(gr0 + r) * N + gc] = x;
      }
    }
  }
}

// ---------------------------------------------------------------------------
// Batched weight transpose+convert: W(K,N) f32 -> Wt(N,K) bf16, 32x32 tiles.
// ---------------------------------------------------------------------------
struct WSpec { const float* w; u16* wt; int K, N, blk0; };
struct WPack { WSpec s[14]; };

__global__ __launch_bounds__(256) void wt_transpose(WPack p) {
  __shared__ float tile[32][33];
  const int b = blockIdx.x;
  int i = 0;
#pragma unroll
  for (int j = 1; j < 14; ++j) if (b >= p.s[j].blk0) i = j;
  const float* w = p.s[i].w;
  u16* wt = p.s[i].wt;
  const int K = p.s[i].K, N = p.s[i].N;
  const int lb = b - p.s[i].blk0;
  const int ntN = N >> 5;
  const int tk = lb / ntN, tn = lb - tk * ntN;
  const int r = threadIdx.x >> 5, c = threadIdx.x & 31;
#pragma unroll
  for (int j = 0; j < 4; ++j)
    tile[r + j * 8][c] = w[(size_t)(tk * 32 + r + j * 8) * N + tn * 32 + c];
  __syncthreads();
#pragma unroll
  for (int j = 0; j < 4; ++j)
    wt[(size_t)(tn * 32 + r + j * 8) * K + tk * 32 + c] = f2b(tile[c][r + j * 8]);
}

__global__ __launch_bounds__(256) void cvt_bf16(
    const float* __restrict__ x, u16* __restrict__ y, int n4)
{
  int i = blockIdx.x * 256 + threadIdx.x;
  const int stride = gridDim.x * 256;
  for (; i < n4; i += stride) {
    const float4 v = ((const float4*)x)[i];
    uint2 pk;
    pk.x = (u32)f2b(v.x) | ((u32)f2b(v.y) << 16);
    pk.y = (u32)f2b(v.z) | ((u32)f2b(v.w) << 16);
    ((uint2*)y)[i] = pk;
  }
}

__global__ __launch_bounds__(256) void add_vec_bf16(
    const float* __restrict__ a, const float* __restrict__ b,
    u16* __restrict__ c, int n4)
{
  const int i = blockIdx.x * 256 + threadIdx.x;
  if (i < n4) {
    const float4 va = ((const float4*)a)[i];
    const float4 vb = ((const float4*)b)[i];
    uint2 pk;
    pk.x = (u32)f2b(va.x + vb.x) | ((u32)f2b(va.y + vb.y) << 16);
    pk.y = (u32)f2b(va.z + vb.z) | ((u32)f2b(va.w + vb.w) << 16);
    ((uint2*)c)[i] = pk;
  }
}

// [ca_off_b|ca_attn_b|se_off_b|se_attn_b] -> 512 floats
__global__ __launch_bounds__(256) void concat_bias4(
    const float* __restrict__ a, const float* __restrict__ b,
    const float* __restrict__ c, const float* __restrict__ d,
    float* __restrict__ o)
{
  const int i = threadIdx.x & 127;
  const int w = threadIdx.x >> 7;
  const float* lo = w ? c : a;
  const float* hi = w ? d : b;
  o[w * 256 + i] = lo[i];
  o[w * 256 + 128 + i] = hi[i];
}

// ---------------------------------------------------------------------------
// Self-attention v2: split-K softmax (see round 3).
// ---------------------------------------------------------------------------
__global__ __launch_bounds__(512) void mha_v2(
    const u16* __restrict__ qh, const u16* __restrict__ kh,
    const u16* __restrict__ vh, u16* __restrict__ out)
{
  __shared__ __align__(16) float Ks[8 * 300 * 4];
  __shared__ __align__(16) float Vs[8 * 300 * 4];
  const int bh  = blockIdx.x & 255;      // b*8+h
  const int seg = blockIdx.x >> 8;       // 0..2
  const int b = bh >> 3, h = bh & 7;
  const u16* kbase = kh + (size_t)b * LQ * D + h * DH;
  const u16* vbase = vh + (size_t)b * LQ * D + h * DH;
  for (int e = threadIdx.x; e < 300 * 8; e += 512) {
    const int r = e >> 3, j = e & 7;
    float4 f;
    const uint2 kv = *(const uint2*)(kbase + (size_t)r * D + j * 4);
    unpack2(kv.x, f.x, f.y);
    unpack2(kv.y, f.z, f.w);
    *(float4*)(&Ks[(j * 300 + r) * 4]) = f;
    const uint2 vv = *(const uint2*)(vbase + (size_t)r * D + j * 4);
    unpack2(vv.x, f.x, f.y);
    unpack2(vv.y, f.z, f.w);
    *(float4*)(&Vs[(j * 300 + r) * 4]) = f;
  }
  __syncthreads();

  const int lane = threadIdx.x & 63;
  const int lq = (threadIdx.x >> 6) * 16 + (lane >> 2);   // 0..127
  const int kc = lane & 3;
  const int q = seg * 128 + lq;
  if (q >= LQ) return;

  const u16* qrow = qh + (size_t)(b * LQ + q) * D + h * DH;
  float qv[DH];
#pragma unroll
  for (int c4 = 0; c4 < 4; ++c4) {
    const uint4 u = *(const uint4*)(qrow + c4 * 8);
    unpack2(u.x, qv[c4 * 8 + 0], qv[c4 * 8 + 1]);
    unpack2(u.y, qv[c4 * 8 + 2], qv[c4 * 8 + 3]);
    unpack2(u.z, qv[c4 * 8 + 4], qv[c4 * 8 + 5]);
    unpack2(u.w, qv[c4 * 8 + 6], qv[c4 * 8 + 7]);
  }
#pragma unroll
  for (int d = 0; d < DH; ++d) qv[d] *= 0.17677669529663689f;  // 1/sqrt(32)

  float o[DH] = {};
  float ssum = 0.f;
  const float* kp = &Ks[kc * 75 * 4];
  const float* vp = &Vs[kc * 75 * 4];
  for (int i = 0; i < 75; ++i) {
    float s = 0.f;
#pragma unroll
    for (int j = 0; j < 8; ++j) {
      const float4 kf = *(const float4*)(kp + i * 4 + j * 1200);
      s += qv[j * 4 + 0] * kf.x + qv[j * 4 + 1] * kf.y
         + qv[j * 4 + 2] * kf.z + qv[j * 4 + 3] * kf.w;
    }
    const float p = __expf(s);
    ssum += p;
#pragma unroll
    for (int j = 0; j < 8; ++j) {
      const float4 vf = *(const float4*)(vp + i * 4 + j * 1200);
      o[j * 4 + 0] += p * vf.x; o[j * 4 + 1] += p * vf.y;
      o[j * 4 + 2] += p * vf.z; o[j * 4 + 3] += p * vf.w;
    }
  }

  ssum += __shfl_xor(ssum, 1, 64);
  ssum += __shfl_xor(ssum, 2, 64);
#pragma unroll
  for (int d = 0; d < DH; ++d) {
    o[d] += __shfl_xor(o[d], 1, 64);
    o[d] += __shfl_xor(o[d], 2, 64);
  }
  const float inv = 1.f / ssum;

  u16* orow = out + (size_t)(b * LQ + q) * D + h * DH;
#pragma unroll
  for (int c = 0; c < 4; ++c) {
    if (kc == c) {
      uint4 w;
      w.x = (u32)f2b(o[c * 8 + 0] * inv) | ((u32)f2b(o[c * 8 + 1] * inv) << 16);
      w.y = (u32)f2b(o[c * 8 + 2] * inv) | ((u32)f2b(o[c * 8 + 3] * inv) << 16);
      w.z = (u32)f2b(o[c * 8 + 4] * inv) | ((u32)f2b(o[c * 8 + 5] * inv) << 16);
      w.w = (u32)f2b(o[c * 8 + 6] * inv) | ((u32)f2b(o[c * 8 + 7] * inv) << 16);
      *(uint4*)(orow + c * 8) = w;
    }
  }
}

// ---------------------------------------------------------------------------
// Deformable sampling v2: one block (128 thr) per (b,q).
// Phase A: thread t=(h,l,p) -> coalesced off/att load, 16-lane softmax,
//          tap table {byteoff0, w0, byteoff1, w1} in LDS (weights folded with
//          attn/denominator; OOB -> weight 0, index clamped).
// Phase B: 16-lane group g owns head g: 16 taps x 2 gathers, u32 loads
//          (2 dims/lane, 64 B/instr), all independent; packed u32 store.
// oa layout: (NQ, 256) f32: cols [0,128) = off, [128,256) = attn logits.
// ---------------------------------------------------------------------------
template<bool BOUNDARY>
__global__ __launch_bounds__(128) void deform_v2(
    const float* __restrict__ oa, const float* __restrict__ ref,
    const u16* __restrict__ value, u16* __restrict__ out)
{
  __shared__ __align__(16) uint4 owt[128];
  const int bq = blockIdx.x;
  const int b = bq / LQ;
  const int t = threadIdx.x;        // 0..127
  const int h = t >> 4;
  const int l = (t >> 2) & 3;
  const int p = t & 3;

  const float off   = oa[(size_t)bq * 256 + t];
  const float logit = oa[(size_t)bq * 256 + 128 + t];
  const float center = ref[(size_t)bq * 8 + l * 2 + 0];
  const float width  = ref[(size_t)bq * 8 + l * 2 + 1];

  const float e = __expf(logit);
  float ssum = e;
  ssum += __shfl_xor(ssum, 1, 64);
  ssum += __shfl_xor(ssum, 2, 64);
  ssum += __shfl_xor(ssum, 4, 64);
  ssum += __shfl_xor(ssum, 8, 64);
  const float wa = e / ssum;

  const int T  = 2048 >> l;
  const int s0 = 4096 - (4096 >> l);
  float anchor = center;
  if (BOUNDARY) anchor += (p < 2 ? -0.5f : 0.5f) * width;
  const float loc = anchor + off * width * 0.125f;
  const float x = loc * (float)T - 0.5f;
  const float x0 = floorf(x);
  const float w = x - x0;
  const int i0 = (int)x0;
  const int i1 = i0 + 1;
  const float w0 = (i0 >= 0 && i0 < T) ? wa * (1.f - w) : 0.f;
  const float w1 = (i1 >= 0 && i1 < T) ? wa * w : 0.f;
  const int i0c = min(max(i0, 0), T - 1);
  const int i1c = min(max(i1, 0), T - 1);
  uint4 pack;
  pack.x = (u32)((s0 + i0c) * (D * 2) + h * (DH * 2));
  pack.y = __builtin_bit_cast(u32, w0);
  pack.z = (u32)((s0 + i1c) * (D * 2) + h * (DH * 2));
  pack.w = __builtin_bit_cast(u32, w1);
  owt[t] = pack;
  __syncthreads();

  const int g  = t >> 4;         // group = head
  const int ln = t & 15;         // dims 2ln, 2ln+1
  const char* vb = (const char*)(value + (size_t)b * S * D) + ln * 4;
  float o0 = 0.f, o1 = 0.f;
#pragma unroll
  for (int j = 0; j < 16; ++j) {
    const uint4 ow = owt[g * 16 + j];
    const u32 v0 = *(const u32*)(vb + ow.x);
    const u32 v1 = *(const u32*)(vb + ow.z);
    const float wt0 = __builtin_bit_cast(float, ow.y);
    const float wt1 = __builtin_bit_cast(float, ow.w);
    float a, c;
    unpack2(v0, a, c); o0 += wt0 * a; o1 += wt0 * c;
    unpack2(v1, a, c); o0 += wt1 * a; o1 += wt1 * c;
  }
  const u32 res = (u32)f2b(o0) | ((u32)f2b(o1) << 16);
  *(u32*)(out + (size_t)bq * D + g * DH + ln * 2) = res;
}

// ---------------------------------------------------------------------------
// out = LN(x + res); optionally also emit bf16 copy.
// ---------------------------------------------------------------------------
template<bool WRITE_BF>
__global__ __launch_bounds__(256) void add_ln(
    const float* __restrict__ x, const float* __restrict__ res,
    const float* __restrict__ g, const float* __restrict__ bb,
    float* __restrict__ out, u16* __restrict__ outb)
{
  const int row = blockIdx.x * 4 + (threadIdx.x >> 6);
  const int lane = threadIdx.x & 63;
  const float* xr = x + (size_t)row * D;
  const float* rr = res + (size_t)row * D;
  float v[4];
  float s = 0.f;
#pragma unroll
  for (int i = 0; i < 4; ++i) { v[i] = xr[lane + 64 * i] + rr[lane + 64 * i]; s += v[i]; }
#pragma unroll
  for (int off = 32; off > 0; off >>= 1) s += __shfl_xor(s, off, 64);
  const float mean = s * (1.f / D);
  float vs = 0.f;
#pragma unroll
  for (int i = 0; i < 4; ++i) { const float dd = v[i] - mean; vs += dd * dd; }
#pragma unroll
  for (int off = 32; off > 0; off >>= 1) vs += __shfl_xor(vs, off, 64);
  const float rstd = rsqrtf(vs * (1.f / D) + 1e-5f);
  float* orow = out + (size_t)row * D;
#pragma unroll
  for (int i = 0; i < 4; ++i) {
    const float y = (v[i] - mean) * rstd * g[lane + 64 * i] + bb[lane + 64 * i];
    orow[lane + 64 * i] = y;
    if (WRITE_BF) outb[(size_t)row * D + lane + 64 * i] = f2b(y);
  }
}

}  // namespace

extern "C" void kernel_launch(void* const* d_in, const int* in_sizes, int n_in,
                              void* d_out, int out_size, void* d_ws, size_t ws_size,
                              hipStream_t stream)
{
  const float* tgt   = (const float*)d_in[0];
  const float* qpos  = (const float*)d_in[1];
  const float* ref   = (const float*)d_in[2];
  const float* src   = (const float*)d_in[3];
  const float* sa_qw = (const float*)d_in[6];
  const float* sa_kw = (const float*)d_in[7];
  const float* sa_vw = (const float*)d_in[8];
  const float* sa_ow = (const float*)d_in[9];
  const float* ff1_w = (const float*)d_in[10];
  const float* ff2_w = (const float*)d_in[11];
  const float* sa_qb = (const float*)d_in[12];
  const float* sa_kb = (const float*)d_in[13];
  const float* sa_vb = (const float*)d_in[14];
  const float* sa_ob = (const float*)d_in[15];
  const float* ff1_b = (const float*)d_in[16];
  const float* ff2_b = (const float*)d_in[17];
  const float* ca_off_w  = (const float*)d_in[18];
  const float* ca_off_b  = (const float*)d_in[19];
  const float* ca_attn_w = (const float*)d_in[20];
  const float* ca_attn_b = (const float*)d_in[21];
  const float* ca_val_w  = (const float*)d_in[22];
  const float* ca_val_b  = (const float*)d_in[23];
  const float* ca_out_w  = (const float*)d_in[24];
  const float* ca_out_b  = (const float*)d_in[25];
  const float* se_off_w  = (const float*)d_in[26];
  const float* se_off_b  = (const float*)d_in[27];
  const float* se_attn_w = (const float*)d_in[28];
  const float* se_attn_b = (const float*)d_in[29];
  const float* se_val_w  = (const float*)d_in[30];
  const float* se_val_b  = (const float*)d_in[31];
  const float* se_out_w  = (const float*)d_in[32];
  const float* se_out_b  = (const float*)d_in[33];
  const float* ln1_g  = (const float*)d_in[34];
  const float* ln1_b  = (const float*)d_in[35];
  const float* lnse_g = (const float*)d_in[36];
  const float* lnse_b = (const float*)d_in[37];
  const float* ln2_g  = (const float*)d_in[38];
  const float* ln2_b  = (const float*)d_in[39];
  const float* ln3_g  = (const float*)d_in[40];
  const float* ln3_b  = (const float*)d_in[41];

  const size_t ND = (size_t)NQ * D;       // 2,457,600
  const size_t MD = (size_t)MS * D;       // 31,457,280

  char* base = (char*)d_ws;
  size_t off = 0;
  auto alloc = [&](size_t bytes) -> void* {
    void* p = base + off;
    off += (bytes + 255) & ~(size_t)255;
    return p;
  };
  u16*  srcb = (u16*)alloc(MD * 2);
  u16*  Vbuf = (u16*)alloc(MD * 2);       // aliases: qh/kh/vh early, ffh late
  u16*  qbuf = (u16*)alloc(ND * 2);
  u16*  smpb = (u16*)alloc(ND * 2);
  u16*  tgtb = (u16*)alloc(ND * 2);
  u16*  curb = (u16*)alloc(ND * 2);
  float* t2  = (float*)alloc(ND * 4);
  float* cur = (float*)alloc(ND * 4);
  float* oabuf = (float*)alloc((size_t)NQ * 256 * 4);
  float* bias4 = (float*)alloc(512 * 4);

  u16* qh = Vbuf;
  u16* kh = Vbuf + ND;
  u16* vh = Vbuf + 2 * ND;
  u16* ffh = Vbuf;                         // used after V is dead

  // transposed bf16 weights
  WPack pk;
  int wi = 0, blk = 0;
  auto addw = [&](const float* w, int K, int N) -> u16* {
    u16* wt = (u16*)alloc((size_t)K * N * 2);
    pk.s[wi].w = w; pk.s[wi].wt = wt; pk.s[wi].K = K; pk.s[wi].N = N; pk.s[wi].blk0 = blk;
    blk += (K / 32) * (N / 32);
    ++wi;
    return wt;
  };
  u16* saq_t = addw(sa_qw, D, D);
  u16* sak_t = addw(sa_kw, D, D);
  u16* sav_t = addw(sa_vw, D, D);
  u16* sao_t = addw(sa_ow, D, D);
  u16* ff1_t = addw(ff1_w, D, DFFN);
  u16* ff2_t = addw(ff2_w, DFFN, D);
  // off & att transposed weights must be CONTIGUOUS (fused N=256 GEMM):
  // alloc sizes are 256-byte multiples so adjacency holds.
  u16* caoff_t = addw(ca_off_w, D, 128);
  u16* caatt_t = addw(ca_attn_w, D, 128);  (void)caatt_t;
  u16* caval_t = addw(ca_val_w, D, D);
  u16* caout_t = addw(ca_out_w, D, D);
  u16* seoff_t = addw(se_off_w, D, 128);
  u16* seatt_t = addw(se_attn_w, D, 128);  (void)seatt_t;
  u16* seval_t = addw(se_val_w, D, D);
  u16* seout_t = addw(se_out_w, D, D);

  const int n4 = (int)(ND / 4);           // 614400
  const dim3 gNQ(2, NQ / 128);            // N=256 GEMMs over 9600 rows
  const dim3 gMS(2, MS / 128);            // val GEMMs
  const dim3 gFF1(DFFN / 128, NQ / 128);

  // prep: weights + bf16 copies of src/tgt + concat biases
  wt_transpose<<<blk, 256, 0, stream>>>(pk);
  cvt_bf16<<<2048, 256, 0, stream>>>(src, srcb, (int)(MD / 4));
  cvt_bf16<<<1200, 256, 0, stream>>>(tgt, tgtb, n4);
  concat_bias4<<<1, 256, 0, stream>>>(ca_off_b, ca_attn_b, se_off_b, se_attn_b, bias4);

  // ---- self-attention ----
  add_vec_bf16<<<2400, 256, 0, stream>>>(tgt, qpos, qbuf, n4);
  gemm_bf16<true,  false><<<gNQ, 256, 0, stream>>>(qbuf, saq_t, sa_qb, qh, NQ, D, D);
  gemm_bf16<true,  false><<<gNQ, 256, 0, stream>>>(qbuf, sak_t, sa_kb, kh, NQ, D, D);
  gemm_bf16<true,  false><<<gNQ, 256, 0, stream>>>(tgtb, sav_t, sa_vb, vh, NQ, D, D);
  mha_v2<<<B * H * 3, 512, 0, stream>>>(qh, kh, vh, smpb);
  gemm_bf16<false, false><<<gNQ, 256, 0, stream>>>(smpb, sao_t, sa_ob, t2, NQ, D, D);
  add_ln<true><<<NQ / 4, 256, 0, stream>>>(t2, tgt, ln2_g, ln2_b, cur, curb);

  // ---- deformable cross-attn (ca, boundary=False) ----
  add_vec_bf16<<<2400, 256, 0, stream>>>(cur, qpos, qbuf, n4);
  gemm_bf16<true,  false><<<gMS, 256, 0, stream>>>(srcb, caval_t, ca_val_b, Vbuf, MS, D, D);
  gemm_bf16<false, false><<<gNQ, 256, 0, stream>>>(qbuf, caoff_t, bias4, oabuf, NQ, D, 256);
  deform_v2<false><<<NQ, 128, 0, stream>>>(oabuf, ref, Vbuf, smpb);
  gemm_bf16<false, false><<<gNQ, 256, 0, stream>>>(smpb, caout_t, ca_out_b, t2, NQ, D, D);
  add_ln<true><<<NQ / 4, 256, 0, stream>>>(t2, cur, ln1_g, ln1_b, cur, curb);

  // ---- deformable cross-attn (se, boundary=True) ----
  add_vec_bf16<<<2400, 256, 0, stream>>>(cur, qpos, qbuf, n4);
  gemm_bf16<true,  false><<<gMS, 256, 0, stream>>>(srcb, seval_t, se_val_b, Vbuf, MS, D, D);
  gemm_bf16<false, false><<<gNQ, 256, 0, stream>>>(qbuf, seoff_t, bias4 + 256, oabuf, NQ, D, 256);
  deform_v2<true><<<NQ, 128, 0, stream>>>(oabuf, ref, Vbuf, smpb);
  gemm_bf16<false, false><<<gNQ, 256, 0, stream>>>(smpb, seout_t, se_out_b, t2, NQ, D, D);
  add_ln<true><<<NQ / 4, 256, 0, stream>>>(t2, cur, lnse_g, lnse_b, cur, curb);

  // ---- FFN ----
  gemm_bf16<true,  true ><<<gFF1, 256, 0, stream>>>(curb, ff1_t, ff1_b, ffh, NQ, D, DFFN);
  gemm_bf16<false, false><<<gNQ, 256, 0, stream>>>(ffh, ff2_t, ff2_b, t2, NQ, DFFN, D);
  add_ln<false><<<NQ / 4, 256, 0, stream>>>(t2, cur, ln3_g, ln3_b, (float*)d_out, nullptr);
}

// Round 5
// 533.165 us; speedup vs baseline: 2.6582x; 1.1498x over previous
//
#include <hip/hip_runtime.h>
#include <hip/hip_bf16.h>

namespace {

typedef unsigned short u16;
typedef unsigned int u32;

constexpr int D    = 256;
constexpr int H    = 8;
constexpr int DH   = 32;
constexpr int L    = 4;
constexpr int P    = 4;
constexpr int B    = 32;
constexpr int LQ   = 300;
constexpr int NQ   = B * LQ;      // 9600
constexpr int S    = 3840;
constexpr int MS   = B * S;       // 122880
constexpr int DFFN = 1024;

typedef __attribute__((ext_vector_type(8))) short bf16x8;
typedef __attribute__((ext_vector_type(4))) float f32x4;

__device__ inline u16 f2b(float x) {
  u32 u = __builtin_bit_cast(u32, x);
  u32 r = (u + 0x7FFFu + ((u >> 16) & 1u)) >> 16;
  return (u16)r;
}
__device__ inline float b2f(u16 v) {
  return __builtin_bit_cast(float, (u32)v << 16);
}
__device__ inline void unpack2(u32 w, float& a, float& b) {
  a = __builtin_bit_cast(float, w << 16);
  b = __builtin_bit_cast(float, w & 0xffff0000u);
}

// ---------------------------------------------------------------------------
// bf16 MFMA GEMM: C[M,N] = A[M,K] @ Bt[N,K]^T + bias. 128x128 tile, BK=64,
// 256 threads = 4 waves (2x2), 16x16x32 MFMA, reg-staged LDS (stride 72).
// OUT_BF16 path: LDS-staged coalesced epilogue (16B/lane stores).
// ---------------------------------------------------------------------------
template<bool OUT_BF16, bool RELU>
__global__ __launch_bounds__(256) void gemm_bf16(
    const u16* __restrict__ A, const u16* __restrict__ Bt,
    const float* __restrict__ bias, void* __restrict__ Cv,
    int M, int K, int N)
{
  constexpr int BM = 128, BN = 128, BK = 64, LDK = 72;
  __shared__ __align__(16) u16 sh[BM * LDK + BN * LDK];   // 36864 B
  u16* As = sh;
  u16* Bs = sh + BM * LDK;
  const int tid  = threadIdx.x;
  const int lane = tid & 63;
  const int wid  = tid >> 6;
  const int wm = wid >> 1, wn = wid & 1;
  const int m0 = blockIdx.y * BM, n0 = blockIdx.x * BN;

  f32x4 acc[4][4] = {};

  uint4 ra[4], rb[4];
  const int NT = K / BK;

#pragma unroll
  for (int i = 0; i < 4; ++i) {
    const int g = tid + 256 * i;
    const int row = g >> 3, ch = g & 7;
    ra[i] = *(const uint4*)(A  + (size_t)(m0 + row) * K + ch * 8);
    rb[i] = *(const uint4*)(Bt + (size_t)(n0 + row) * K + ch * 8);
  }

  for (int t = 0; t < NT; ++t) {
#pragma unroll
    for (int i = 0; i < 4; ++i) {
      const int g = tid + 256 * i;
      const int row = g >> 3, ch = g & 7;
      *(uint4*)(&As[row * LDK + ch * 8]) = ra[i];
      *(uint4*)(&Bs[row * LDK + ch * 8]) = rb[i];
    }
    __syncthreads();
    if (t + 1 < NT) {
      const int k0 = (t + 1) * BK;
#pragma unroll
      for (int i = 0; i < 4; ++i) {
        const int g = tid + 256 * i;
        const int row = g >> 3, ch = g & 7;
        ra[i] = *(const uint4*)(A  + (size_t)(m0 + row) * K + k0 + ch * 8);
        rb[i] = *(const uint4*)(Bt + (size_t)(n0 + row) * K + k0 + ch * 8);
      }
    }
#pragma unroll
    for (int kk = 0; kk < 2; ++kk) {
      bf16x8 af[4], bfr[4];
      const int krd = kk * 32 + (lane >> 4) * 8;
      const int ra0 = (wm * 64 + (lane & 15)) * LDK + krd;
      const int rb0 = (wn * 64 + (lane & 15)) * LDK + krd;
#pragma unroll
      for (int m = 0; m < 4; ++m) af[m]  = *(const bf16x8*)(&As[ra0 + m * 16 * LDK]);
#pragma unroll
      for (int n = 0; n < 4; ++n) bfr[n] = *(const bf16x8*)(&Bs[rb0 + n * 16 * LDK]);
#pragma unroll
      for (int m = 0; m < 4; ++m)
#pragma unroll
        for (int n = 0; n < 4; ++n)
          acc[m][n] = __builtin_amdgcn_mfma_f32_16x16x32_bf16(af[m], bfr[n], acc[m][n], 0, 0, 0);
    }
    __syncthreads();
  }

  const int cr = (lane >> 4) * 4;
  const int cc = lane & 15;
  if constexpr (OUT_BF16) {
    // stage bf16 C-tile in LDS (stride 136), then coalesced 16B stores
    constexpr int STC = 136;
    u16* stg = sh;
#pragma unroll
    for (int n = 0; n < 4; ++n) {
      const int lc = wn * 64 + n * 16 + cc;
      const float bv = bias[n0 + lc];
#pragma unroll
      for (int m = 0; m < 4; ++m) {
        const int lr0 = wm * 64 + m * 16 + cr;
#pragma unroll
        for (int r = 0; r < 4; ++r) {
          float x = acc[m][n][r] + bv;
          if (RELU) x = fmaxf(x, 0.f);
          stg[(lr0 + r) * STC + lc] = f2b(x);
        }
      }
    }
    __syncthreads();
    u16* Cb = (u16*)Cv;
#pragma unroll
    for (int i = 0; i < 8; ++i) {
      const int c = tid + 256 * i;
      const int row = c >> 4, chk = c & 15;
      *(uint4*)(Cb + (size_t)(m0 + row) * N + n0 + chk * 8) =
          *(const uint4*)(&stg[row * STC + chk * 8]);
    }
  } else {
#pragma unroll
    for (int n = 0; n < 4; ++n) {
      const int gc = n0 + wn * 64 + n * 16 + cc;
      const float bv = bias[gc];
#pragma unroll
      for (int m = 0; m < 4; ++m) {
        const int gr0 = m0 + wm * 64 + m * 16 + cr;
#pragma unroll
        for (int r = 0; r < 4; ++r) {
          float x = acc[m][n][r] + bv;
          if (RELU) x = fmaxf(x, 0.f);
          ((float*)Cv)[(size_t)(gr0 + r) * N + gc] = x;
        }
      }
    }
  }
}

// ---------------------------------------------------------------------------
// Value-projection GEMM: C[M,256] = f32 A[M,256] @ Bt[256,256]^T + bias,
// bf16 out. BM=128, BN=256 (A read exactly once), 512 thr = 8 waves (2x4).
// A converted f32->bf16 in registers; coalesced LDS-staged epilogue.
// ---------------------------------------------------------------------------
__global__ __launch_bounds__(512) void gemm_val(
    const float* __restrict__ A, const u16* __restrict__ Bt,
    const float* __restrict__ bias, u16* __restrict__ C)
{
  constexpr int K = 256, N = 256, BM = 128, BN = 256, BK = 64, LDK = 72;
  __shared__ __align__(16) u16 sh[(BM + BN) * LDK];       // 55296 B
  u16* As = sh;
  u16* Bs = sh + BM * LDK;
  const int tid  = threadIdx.x;
  const int lane = tid & 63;
  const int wid  = tid >> 6;
  const int wm = wid >> 2, wn = wid & 3;
  const int m0 = blockIdx.x * BM;

  f32x4 acc[4][4] = {};
  float4 ra[2][2];
  uint4 rb[4];

#pragma unroll
  for (int i = 0; i < 2; ++i) {
    const int g = tid + 512 * i;
    const int row = g >> 3, ch = g & 7;
    const float* ap = A + (size_t)(m0 + row) * K + ch * 8;
    ra[i][0] = *(const float4*)(ap);
    ra[i][1] = *(const float4*)(ap + 4);
  }
#pragma unroll
  for (int i = 0; i < 4; ++i) {
    const int g = tid + 512 * i;
    const int row = g >> 3, ch = g & 7;
    rb[i] = *(const uint4*)(Bt + (size_t)row * K + ch * 8);
  }

  for (int t = 0; t < 4; ++t) {
#pragma unroll
    for (int i = 0; i < 2; ++i) {
      const int g = tid + 512 * i;
      const int row = g >> 3, ch = g & 7;
      uint4 w;
      w.x = (u32)f2b(ra[i][0].x) | ((u32)f2b(ra[i][0].y) << 16);
      w.y = (u32)f2b(ra[i][0].z) | ((u32)f2b(ra[i][0].w) << 16);
      w.z = (u32)f2b(ra[i][1].x) | ((u32)f2b(ra[i][1].y) << 16);
      w.w = (u32)f2b(ra[i][1].z) | ((u32)f2b(ra[i][1].w) << 16);
      *(uint4*)(&As[row * LDK + ch * 8]) = w;
    }
#pragma unroll
    for (int i = 0; i < 4; ++i) {
      const int g = tid + 512 * i;
      const int row = g >> 3, ch = g & 7;
      *(uint4*)(&Bs[row * LDK + ch * 8]) = rb[i];
    }
    __syncthreads();
    if (t + 1 < 4) {
      const int k0 = (t + 1) * BK;
#pragma unroll
      for (int i = 0; i < 2; ++i) {
        const int g = tid + 512 * i;
        const int row = g >> 3, ch = g & 7;
        const float* ap = A + (size_t)(m0 + row) * K + k0 + ch * 8;
        ra[i][0] = *(const float4*)(ap);
        ra[i][1] = *(const float4*)(ap + 4);
      }
#pragma unroll
      for (int i = 0; i < 4; ++i) {
        const int g = tid + 512 * i;
        const int row = g >> 3, ch = g & 7;
        rb[i] = *(const uint4*)(Bt + (size_t)row * K + k0 + ch * 8);
      }
    }
#pragma unroll
    for (int kk = 0; kk < 2; ++kk) {
      bf16x8 af[4], bfr[4];
      const int krd = kk * 32 + (lane >> 4) * 8;
      const int ra0 = (wm * 64 + (lane & 15)) * LDK + krd;
      const int rb0 = (wn * 64 + (lane & 15)) * LDK + krd;
#pragma unroll
      for (int m = 0; m < 4; ++m) af[m]  = *(const bf16x8*)(&As[ra0 + m * 16 * LDK]);
#pragma unroll
      for (int n = 0; n < 4; ++n) bfr[n] = *(const bf16x8*)(&Bs[rb0 + n * 16 * LDK]);
#pragma unroll
      for (int m = 0; m < 4; ++m)
#pragma unroll
        for (int n = 0; n < 4; ++n)
          acc[m][n] = __builtin_amdgcn_mfma_f32_16x16x32_bf16(af[m], bfr[n], acc[m][n], 0, 0, 0);
    }
    __syncthreads();
  }

  // epilogue: two 64-row passes staged in LDS (stride 264), coalesced stores
  constexpr int STC = 264;
  const int cr = (lane >> 4) * 4;
  const int cc = lane & 15;
  u16* stg = sh;
#pragma unroll
  for (int pass = 0; pass < 2; ++pass) {
    if (pass) __syncthreads();
    if (wm == pass) {
#pragma unroll
      for (int n = 0; n < 4; ++n) {
        const int col = wn * 64 + n * 16 + cc;
        const float bv = bias[col];
#pragma unroll
        for (int m = 0; m < 4; ++m) {
          const int lr0 = m * 16 + cr;
#pragma unroll
          for (int r = 0; r < 4; ++r)
            stg[(lr0 + r) * STC + col] = f2b(acc[m][n][r] + bv);
        }
      }
    }
    __syncthreads();
#pragma unroll
    for (int i = 0; i < 4; ++i) {
      const int c = tid + 512 * i;
      const int row = c >> 5, chk = c & 31;
      *(uint4*)(C + (size_t)(m0 + pass * 64 + row) * N + chk * 8) =
          *(const uint4*)(&stg[row * STC + chk * 8]);
    }
  }
}

// ---------------------------------------------------------------------------
// Batched weight transpose+convert: W(K,N) f32 -> Wt(N,K) bf16, 32x32 tiles.
// ---------------------------------------------------------------------------
struct WSpec { const float* w; u16* wt; int K, N, blk0; };
struct WPack { WSpec s[14]; };

__global__ __launch_bounds__(256) void wt_transpose(WPack p) {
  __shared__ float tile[32][33];
  const int b = blockIdx.x;
  int i = 0;
#pragma unroll
  for (int j = 1; j < 14; ++j) if (b >= p.s[j].blk0) i = j;
  const float* w = p.s[i].w;
  u16* wt = p.s[i].wt;
  const int K = p.s[i].K, N = p.s[i].N;
  const int lb = b - p.s[i].blk0;
  const int ntN = N >> 5;
  const int tk = lb / ntN, tn = lb - tk * ntN;
  const int r = threadIdx.x >> 5, c = threadIdx.x & 31;
#pragma unroll
  for (int j = 0; j < 4; ++j)
    tile[r + j * 8][c] = w[(size_t)(tk * 32 + r + j * 8) * N + tn * 32 + c];
  __syncthreads();
#pragma unroll
  for (int j = 0; j < 4; ++j)
    wt[(size_t)(tn * 32 + r + j * 8) * K + tk * 32 + c] = f2b(tile[c][r + j * 8]);
}

__global__ __launch_bounds__(256) void cvt_bf16(
    const float* __restrict__ x, u16* __restrict__ y, int n4)
{
  int i = blockIdx.x * 256 + threadIdx.x;
  const int stride = gridDim.x * 256;
  for (; i < n4; i += stride) {
    const float4 v = ((const float4*)x)[i];
    uint2 pk;
    pk.x = (u32)f2b(v.x) | ((u32)f2b(v.y) << 16);
    pk.y = (u32)f2b(v.z) | ((u32)f2b(v.w) << 16);
    ((uint2*)y)[i] = pk;
  }
}

__global__ __launch_bounds__(256) void add_vec_bf16(
    const float* __restrict__ a, const float* __restrict__ b,
    u16* __restrict__ c, int n4)
{
  const int i = blockIdx.x * 256 + threadIdx.x;
  if (i < n4) {
    const float4 va = ((const float4*)a)[i];
    const float4 vb = ((const float4*)b)[i];
    uint2 pk;
    pk.x = (u32)f2b(va.x + vb.x) | ((u32)f2b(va.y + vb.y) << 16);
    pk.y = (u32)f2b(va.z + vb.z) | ((u32)f2b(va.w + vb.w) << 16);
    ((uint2*)c)[i] = pk;
  }
}

// [ca_off_b|ca_attn_b|se_off_b|se_attn_b] -> 512 floats
__global__ __launch_bounds__(256) void concat_bias4(
    const float* __restrict__ a, const float* __restrict__ b,
    const float* __restrict__ c, const float* __restrict__ d,
    float* __restrict__ o)
{
  const int i = threadIdx.x & 127;
  const int w = threadIdx.x >> 7;
  const float* lo = w ? c : a;
  const float* hi = w ? d : b;
  o[w * 256 + i] = lo[i];
  o[w * 256 + 128 + i] = hi[i];
}

// ---------------------------------------------------------------------------
// Self-attention v2: split-K softmax (see round 3).
// ---------------------------------------------------------------------------
__global__ __launch_bounds__(512) void mha_v2(
    const u16* __restrict__ qh, const u16* __restrict__ kh,
    const u16* __restrict__ vh, u16* __restrict__ out)
{
  __shared__ __align__(16) float Ks[8 * 300 * 4];
  __shared__ __align__(16) float Vs[8 * 300 * 4];
  const int bh  = blockIdx.x & 255;      // b*8+h
  const int seg = blockIdx.x >> 8;       // 0..2
  const int b = bh >> 3, h = bh & 7;
  const u16* kbase = kh + (size_t)b * LQ * D + h * DH;
  const u16* vbase = vh + (size_t)b * LQ * D + h * DH;
  for (int e = threadIdx.x; e < 300 * 8; e += 512) {
    const int r = e >> 3, j = e & 7;
    float4 f;
    const uint2 kv = *(const uint2*)(kbase + (size_t)r * D + j * 4);
    unpack2(kv.x, f.x, f.y);
    unpack2(kv.y, f.z, f.w);
    *(float4*)(&Ks[(j * 300 + r) * 4]) = f;
    const uint2 vv = *(const uint2*)(vbase + (size_t)r * D + j * 4);
    unpack2(vv.x, f.x, f.y);
    unpack2(vv.y, f.z, f.w);
    *(float4*)(&Vs[(j * 300 + r) * 4]) = f;
  }
  __syncthreads();

  const int lane = threadIdx.x & 63;
  const int lq = (threadIdx.x >> 6) * 16 + (lane >> 2);   // 0..127
  const int kc = lane & 3;
  const int q = seg * 128 + lq;
  if (q >= LQ) return;

  const u16* qrow = qh + (size_t)(b * LQ + q) * D + h * DH;
  float qv[DH];
#pragma unroll
  for (int c4 = 0; c4 < 4; ++c4) {
    const uint4 u = *(const uint4*)(qrow + c4 * 8);
    unpack2(u.x, qv[c4 * 8 + 0], qv[c4 * 8 + 1]);
    unpack2(u.y, qv[c4 * 8 + 2], qv[c4 * 8 + 3]);
    unpack2(u.z, qv[c4 * 8 + 4], qv[c4 * 8 + 5]);
    unpack2(u.w, qv[c4 * 8 + 6], qv[c4 * 8 + 7]);
  }
#pragma unroll
  for (int d = 0; d < DH; ++d) qv[d] *= 0.17677669529663689f;  // 1/sqrt(32)

  float o[DH] = {};
  float ssum = 0.f;
  const float* kp = &Ks[kc * 75 * 4];
  const float* vp = &Vs[kc * 75 * 4];
  for (int i = 0; i < 75; ++i) {
    float s = 0.f;
#pragma unroll
    for (int j = 0; j < 8; ++j) {
      const float4 kf = *(const float4*)(kp + i * 4 + j * 1200);
      s += qv[j * 4 + 0] * kf.x + qv[j * 4 + 1] * kf.y
         + qv[j * 4 + 2] * kf.z + qv[j * 4 + 3] * kf.w;
    }
    const float p = __expf(s);
    ssum += p;
#pragma unroll
    for (int j = 0; j < 8; ++j) {
      const float4 vf = *(const float4*)(vp + i * 4 + j * 1200);
      o[j * 4 + 0] += p * vf.x; o[j * 4 + 1] += p * vf.y;
      o[j * 4 + 2] += p * vf.z; o[j * 4 + 3] += p * vf.w;
    }
  }

  ssum += __shfl_xor(ssum, 1, 64);
  ssum += __shfl_xor(ssum, 2, 64);
#pragma unroll
  for (int d = 0; d < DH; ++d) {
    o[d] += __shfl_xor(o[d], 1, 64);
    o[d] += __shfl_xor(o[d], 2, 64);
  }
  const float inv = 1.f / ssum;

  u16* orow = out + (size_t)(b * LQ + q) * D + h * DH;
#pragma unroll
  for (int c = 0; c < 4; ++c) {
    if (kc == c) {
      uint4 w;
      w.x = (u32)f2b(o[c * 8 + 0] * inv) | ((u32)f2b(o[c * 8 + 1] * inv) << 16);
      w.y = (u32)f2b(o[c * 8 + 2] * inv) | ((u32)f2b(o[c * 8 + 3] * inv) << 16);
      w.z = (u32)f2b(o[c * 8 + 4] * inv) | ((u32)f2b(o[c * 8 + 5] * inv) << 16);
      w.w = (u32)f2b(o[c * 8 + 6] * inv) | ((u32)f2b(o[c * 8 + 7] * inv) << 16);
      *(uint4*)(orow + c * 8) = w;
    }
  }
}

// ---------------------------------------------------------------------------
// Deformable sampling v2 (see round 4).
// ---------------------------------------------------------------------------
template<bool BOUNDARY>
__global__ __launch_bounds__(128) void deform_v2(
    const float* __restrict__ oa, const float* __restrict__ ref,
    const u16* __restrict__ value, u16* __restrict__ out)
{
  __shared__ __align__(16) uint4 owt[128];
  const int bq = blockIdx.x;
  const int b = bq / LQ;
  const int t = threadIdx.x;        // 0..127
  const int h = t >> 4;
  const int l = (t >> 2) & 3;
  const int p = t & 3;

  const float off   = oa[(size_t)bq * 256 + t];
  const float logit = oa[(size_t)bq * 256 + 128 + t];
  const float center = ref[(size_t)bq * 8 + l * 2 + 0];
  const float width  = ref[(size_t)bq * 8 + l * 2 + 1];

  const float e = __expf(logit);
  float ssum = e;
  ssum += __shfl_xor(ssum, 1, 64);
  ssum += __shfl_xor(ssum, 2, 64);
  ssum += __shfl_xor(ssum, 4, 64);
  ssum += __shfl_xor(ssum, 8, 64);
  const float wa = e / ssum;

  const int T  = 2048 >> l;
  const int s0 = 4096 - (4096 >> l);
  float anchor = center;
  if (BOUNDARY) anchor += (p < 2 ? -0.5f : 0.5f) * width;
  const float loc = anchor + off * width * 0.125f;
  const float x = loc * (float)T - 0.5f;
  const float x0 = floorf(x);
  const float w = x - x0;
  const int i0 = (int)x0;
  const int i1 = i0 + 1;
  const float w0 = (i0 >= 0 && i0 < T) ? wa * (1.f - w) : 0.f;
  const float w1 = (i1 >= 0 && i1 < T) ? wa * w : 0.f;
  const int i0c = min(max(i0, 0), T - 1);
  const int i1c = min(max(i1, 0), T - 1);
  uint4 pack;
  pack.x = (u32)((s0 + i0c) * (D * 2) + h * (DH * 2));
  pack.y = __builtin_bit_cast(u32, w0);
  pack.z = (u32)((s0 + i1c) * (D * 2) + h * (DH * 2));
  pack.w = __builtin_bit_cast(u32, w1);
  owt[t] = pack;
  __syncthreads();

  const int g  = t >> 4;         // group = head
  const int ln = t & 15;         // dims 2ln, 2ln+1
  const char* vb = (const char*)(value + (size_t)b * S * D) + ln * 4;
  float o0 = 0.f, o1 = 0.f;
#pragma unroll
  for (int j = 0; j < 16; ++j) {
    const uint4 ow = owt[g * 16 + j];
    const u32 v0 = *(const u32*)(vb + ow.x);
    const u32 v1 = *(const u32*)(vb + ow.z);
    const float wt0 = __builtin_bit_cast(float, ow.y);
    const float wt1 = __builtin_bit_cast(float, ow.w);
    float a, c;
    unpack2(v0, a, c); o0 += wt0 * a; o1 += wt0 * c;
    unpack2(v1, a, c); o0 += wt1 * a; o1 += wt1 * c;
  }
  const u32 res = (u32)f2b(o0) | ((u32)f2b(o1) << 16);
  *(u32*)(out + (size_t)bq * D + g * DH + ln * 2) = res;
}

// ---------------------------------------------------------------------------
// out = LN(x + res); optionally also emit bf16 copy.
// ---------------------------------------------------------------------------
template<bool WRITE_BF>
__global__ __launch_bounds__(256) void add_ln(
    const float* __restrict__ x, const float* __restrict__ res,
    const float* __restrict__ g, const float* __restrict__ bb,
    float* __restrict__ out, u16* __restrict__ outb)
{
  const int row = blockIdx.x * 4 + (threadIdx.x >> 6);
  const int lane = threadIdx.x & 63;
  const float* xr = x + (size_t)row * D;
  const float* rr = res + (size_t)row * D;
  float v[4];
  float s = 0.f;
#pragma unroll
  for (int i = 0; i < 4; ++i) { v[i] = xr[lane + 64 * i] + rr[lane + 64 * i]; s += v[i]; }
#pragma unroll
  for (int off = 32; off > 0; off >>= 1) s += __shfl_xor(s, off, 64);
  const float mean = s * (1.f / D);
  float vs = 0.f;
#pragma unroll
  for (int i = 0; i < 4; ++i) { const float dd = v[i] - mean; vs += dd * dd; }
#pragma unroll
  for (int off = 32; off > 0; off >>= 1) vs += __shfl_xor(vs, off, 64);
  const float rstd = rsqrtf(vs * (1.f / D) + 1e-5f);
  float* orow = out + (size_t)row * D;
#pragma unroll
  for (int i = 0; i < 4; ++i) {
    const float y = (v[i] - mean) * rstd * g[lane + 64 * i] + bb[lane + 64 * i];
    orow[lane + 64 * i] = y;
    if (WRITE_BF) outb[(size_t)row * D + lane + 64 * i] = f2b(y);
  }
}

}  // namespace

extern "C" void kernel_launch(void* const* d_in, const int* in_sizes, int n_in,
                              void* d_out, int out_size, void* d_ws, size_t ws_size,
                              hipStream_t stream)
{
  const float* tgt   = (const float*)d_in[0];
  const float* qpos  = (const float*)d_in[1];
  const float* ref   = (const float*)d_in[2];
  const float* src   = (const float*)d_in[3];
  const float* sa_qw = (const float*)d_in[6];
  const float* sa_kw = (const float*)d_in[7];
  const float* sa_vw = (const float*)d_in[8];
  const float* sa_ow = (const float*)d_in[9];
  const float* ff1_w = (const float*)d_in[10];
  const float* ff2_w = (const float*)d_in[11];
  const float* sa_qb = (const float*)d_in[12];
  const float* sa_kb = (const float*)d_in[13];
  const float* sa_vb = (const float*)d_in[14];
  const float* sa_ob = (const float*)d_in[15];
  const float* ff1_b = (const float*)d_in[16];
  const float* ff2_b = (const float*)d_in[17];
  const float* ca_off_w  = (const float*)d_in[18];
  const float* ca_off_b  = (const float*)d_in[19];
  const float* ca_attn_w = (const float*)d_in[20];
  const float* ca_attn_b = (const float*)d_in[21];
  const float* ca_val_w  = (const float*)d_in[22];
  const float* ca_val_b  = (const float*)d_in[23];
  const float* ca_out_w  = (const float*)d_in[24];
  const float* ca_out_b  = (const float*)d_in[25];
  const float* se_off_w  = (const float*)d_in[26];
  const float* se_off_b  = (const float*)d_in[27];
  const float* se_attn_w = (const float*)d_in[28];
  const float* se_attn_b = (const float*)d_in[29];
  const float* se_val_w  = (const float*)d_in[30];
  const float* se_val_b  = (const float*)d_in[31];
  const float* se_out_w  = (const float*)d_in[32];
  const float* se_out_b  = (const float*)d_in[33];
  const float* ln1_g  = (const float*)d_in[34];
  const float* ln1_b  = (const float*)d_in[35];
  const float* lnse_g = (const float*)d_in[36];
  const float* lnse_b = (const float*)d_in[37];
  const float* ln2_g  = (const float*)d_in[38];
  const float* ln2_b  = (const float*)d_in[39];
  const float* ln3_g  = (const float*)d_in[40];
  const float* ln3_b  = (const float*)d_in[41];

  const size_t ND = (size_t)NQ * D;       // 2,457,600
  const size_t MD = (size_t)MS * D;       // 31,457,280

  char* base = (char*)d_ws;
  size_t off = 0;
  auto alloc = [&](size_t bytes) -> void* {
    void* p = base + off;
    off += (bytes + 255) & ~(size_t)255;
    return p;
  };
  u16*  Vbuf = (u16*)alloc(MD * 2);       // aliases: qh/kh/vh early, ffh late
  u16*  qbuf = (u16*)alloc(ND * 2);
  u16*  smpb = (u16*)alloc(ND * 2);
  u16*  tgtb = (u16*)alloc(ND * 2);
  u16*  curb = (u16*)alloc(ND * 2);
  float* t2  = (float*)alloc(ND * 4);
  float* cur = (float*)alloc(ND * 4);
  float* oabuf = (float*)alloc((size_t)NQ * 256 * 4);
  float* bias4 = (float*)alloc(512 * 4);

  u16* qh = Vbuf;
  u16* kh = Vbuf + ND;
  u16* vh = Vbuf + 2 * ND;
  u16* ffh = Vbuf;                         // used after V is dead

  // transposed bf16 weights
  WPack pk;
  int wi = 0, blk = 0;
  auto addw = [&](const float* w, int K, int N) -> u16* {
    u16* wt = (u16*)alloc((size_t)K * N * 2);
    pk.s[wi].w = w; pk.s[wi].wt = wt; pk.s[wi].K = K; pk.s[wi].N = N; pk.s[wi].blk0 = blk;
    blk += (K / 32) * (N / 32);
    ++wi;
    return wt;
  };
  u16* saq_t = addw(sa_qw, D, D);
  u16* sak_t = addw(sa_kw, D, D);
  u16* sav_t = addw(sa_vw, D, D);
  u16* sao_t = addw(sa_ow, D, D);
  u16* ff1_t = addw(ff1_w, D, DFFN);
  u16* ff2_t = addw(ff2_w, DFFN, D);
  // off & att transposed weights must be CONTIGUOUS (fused N=256 GEMM):
  u16* caoff_t = addw(ca_off_w, D, 128);
  u16* caatt_t = addw(ca_attn_w, D, 128);  (void)caatt_t;
  u16* caval_t = addw(ca_val_w, D, D);
  u16* caout_t = addw(ca_out_w, D, D);
  u16* seoff_t = addw(se_off_w, D, 128);
  u16* seatt_t = addw(se_attn_w, D, 128);  (void)seatt_t;
  u16* seval_t = addw(se_val_w, D, D);
  u16* seout_t = addw(se_out_w, D, D);

  const int n4 = (int)(ND / 4);           // 614400
  const dim3 gNQ(2, NQ / 128);            // N=256 GEMMs over 9600 rows
  const dim3 gFF1(DFFN / 128, NQ / 128);

  // prep: weights + bf16 copy of tgt + concat biases
  wt_transpose<<<blk, 256, 0, stream>>>(pk);
  cvt_bf16<<<1200, 256, 0, stream>>>(tgt, tgtb, n4);
  concat_bias4<<<1, 256, 0, stream>>>(ca_off_b, ca_attn_b, se_off_b, se_attn_b, bias4);

  // ---- self-attention ----
  add_vec_bf16<<<2400, 256, 0, stream>>>(tgt, qpos, qbuf, n4);
  gemm_bf16<true,  false><<<gNQ, 256, 0, stream>>>(qbuf, saq_t, sa_qb, qh, NQ, D, D);
  gemm_bf16<true,  false><<<gNQ, 256, 0, stream>>>(qbuf, sak_t, sa_kb, kh, NQ, D, D);
  gemm_bf16<true,  false><<<gNQ, 256, 0, stream>>>(tgtb, sav_t, sa_vb, vh, NQ, D, D);
  mha_v2<<<B * H * 3, 512, 0, stream>>>(qh, kh, vh, smpb);
  gemm_bf16<false, false><<<gNQ, 256, 0, stream>>>(smpb, sao_t, sa_ob, t2, NQ, D, D);
  add_ln<true><<<NQ / 4, 256, 0, stream>>>(t2, tgt, ln2_g, ln2_b, cur, curb);

  // ---- deformable cross-attn (ca, boundary=False) ----
  add_vec_bf16<<<2400, 256, 0, stream>>>(cur, qpos, qbuf, n4);
  gemm_val<<<MS / 128, 512, 0, stream>>>(src, caval_t, ca_val_b, Vbuf);
  gemm_bf16<false, false><<<gNQ, 256, 0, stream>>>(qbuf, caoff_t, bias4, oabuf, NQ, D, 256);
  deform_v2<false><<<NQ, 128, 0, stream>>>(oabuf, ref, Vbuf, smpb);
  gemm_bf16<false, false><<<gNQ, 256, 0, stream>>>(smpb, caout_t, ca_out_b, t2, NQ, D, D);
  add_ln<true><<<NQ / 4, 256, 0, stream>>>(t2, cur, ln1_g, ln1_b, cur, curb);

  // ---- deformable cross-attn (se, boundary=True) ----
  add_vec_bf16<<<2400, 256, 0, stream>>>(cur, qpos, qbuf, n4);
  gemm_val<<<MS / 128, 512, 0, stream>>>(src, seval_t, se_val_b, Vbuf);
  gemm_bf16<false, false><<<gNQ, 256, 0, stream>>>(qbuf, seoff_t, bias4 + 256, oabuf, NQ, D, 256);
  deform_v2<true><<<NQ, 128, 0, stream>>>(oabuf, ref, Vbuf, smpb);
  gemm_bf16<false, false><<<gNQ, 256, 0, stream>>>(smpb, seout_t, se_out_b, t2, NQ, D, D);
  add_ln<true><<<NQ / 4, 256, 0, stream>>>(t2, cur, lnse_g, lnse_b, cur, curb);

  // ---- FFN ----
  gemm_bf16<true,  true ><<<gFF1, 256, 0, stream>>>(curb, ff1_t, ff1_b, ffh, NQ, D, DFFN);
  gemm_bf16<false, false><<<gNQ, 256, 0, stream>>>(ffh, ff2_t, ff2_b, t2, NQ, DFFN, D);
  add_ln<false><<<NQ / 4, 256, 0, stream>>>(t2, cur, ln3_g, ln3_b, (float*)d_out, nullptr);
}

// Round 6
// 526.192 us; speedup vs baseline: 2.6934x; 1.0133x over previous
//
#include <hip/hip_runtime.h>
#include <hip/hip_bf16.h>

namespace {

typedef unsigned short u16;
typedef unsigned int u32;

constexpr int D    = 256;
constexpr int H    = 8;
constexpr int DH   = 32;
constexpr int L    = 4;
constexpr int P    = 4;
constexpr int B    = 32;
constexpr int LQ   = 300;
constexpr int NQ   = B * LQ;      // 9600
constexpr int S    = 3840;
constexpr int MS   = B * S;       // 122880
constexpr int DFFN = 1024;

typedef __attribute__((ext_vector_type(8))) short bf16x8;
typedef __attribute__((ext_vector_type(4))) float f32x4;

__device__ inline u16 f2b(float x) {
  u32 u = __builtin_bit_cast(u32, x);
  u32 r = (u + 0x7FFFu + ((u >> 16) & 1u)) >> 16;
  return (u16)r;
}
__device__ inline void unpack2(u32 w, float& a, float& b) {
  a = __builtin_bit_cast(float, w << 16);
  b = __builtin_bit_cast(float, w & 0xffff0000u);
}

// ---------------------------------------------------------------------------
// Small-M GEMM: 64x64 tile, BK=64, 256 thr = 4 waves (2x2, 32x32 each).
// C[M,N] = A[M,K] @ Bt[N,K]^T + bias. High block count for latency hiding.
// ---------------------------------------------------------------------------
template<bool OUT_BF16, bool RELU>
__global__ __launch_bounds__(256) void gemm_sm(
    const u16* __restrict__ A, const u16* __restrict__ Bt,
    const float* __restrict__ bias, void* __restrict__ Cv,
    int M, int K, int N)
{
  constexpr int BM = 64, BN = 64, BK = 64, LDK = 72;
  __shared__ __align__(16) u16 sh[(BM + BN) * LDK];    // 18432 B
  u16* As = sh;
  u16* Bs = sh + BM * LDK;
  const int tid  = threadIdx.x;
  const int lane = tid & 63;
  const int wid  = tid >> 6;
  const int wm = wid >> 1, wn = wid & 1;
  const int m0 = blockIdx.y * BM, n0 = blockIdx.x * BN;

  f32x4 acc[2][2] = {};
  uint4 ra[2], rb[2];
  const int NT = K / BK;
  const int srow = tid >> 3, sch = (tid & 7) * 8;      // +256: rows 32..63

#pragma unroll
  for (int i = 0; i < 2; ++i) {
    const int row = srow + i * 32;
    ra[i] = *(const uint4*)(A  + (size_t)(m0 + row) * K + sch);
    rb[i] = *(const uint4*)(Bt + (size_t)(n0 + row) * K + sch);
  }

  for (int t = 0; t < NT; ++t) {
#pragma unroll
    for (int i = 0; i < 2; ++i) {
      const int row = srow + i * 32;
      *(uint4*)(&As[row * LDK + sch]) = ra[i];
      *(uint4*)(&Bs[row * LDK + sch]) = rb[i];
    }
    __syncthreads();
    if (t + 1 < NT) {
      const int k0 = (t + 1) * BK;
#pragma unroll
      for (int i = 0; i < 2; ++i) {
        const int row = srow + i * 32;
        ra[i] = *(const uint4*)(A  + (size_t)(m0 + row) * K + k0 + sch);
        rb[i] = *(const uint4*)(Bt + (size_t)(n0 + row) * K + k0 + sch);
      }
    }
#pragma unroll
    for (int kk = 0; kk < 2; ++kk) {
      const int krd = kk * 32 + (lane >> 4) * 8;
      bf16x8 af[2], bf[2];
#pragma unroll
      for (int m = 0; m < 2; ++m)
        af[m] = *(const bf16x8*)(&As[(wm * 32 + (lane & 15) + 16 * m) * LDK + krd]);
#pragma unroll
      for (int n = 0; n < 2; ++n)
        bf[n] = *(const bf16x8*)(&Bs[(wn * 32 + (lane & 15) + 16 * n) * LDK + krd]);
#pragma unroll
      for (int m = 0; m < 2; ++m)
#pragma unroll
        for (int n = 0; n < 2; ++n)
          acc[m][n] = __builtin_amdgcn_mfma_f32_16x16x32_bf16(af[m], bf[n], acc[m][n], 0, 0, 0);
    }
    __syncthreads();
  }

  const int cr = (lane >> 4) * 4;
  const int cc = lane & 15;
  if constexpr (OUT_BF16) {
    u16* stg = sh;   // 64 x 72
#pragma unroll
    for (int n = 0; n < 2; ++n) {
      const int lc = wn * 32 + n * 16 + cc;
      const float bv = bias[n0 + lc];
#pragma unroll
      for (int m = 0; m < 2; ++m) {
        const int lr0 = wm * 32 + m * 16 + cr;
#pragma unroll
        for (int r = 0; r < 4; ++r) {
          float x = acc[m][n][r] + bv;
          if (RELU) x = fmaxf(x, 0.f);
          stg[(lr0 + r) * LDK + lc] = f2b(x);
        }
      }
    }
    __syncthreads();
    u16* Cb = (u16*)Cv;
#pragma unroll
    for (int i = 0; i < 2; ++i) {
      const int c = tid + 256 * i;
      const int row = c >> 3, ch = c & 7;
      *(uint4*)(Cb + (size_t)(m0 + row) * N + n0 + ch * 8) =
          *(const uint4*)(&stg[row * LDK + ch * 8]);
    }
  } else {
#pragma unroll
    for (int n = 0; n < 2; ++n) {
      const int gc = n0 + wn * 32 + n * 16 + cc;
      const float bv = bias[gc];
#pragma unroll
      for (int m = 0; m < 2; ++m) {
        const int gr0 = m0 + wm * 32 + m * 16 + cr;
#pragma unroll
        for (int r = 0; r < 4; ++r) {
          float x = acc[m][n][r] + bv;
          if (RELU) x = fmaxf(x, 0.f);
          ((float*)Cv)[(size_t)(gr0 + r) * N + gc] = x;
        }
      }
    }
  }
}

// ---------------------------------------------------------------------------
// Fused dual value-projection: Vca/Vse[M,256] = f32 src[M,256] @ {ca,se}valW.
// BM=64, N=512 total (A read ONCE), 1024 thr = 16 waves (each 64x32 cols).
// Bt2 = [caval_t ; seval_t] contiguous (512,256) bf16; B read from L2 direct.
// A f32->bf16 in registers; LDS-staged coalesced epilogue.
// ---------------------------------------------------------------------------
__global__ __launch_bounds__(1024) void gemm_val2(
    const float* __restrict__ A, const u16* __restrict__ Bt2,
    const float* __restrict__ bias2, u16* __restrict__ Vca, u16* __restrict__ Vse)
{
  constexpr int K = 256, BM = 64, LDK = 136;          // BK=128, 2 K-tiles
  __shared__ __align__(16) u16 sh[2 * BM * LDK];      // 34816 B
  const int tid  = threadIdx.x;
  const int lane = tid & 63;
  const int w    = tid >> 6;                          // 0..15 col-block
  const int m0   = blockIdx.x * BM;

  f32x4 acc[4][2] = {};
  float4 ra0, ra1;
  const int srow = tid >> 4;                          // 0..63
  const int scol = (tid & 15) * 8;                    // 0..120
  {
    const float* ap = A + (size_t)(m0 + srow) * K + scol;
    ra0 = *(const float4*)(ap);
    ra1 = *(const float4*)(ap + 4);
  }
  const u16* bb = Bt2 + (size_t)(w * 32 + (lane & 15)) * K + (lane >> 4) * 8;

  for (int t = 0; t < 2; ++t) {
    u16* As = sh + t * BM * LDK;
    {
      uint4 pk;
      pk.x = (u32)f2b(ra0.x) | ((u32)f2b(ra0.y) << 16);
      pk.y = (u32)f2b(ra0.z) | ((u32)f2b(ra0.w) << 16);
      pk.z = (u32)f2b(ra1.x) | ((u32)f2b(ra1.y) << 16);
      pk.w = (u32)f2b(ra1.z) | ((u32)f2b(ra1.w) << 16);
      *(uint4*)(&As[srow * LDK + scol]) = pk;
    }
    __syncthreads();
    if (t == 0) {
      const float* ap = A + (size_t)(m0 + srow) * K + 128 + scol;
      ra0 = *(const float4*)(ap);
      ra1 = *(const float4*)(ap + 4);
    }
#pragma unroll
    for (int kk = 0; kk < 4; ++kk) {
      const int krd = kk * 32 + (lane >> 4) * 8;
      bf16x8 af[4], bf[2];
#pragma unroll
      for (int m = 0; m < 4; ++m)
        af[m] = *(const bf16x8*)(&As[((lane & 15) + 16 * m) * LDK + krd]);
#pragma unroll
      for (int n = 0; n < 2; ++n)
        bf[n] = *(const bf16x8*)(bb + (size_t)n * 16 * K + t * 128 + kk * 32);
#pragma unroll
      for (int m = 0; m < 4; ++m)
#pragma unroll
        for (int n = 0; n < 2; ++n)
          acc[m][n] = __builtin_amdgcn_mfma_f32_16x16x32_bf16(af[m], bf[n], acc[m][n], 0, 0, 0);
    }
  }
  __syncthreads();

  // epilogue: 2 passes of 32 rows staged in LDS (stride 520), coalesced out
  constexpr int STC = 520;
  u16* stg = sh;
  const int col = w * 32 + (lane & 15);
#pragma unroll
  for (int pass = 0; pass < 2; ++pass) {
    if (pass) __syncthreads();
#pragma unroll
    for (int n = 0; n < 2; ++n) {
      const int c = col + n * 16;
      const float bv = bias2[c];
#pragma unroll
      for (int mi = 0; mi < 2; ++mi) {
        const int m = pass * 2 + mi;
        const int rl0 = mi * 16 + (lane >> 4) * 4;
#pragma unroll
        for (int r = 0; r < 4; ++r)
          stg[(rl0 + r) * STC + c] = f2b(acc[m][n][r] + bv);
      }
    }
    __syncthreads();
#pragma unroll
    for (int i = 0; i < 2; ++i) {
      const int c = tid + 1024 * i;
      const int row = c >> 6, ch = c & 63;            // 64 chunks of 8 cols
      u16* dst = (ch < 32 ? Vca : Vse);
      *(uint4*)(dst + (size_t)(m0 + pass * 32 + row) * 256 + (ch & 31) * 8) =
          *(const uint4*)(&stg[row * STC + ch * 8]);
    }
  }
}

// ---------------------------------------------------------------------------
// Batched weight transpose+convert: W(K,N) f32 -> Wt(N,K) bf16, 32x32 tiles.
// ---------------------------------------------------------------------------
struct WSpec { const float* w; u16* wt; int K, N, blk0; };
struct WPack { WSpec s[14]; };

__global__ __launch_bounds__(256) void wt_transpose(WPack p) {
  __shared__ float tile[32][33];
  const int b = blockIdx.x;
  int i = 0;
#pragma unroll
  for (int j = 1; j < 14; ++j) if (b >= p.s[j].blk0) i = j;
  const float* w = p.s[i].w;
  u16* wt = p.s[i].wt;
  const int K = p.s[i].K, N = p.s[i].N;
  const int lb = b - p.s[i].blk0;
  const int ntN = N >> 5;
  const int tk = lb / ntN, tn = lb - tk * ntN;
  const int r = threadIdx.x >> 5, c = threadIdx.x & 31;
#pragma unroll
  for (int j = 0; j < 4; ++j)
    tile[r + j * 8][c] = w[(size_t)(tk * 32 + r + j * 8) * N + tn * 32 + c];
  __syncthreads();
#pragma unroll
  for (int j = 0; j < 4; ++j)
    wt[(size_t)(tn * 32 + r + j * 8) * K + tk * 32 + c] = f2b(tile[c][r + j * 8]);
}

__global__ __launch_bounds__(256) void cvt_bf16(
    const float* __restrict__ x, u16* __restrict__ y, int n4)
{
  int i = blockIdx.x * 256 + threadIdx.x;
  const int stride = gridDim.x * 256;
  for (; i < n4; i += stride) {
    const float4 v = ((const float4*)x)[i];
    uint2 pk;
    pk.x = (u32)f2b(v.x) | ((u32)f2b(v.y) << 16);
    pk.y = (u32)f2b(v.z) | ((u32)f2b(v.w) << 16);
    ((uint2*)y)[i] = pk;
  }
}

__global__ __launch_bounds__(256) void add_vec_bf16(
    const float* __restrict__ a, const float* __restrict__ b,
    u16* __restrict__ c, int n4)
{
  const int i = blockIdx.x * 256 + threadIdx.x;
  if (i < n4) {
    const float4 va = ((const float4*)a)[i];
    const float4 vb = ((const float4*)b)[i];
    uint2 pk;
    pk.x = (u32)f2b(va.x + vb.x) | ((u32)f2b(va.y + vb.y) << 16);
    pk.y = (u32)f2b(va.z + vb.z) | ((u32)f2b(va.w + vb.w) << 16);
    ((uint2*)c)[i] = pk;
  }
}

// build concatenated bias vectors: bias4 = [ca_off|ca_attn|se_off|se_attn],
// qkb = [sa_qb|sa_kb], valb = [ca_val_b|se_val_b]
__global__ __launch_bounds__(512) void concat_b3(
    const float* ca_off_b, const float* ca_attn_b,
    const float* se_off_b, const float* se_attn_b,
    const float* sa_qb, const float* sa_kb,
    const float* ca_val_b, const float* se_val_b,
    float* __restrict__ bias4, float* __restrict__ qkb, float* __restrict__ valb)
{
  const int t = threadIdx.x;
  bias4[t] = t < 128 ? ca_off_b[t] : t < 256 ? ca_attn_b[t - 128]
           : t < 384 ? se_off_b[t - 256] : se_attn_b[t - 384];
  qkb[t]  = t < 256 ? sa_qb[t] : sa_kb[t - 256];
  valb[t] = t < 256 ? ca_val_b[t] : se_val_b[t - 256];
}

// ---------------------------------------------------------------------------
// Self-attention: split-K softmax. qk layout (NQ,512): q cols 0-255, k 256-511.
// ---------------------------------------------------------------------------
__global__ __launch_bounds__(512) void mha_v2(
    const u16* __restrict__ qk, const u16* __restrict__ vh,
    u16* __restrict__ out)
{
  __shared__ __align__(16) float Ks[8 * 300 * 4];
  __shared__ __align__(16) float Vs[8 * 300 * 4];
  const int bh  = blockIdx.x & 255;      // b*8+h
  const int seg = blockIdx.x >> 8;       // 0..2
  const int b = bh >> 3, h = bh & 7;
  const u16* kbase = qk + (size_t)b * LQ * 512 + 256 + h * DH;
  const u16* vbase = vh + (size_t)b * LQ * D + h * DH;
  for (int e = threadIdx.x; e < 300 * 8; e += 512) {
    const int r = e >> 3, j = e & 7;
    float4 f;
    const uint2 kv = *(const uint2*)(kbase + (size_t)r * 512 + j * 4);
    unpack2(kv.x, f.x, f.y);
    unpack2(kv.y, f.z, f.w);
    *(float4*)(&Ks[(j * 300 + r) * 4]) = f;
    const uint2 vv = *(const uint2*)(vbase + (size_t)r * D + j * 4);
    unpack2(vv.x, f.x, f.y);
    unpack2(vv.y, f.z, f.w);
    *(float4*)(&Vs[(j * 300 + r) * 4]) = f;
  }
  __syncthreads();

  const int lane = threadIdx.x & 63;
  const int lq = (threadIdx.x >> 6) * 16 + (lane >> 2);   // 0..127
  const int kc = lane & 3;
  const int q = seg * 128 + lq;
  if (q >= LQ) return;

  const u16* qrow = qk + (size_t)(b * LQ + q) * 512 + h * DH;
  float qv[DH];
#pragma unroll
  for (int c4 = 0; c4 < 4; ++c4) {
    const uint4 u = *(const uint4*)(qrow + c4 * 8);
    unpack2(u.x, qv[c4 * 8 + 0], qv[c4 * 8 + 1]);
    unpack2(u.y, qv[c4 * 8 + 2], qv[c4 * 8 + 3]);
    unpack2(u.z, qv[c4 * 8 + 4], qv[c4 * 8 + 5]);
    unpack2(u.w, qv[c4 * 8 + 6], qv[c4 * 8 + 7]);
  }
#pragma unroll
  for (int d = 0; d < DH; ++d) qv[d] *= 0.17677669529663689f;  // 1/sqrt(32)

  float o[DH] = {};
  float ssum = 0.f;
  const float* kp = &Ks[kc * 75 * 4];
  const float* vp = &Vs[kc * 75 * 4];
  for (int i = 0; i < 75; ++i) {
    float s = 0.f;
#pragma unroll
    for (int j = 0; j < 8; ++j) {
      const float4 kf = *(const float4*)(kp + i * 4 + j * 1200);
      s += qv[j * 4 + 0] * kf.x + qv[j * 4 + 1] * kf.y
         + qv[j * 4 + 2] * kf.z + qv[j * 4 + 3] * kf.w;
    }
    const float p = __expf(s);
    ssum += p;
#pragma unroll
    for (int j = 0; j < 8; ++j) {
      const float4 vf = *(const float4*)(vp + i * 4 + j * 1200);
      o[j * 4 + 0] += p * vf.x; o[j * 4 + 1] += p * vf.y;
      o[j * 4 + 2] += p * vf.z; o[j * 4 + 3] += p * vf.w;
    }
  }

  ssum += __shfl_xor(ssum, 1, 64);
  ssum += __shfl_xor(ssum, 2, 64);
#pragma unroll
  for (int d = 0; d < DH; ++d) {
    o[d] += __shfl_xor(o[d], 1, 64);
    o[d] += __shfl_xor(o[d], 2, 64);
  }
  const float inv = 1.f / ssum;

  u16* orow = out + (size_t)(b * LQ + q) * D + h * DH;
#pragma unroll
  for (int c = 0; c < 4; ++c) {
    if (kc == c) {
      uint4 w;
      w.x = (u32)f2b(o[c * 8 + 0] * inv) | ((u32)f2b(o[c * 8 + 1] * inv) << 16);
      w.y = (u32)f2b(o[c * 8 + 2] * inv) | ((u32)f2b(o[c * 8 + 3] * inv) << 16);
      w.z = (u32)f2b(o[c * 8 + 4] * inv) | ((u32)f2b(o[c * 8 + 5] * inv) << 16);
      w.w = (u32)f2b(o[c * 8 + 6] * inv) | ((u32)f2b(o[c * 8 + 7] * inv) << 16);
      *(uint4*)(orow + c * 8) = w;
    }
  }
}

// ---------------------------------------------------------------------------
// Deformable sampling v2 (see round 4).
// ---------------------------------------------------------------------------
template<bool BOUNDARY>
__global__ __launch_bounds__(128) void deform_v2(
    const float* __restrict__ oa, const float* __restrict__ ref,
    const u16* __restrict__ value, u16* __restrict__ out)
{
  __shared__ __align__(16) uint4 owt[128];
  const int bq = blockIdx.x;
  const int b = bq / LQ;
  const int t = threadIdx.x;        // 0..127
  const int h = t >> 4;
  const int l = (t >> 2) & 3;
  const int p = t & 3;

  const float off   = oa[(size_t)bq * 256 + t];
  const float logit = oa[(size_t)bq * 256 + 128 + t];
  const float center = ref[(size_t)bq * 8 + l * 2 + 0];
  const float width  = ref[(size_t)bq * 8 + l * 2 + 1];

  const float e = __expf(logit);
  float ssum = e;
  ssum += __shfl_xor(ssum, 1, 64);
  ssum += __shfl_xor(ssum, 2, 64);
  ssum += __shfl_xor(ssum, 4, 64);
  ssum += __shfl_xor(ssum, 8, 64);
  const float wa = e / ssum;

  const int T  = 2048 >> l;
  const int s0 = 4096 - (4096 >> l);
  float anchor = center;
  if (BOUNDARY) anchor += (p < 2 ? -0.5f : 0.5f) * width;
  const float loc = anchor + off * width * 0.125f;
  const float x = loc * (float)T - 0.5f;
  const float x0 = floorf(x);
  const float w = x - x0;
  const int i0 = (int)x0;
  const int i1 = i0 + 1;
  const float w0 = (i0 >= 0 && i0 < T) ? wa * (1.f - w) : 0.f;
  const float w1 = (i1 >= 0 && i1 < T) ? wa * w : 0.f;
  const int i0c = min(max(i0, 0), T - 1);
  const int i1c = min(max(i1, 0), T - 1);
  uint4 pack;
  pack.x = (u32)((s0 + i0c) * (D * 2) + h * (DH * 2));
  pack.y = __builtin_bit_cast(u32, w0);
  pack.z = (u32)((s0 + i1c) * (D * 2) + h * (DH * 2));
  pack.w = __builtin_bit_cast(u32, w1);
  owt[t] = pack;
  __syncthreads();

  const int g  = t >> 4;         // group = head
  const int ln = t & 15;         // dims 2ln, 2ln+1
  const char* vb = (const char*)(value + (size_t)b * S * D) + ln * 4;
  float o0 = 0.f, o1 = 0.f;
#pragma unroll
  for (int j = 0; j < 16; ++j) {
    const uint4 ow = owt[g * 16 + j];
    const u32 v0 = *(const u32*)(vb + ow.x);
    const u32 v1 = *(const u32*)(vb + ow.z);
    const float wt0 = __builtin_bit_cast(float, ow.y);
    const float wt1 = __builtin_bit_cast(float, ow.w);
    float a, c;
    unpack2(v0, a, c); o0 += wt0 * a; o1 += wt0 * c;
    unpack2(v1, a, c); o0 += wt1 * a; o1 += wt1 * c;
  }
  const u32 res = (u32)f2b(o0) | ((u32)f2b(o1) << 16);
  *(u32*)(out + (size_t)bq * D + g * DH + ln * 2) = res;
}

// ---------------------------------------------------------------------------
// add+LN variants. add_ln: optional bf16 copy. add_ln_q: also qbuf = y+qpos.
// ---------------------------------------------------------------------------
template<bool WRITE_BF>
__global__ __launch_bounds__(256) void add_ln(
    const float* __restrict__ x, const float* __restrict__ res,
    const float* __restrict__ g, const float* __restrict__ bb,
    float* __restrict__ out, u16* __restrict__ outb)
{
  const int row = blockIdx.x * 4 + (threadIdx.x >> 6);
  const int lane = threadIdx.x & 63;
  const float* xr = x + (size_t)row * D;
  const float* rr = res + (size_t)row * D;
  float v[4];
  float s = 0.f;
#pragma unroll
  for (int i = 0; i < 4; ++i) { v[i] = xr[lane + 64 * i] + rr[lane + 64 * i]; s += v[i]; }
#pragma unroll
  for (int off = 32; off > 0; off >>= 1) s += __shfl_xor(s, off, 64);
  const float mean = s * (1.f / D);
  float vs = 0.f;
#pragma unroll
  for (int i = 0; i < 4; ++i) { const float dd = v[i] - mean; vs += dd * dd; }
#pragma unroll
  for (int off = 32; off > 0; off >>= 1) vs += __shfl_xor(vs, off, 64);
  const float rstd = rsqrtf(vs * (1.f / D) + 1e-5f);
  float* orow = out + (size_t)row * D;
#pragma unroll
  for (int i = 0; i < 4; ++i) {
    const float y = (v[i] - mean) * rstd * g[lane + 64 * i] + bb[lane + 64 * i];
    orow[lane + 64 * i] = y;
    if (WRITE_BF) outb[(size_t)row * D + lane + 64 * i] = f2b(y);
  }
}

__global__ __launch_bounds__(256) void add_ln_q(
    const float* __restrict__ x, const float* __restrict__ res,
    const float* __restrict__ g, const float* __restrict__ bb,
    const float* __restrict__ qpos,
    float* __restrict__ out, u16* __restrict__ qout)
{
  const int row = blockIdx.x * 4 + (threadIdx.x >> 6);
  const int lane = threadIdx.x & 63;
  const float* xr = x + (size_t)row * D;
  const float* rr = res + (size_t)row * D;
  float v[4];
  float s = 0.f;
#pragma unroll
  for (int i = 0; i < 4; ++i) { v[i] = xr[lane + 64 * i] + rr[lane + 64 * i]; s += v[i]; }
#pragma unroll
  for (int off = 32; off > 0; off >>= 1) s += __shfl_xor(s, off, 64);
  const float mean = s * (1.f / D);
  float vs = 0.f;
#pragma unroll
  for (int i = 0; i < 4; ++i) { const float dd = v[i] - mean; vs += dd * dd; }
#pragma unroll
  for (int off = 32; off > 0; off >>= 1) vs += __shfl_xor(vs, off, 64);
  const float rstd = rsqrtf(vs * (1.f / D) + 1e-5f);
  float* orow = out + (size_t)row * D;
#pragma unroll
  for (int i = 0; i < 4; ++i) {
    const int idx = lane + 64 * i;
    const float y = (v[i] - mean) * rstd * g[idx] + bb[idx];
    orow[idx] = y;
    qout[(size_t)row * D + idx] = f2b(y + qpos[(size_t)row * D + idx]);
  }
}

}  // namespace

extern "C" void kernel_launch(void* const* d_in, const int* in_sizes, int n_in,
                              void* d_out, int out_size, void* d_ws, size_t ws_size,
                              hipStream_t stream)
{
  const float* tgt   = (const float*)d_in[0];
  const float* qpos  = (const float*)d_in[1];
  const float* ref   = (const float*)d_in[2];
  const float* src   = (const float*)d_in[3];
  const float* sa_qw = (const float*)d_in[6];
  const float* sa_kw = (const float*)d_in[7];
  const float* sa_vw = (const float*)d_in[8];
  const float* sa_ow = (const float*)d_in[9];
  const float* ff1_w = (const float*)d_in[10];
  const float* ff2_w = (const float*)d_in[11];
  const float* sa_qb = (const float*)d_in[12];
  const float* sa_kb = (const float*)d_in[13];
  const float* sa_vb = (const float*)d_in[14];
  const float* sa_ob = (const float*)d_in[15];
  const float* ff1_b = (const float*)d_in[16];
  const float* ff2_b = (const float*)d_in[17];
  const float* ca_off_w  = (const float*)d_in[18];
  const float* ca_off_b  = (const float*)d_in[19];
  const float* ca_attn_w = (const float*)d_in[20];
  const float* ca_attn_b = (const float*)d_in[21];
  const float* ca_val_w  = (const float*)d_in[22];
  const float* ca_val_b  = (const float*)d_in[23];
  const float* ca_out_w  = (const float*)d_in[24];
  const float* ca_out_b  = (const float*)d_in[25];
  const float* se_off_w  = (const float*)d_in[26];
  const float* se_off_b  = (const float*)d_in[27];
  const float* se_attn_w = (const float*)d_in[28];
  const float* se_attn_b = (const float*)d_in[29];
  const float* se_val_w  = (const float*)d_in[30];
  const float* se_val_b  = (const float*)d_in[31];
  const float* se_out_w  = (const float*)d_in[32];
  const float* se_out_b  = (const float*)d_in[33];
  const float* ln1_g  = (const float*)d_in[34];
  const float* ln1_b  = (const float*)d_in[35];
  const float* lnse_g = (const float*)d_in[36];
  const float* lnse_b = (const float*)d_in[37];
  const float* ln2_g  = (const float*)d_in[38];
  const float* ln2_b  = (const float*)d_in[39];
  const float* ln3_g  = (const float*)d_in[40];
  const float* ln3_b  = (const float*)d_in[41];

  const size_t ND = (size_t)NQ * D;       // 2,457,600
  const size_t MD = (size_t)MS * D;       // 31,457,280

  char* base = (char*)d_ws;
  size_t off = 0;
  auto alloc = [&](size_t bytes) -> void* {
    void* p = base + off;
    off += (bytes + 255) & ~(size_t)255;
    return p;
  };
  u16*  Vca  = (u16*)alloc(MD * 2);       // also aliased as ffh after ca-deform
  u16*  Vse  = (u16*)alloc(MD * 2);
  float* t2  = (float*)alloc(ND * 4);     // also aliased as qkbuf before use
  u16*  vh   = (u16*)alloc(ND * 2);
  u16*  qbuf = (u16*)alloc(ND * 2);
  u16*  smpb = (u16*)alloc(ND * 2);
  u16*  tgtb = (u16*)alloc(ND * 2);
  u16*  curb = (u16*)alloc(ND * 2);
  float* cur = (float*)alloc(ND * 4);
  float* oabuf = (float*)alloc((size_t)NQ * 256 * 4);
  float* bias4 = (float*)alloc(512 * 4);
  float* qkb   = (float*)alloc(512 * 4);
  float* valb  = (float*)alloc(512 * 4);

  u16* qkbuf = (u16*)t2;                  // (NQ,512) bf16, dead before t2 use
  u16* ffh   = Vca;                       // (NQ,DFFN) bf16, after Vca dead

  // transposed bf16 weights; adjacency groups: [saq|sak], [caoff|caatt],
  // [seoff|seatt], [caval|seval]  (alloc sizes are 256B multiples)
  WPack pk;
  int wi = 0, blk = 0;
  auto addw = [&](const float* w, int K, int N) -> u16* {
    u16* wt = (u16*)alloc((size_t)K * N * 2);
    pk.s[wi].w = w; pk.s[wi].wt = wt; pk.s[wi].K = K; pk.s[wi].N = N; pk.s[wi].blk0 = blk;
    blk += (K / 32) * (N / 32);
    ++wi;
    return wt;
  };
  u16* saq_t = addw(sa_qw, D, D);
  u16* sak_t = addw(sa_kw, D, D);        (void)sak_t;
  u16* sav_t = addw(sa_vw, D, D);
  u16* sao_t = addw(sa_ow, D, D);
  u16* ff1_t = addw(ff1_w, D, DFFN);
  u16* ff2_t = addw(ff2_w, DFFN, D);
  u16* caoff_t = addw(ca_off_w, D, 128);
  u16* caatt_t = addw(ca_attn_w, D, 128);  (void)caatt_t;
  u16* seoff_t = addw(se_off_w, D, 128);
  u16* seatt_t = addw(se_attn_w, D, 128);  (void)seatt_t;
  u16* caval_t = addw(ca_val_w, D, D);
  u16* seval_t = addw(se_val_w, D, D);     (void)seval_t;
  u16* caout_t = addw(ca_out_w, D, D);
  u16* seout_t = addw(se_out_w, D, D);

  const int n4 = (int)(ND / 4);           // 614400

  // ---- prep ----
  concat_b3<<<1, 512, 0, stream>>>(ca_off_b, ca_attn_b, se_off_b, se_attn_b,
                                   sa_qb, sa_kb, ca_val_b, se_val_b,
                                   bias4, qkb, valb);
  wt_transpose<<<blk, 256, 0, stream>>>(pk);
  gemm_val2<<<MS / 64, 1024, 0, stream>>>(src, caval_t, valb, Vca, Vse);
  cvt_bf16<<<1200, 256, 0, stream>>>(tgt, tgtb, n4);
  add_vec_bf16<<<2400, 256, 0, stream>>>(tgt, qpos, qbuf, n4);

  // ---- self-attention ----
  gemm_sm<true,  false><<<dim3(8, 150), 256, 0, stream>>>(qbuf, saq_t, qkb, qkbuf, NQ, D, 512);
  gemm_sm<true,  false><<<dim3(4, 150), 256, 0, stream>>>(tgtb, sav_t, sa_vb, vh, NQ, D, D);
  mha_v2<<<B * H * 3, 512, 0, stream>>>(qkbuf, vh, smpb);
  gemm_sm<false, false><<<dim3(4, 150), 256, 0, stream>>>(smpb, sao_t, sa_ob, t2, NQ, D, D);
  add_ln_q<<<NQ / 4, 256, 0, stream>>>(t2, tgt, ln2_g, ln2_b, qpos, cur, qbuf);

  // ---- deformable cross-attn (ca, boundary=False) ----
  gemm_sm<false, false><<<dim3(4, 150), 256, 0, stream>>>(qbuf, caoff_t, bias4, oabuf, NQ, D, 256);
  deform_v2<false><<<NQ, 128, 0, stream>>>(oabuf, ref, Vca, smpb);
  gemm_sm<false, false><<<dim3(4, 150), 256, 0, stream>>>(smpb, caout_t, ca_out_b, t2, NQ, D, D);
  add_ln_q<<<NQ / 4, 256, 0, stream>>>(t2, cur, ln1_g, ln1_b, qpos, cur, qbuf);

  // ---- deformable cross-attn (se, boundary=True) ----
  gemm_sm<false, false><<<dim3(4, 150), 256, 0, stream>>>(qbuf, seoff_t, bias4 + 256, oabuf, NQ, D, 256);
  deform_v2<true><<<NQ, 128, 0, stream>>>(oabuf, ref, Vse, smpb);
  gemm_sm<false, false><<<dim3(4, 150), 256, 0, stream>>>(smpb, seout_t, se_out_b, t2, NQ, D, D);
  add_ln<true><<<NQ / 4, 256, 0, stream>>>(t2, cur, lnse_g, lnse_b, cur, curb);

  // ---- FFN ----
  gemm_sm<true,  true ><<<dim3(16, 150), 256, 0, stream>>>(curb, ff1_t, ff1_b, ffh, NQ, D, DFFN);
  gemm_sm<false, false><<<dim3(4, 150), 256, 0, stream>>>(ffh, ff2_t, ff2_b, t2, NQ, DFFN, D);
  add_ln<false><<<NQ / 4, 256, 0, stream>>>(t2, cur, ln3_g, ln3_b, (float*)d_out, nullptr);
}

// Round 7
// 478.617 us; speedup vs baseline: 2.9611x; 1.0994x over previous
//
#include <hip/hip_runtime.h>
#include <hip/hip_bf16.h>

namespace {

typedef unsigned short u16;
typedef unsigned int u32;

constexpr int D    = 256;
constexpr int H    = 8;
constexpr int DH   = 32;
constexpr int L    = 4;
constexpr int P    = 4;
constexpr int B    = 32;
constexpr int LQ   = 300;
constexpr int NQ   = B * LQ;      // 9600
constexpr int S    = 3840;
constexpr int MS   = B * S;       // 122880
constexpr int DFFN = 1024;

typedef __attribute__((ext_vector_type(8))) short bf16x8;
typedef __attribute__((ext_vector_type(4))) float f32x4;

__device__ inline u16 f2b(float x) {
  u32 u = __builtin_bit_cast(u32, x);
  u32 r = (u + 0x7FFFu + ((u >> 16) & 1u)) >> 16;
  return (u16)r;
}
__device__ inline u32 pk2(float a, float b) {
  return (u32)f2b(a) | ((u32)f2b(b) << 16);
}
__device__ inline void unpack2(u32 w, float& a, float& b) {
  a = __builtin_bit_cast(float, w << 16);
  b = __builtin_bit_cast(float, w & 0xffff0000u);
}

// ---------------------------------------------------------------------------
// Small-M GEMM: 64x64 tile, BK=64, 256 thr = 4 waves (2x2).
// ---------------------------------------------------------------------------
template<bool OUT_BF16, bool RELU>
__global__ __launch_bounds__(256) void gemm_sm(
    const u16* __restrict__ A, const u16* __restrict__ Bt,
    const float* __restrict__ bias, void* __restrict__ Cv,
    int M, int K, int N)
{
  constexpr int BM = 64, BN = 64, BK = 64, LDK = 72;
  __shared__ __align__(16) u16 sh[(BM + BN) * LDK];    // 18432 B
  u16* As = sh;
  u16* Bs = sh + BM * LDK;
  const int tid  = threadIdx.x;
  const int lane = tid & 63;
  const int wid  = tid >> 6;
  const int wm = wid >> 1, wn = wid & 1;
  const int m0 = blockIdx.y * BM, n0 = blockIdx.x * BN;

  f32x4 acc[2][2] = {};
  uint4 ra[2], rb[2];
  const int NT = K / BK;
  const int srow = tid >> 3, sch = (tid & 7) * 8;

#pragma unroll
  for (int i = 0; i < 2; ++i) {
    const int row = srow + i * 32;
    ra[i] = *(const uint4*)(A  + (size_t)(m0 + row) * K + sch);
    rb[i] = *(const uint4*)(Bt + (size_t)(n0 + row) * K + sch);
  }

  for (int t = 0; t < NT; ++t) {
#pragma unroll
    for (int i = 0; i < 2; ++i) {
      const int row = srow + i * 32;
      *(uint4*)(&As[row * LDK + sch]) = ra[i];
      *(uint4*)(&Bs[row * LDK + sch]) = rb[i];
    }
    __syncthreads();
    if (t + 1 < NT) {
      const int k0 = (t + 1) * BK;
#pragma unroll
      for (int i = 0; i < 2; ++i) {
        const int row = srow + i * 32;
        ra[i] = *(const uint4*)(A  + (size_t)(m0 + row) * K + k0 + sch);
        rb[i] = *(const uint4*)(Bt + (size_t)(n0 + row) * K + k0 + sch);
      }
    }
#pragma unroll
    for (int kk = 0; kk < 2; ++kk) {
      const int krd = kk * 32 + (lane >> 4) * 8;
      bf16x8 af[2], bf[2];
#pragma unroll
      for (int m = 0; m < 2; ++m)
        af[m] = *(const bf16x8*)(&As[(wm * 32 + (lane & 15) + 16 * m) * LDK + krd]);
#pragma unroll
      for (int n = 0; n < 2; ++n)
        bf[n] = *(const bf16x8*)(&Bs[(wn * 32 + (lane & 15) + 16 * n) * LDK + krd]);
#pragma unroll
      for (int m = 0; m < 2; ++m)
#pragma unroll
        for (int n = 0; n < 2; ++n)
          acc[m][n] = __builtin_amdgcn_mfma_f32_16x16x32_bf16(af[m], bf[n], acc[m][n], 0, 0, 0);
    }
    __syncthreads();
  }

  const int cr = (lane >> 4) * 4;
  const int cc = lane & 15;
  if constexpr (OUT_BF16) {
    u16* stg = sh;
#pragma unroll
    for (int n = 0; n < 2; ++n) {
      const int lc = wn * 32 + n * 16 + cc;
      const float bv = bias[n0 + lc];
#pragma unroll
      for (int m = 0; m < 2; ++m) {
        const int lr0 = wm * 32 + m * 16 + cr;
#pragma unroll
        for (int r = 0; r < 4; ++r) {
          float x = acc[m][n][r] + bv;
          if (RELU) x = fmaxf(x, 0.f);
          stg[(lr0 + r) * LDK + lc] = f2b(x);
        }
      }
    }
    __syncthreads();
    u16* Cb = (u16*)Cv;
#pragma unroll
    for (int i = 0; i < 2; ++i) {
      const int c = tid + 256 * i;
      const int row = c >> 3, ch = c & 7;
      *(uint4*)(Cb + (size_t)(m0 + row) * N + n0 + ch * 8) =
          *(const uint4*)(&stg[row * LDK + ch * 8]);
    }
  } else {
#pragma unroll
    for (int n = 0; n < 2; ++n) {
      const int gc = n0 + wn * 32 + n * 16 + cc;
      const float bv = bias[gc];
#pragma unroll
      for (int m = 0; m < 2; ++m) {
        const int gr0 = m0 + wm * 32 + m * 16 + cr;
#pragma unroll
        for (int r = 0; r < 4; ++r) {
          float x = acc[m][n][r] + bv;
          if (RELU) x = fmaxf(x, 0.f);
          ((float*)Cv)[(size_t)(gr0 + r) * N + gc] = x;
        }
      }
    }
  }
}

// ---------------------------------------------------------------------------
// Dual value-projection v3: Vca/Vse[M,256] = f32 src[M,256] @ {ca,se}valW.
// grid MS/64, 512 thr = 8 waves; wave w -> cols w*64 (of 512). BM=64, full K
// in one XOR-swizzled LDS A-tile (64x256 bf16). B streamed from L2 per kk.
// acc[4][4]/wave; dual-output coalesced LDS-staged epilogue.
// ---------------------------------------------------------------------------
__global__ __launch_bounds__(512) void gemm_val3(
    const float* __restrict__ A, const u16* __restrict__ Bt2,
    const float* __restrict__ bias2, u16* __restrict__ Vca, u16* __restrict__ Vse)
{
  __shared__ __align__(16) char shraw[66560];   // max(A 32768, stg 66560)
  char* Asw = shraw;
  const int tid  = threadIdx.x;
  const int lane = tid & 63;
  const int w    = tid >> 6;                    // 0..7
  const int m0   = blockIdx.x * 64;

  // stage A: 64 rows x 256 f32 -> bf16, swizzled (byte ^= (row&7)<<4)
#pragma unroll
  for (int i = 0; i < 4; ++i) {
    const int idx = tid + 512 * i;              // 0..2047
    const int row = idx >> 5, ch = idx & 31;
    const float* ap = A + (size_t)(m0 + row) * 256 + ch * 8;
    const float4 f0 = *(const float4*)(ap);
    const float4 f1 = *(const float4*)(ap + 4);
    uint4 pk;
    pk.x = pk2(f0.x, f0.y); pk.y = pk2(f0.z, f0.w);
    pk.z = pk2(f1.x, f1.y); pk.w = pk2(f1.z, f1.w);
    *(uint4*)(Asw + row * 512 + ((ch * 16) ^ ((row & 7) << 4))) = pk;
  }
  __syncthreads();

  f32x4 acc[4][4] = {};
  const u16* bb = Bt2 + (size_t)(w * 64 + (lane & 15)) * 256 + (lane >> 4) * 8;

#pragma unroll 2
  for (int kk = 0; kk < 8; ++kk) {
    bf16x8 af[4], bf[4];
    const int kb = kk * 64 + (lane >> 4) * 16;  // byte offset in row
#pragma unroll
    for (int m = 0; m < 4; ++m) {
      const int row = m * 16 + (lane & 15);
      af[m] = *(const bf16x8*)(Asw + row * 512 + (kb ^ ((row & 7) << 4)));
    }
#pragma unroll
    for (int n = 0; n < 4; ++n)
      bf[n] = *(const bf16x8*)(bb + n * 4096 + kk * 32);
#pragma unroll
    for (int m = 0; m < 4; ++m)
#pragma unroll
      for (int n = 0; n < 4; ++n)
        acc[m][n] = __builtin_amdgcn_mfma_f32_16x16x32_bf16(af[m], bf[n], acc[m][n], 0, 0, 0);
  }
  __syncthreads();

  // epilogue: stage 64x512 bf16 (stride 520), then coalesced dual store
  constexpr int STC = 520;
  u16* stg = (u16*)shraw;
  const int cr = (lane >> 4) * 4;
  const int cc = lane & 15;
#pragma unroll
  for (int n = 0; n < 4; ++n) {
    const int col = w * 64 + n * 16 + cc;
    const float bv = bias2[col];
#pragma unroll
    for (int m = 0; m < 4; ++m) {
      const int r0 = m * 16 + cr;
#pragma unroll
      for (int r = 0; r < 4; ++r)
        stg[(r0 + r) * STC + col] = f2b(acc[m][n][r] + bv);
    }
  }
  __syncthreads();
#pragma unroll
  for (int i = 0; i < 8; ++i) {
    const int c = tid + 512 * i;                // 0..4095
    const int row = c >> 6, ch = c & 63;
    u16* dst = (ch < 32) ? (Vca + (size_t)(m0 + row) * 256 + ch * 8)
                         : (Vse + (size_t)(m0 + row) * 256 + (ch - 32) * 8);
    *(uint4*)dst = *(const uint4*)(&stg[row * STC + ch * 8]);
  }
}

// ---------------------------------------------------------------------------
// Fused GEMM + bias + residual + LayerNorm (+ optional qpos add / bf16 out).
// BM=64, BN=256(=N), runtime K. 512 thr = 8 waves (2m x 4n). grid NQ/64.
// MODE: 0 = QOUT (fout f32 + bfout=bf16(y+qpos)), 1 = BFOUT (fout + bf16(y)),
//       2 = FONLY.
// ---------------------------------------------------------------------------
template<int MODE>
__global__ __launch_bounds__(512) void gemm_ln(
    const u16* __restrict__ A, const u16* __restrict__ Bt,
    const float* __restrict__ bias, const float* __restrict__ res,
    const float* __restrict__ g, const float* __restrict__ be,
    const float* __restrict__ qpos,
    float* __restrict__ fout, u16* __restrict__ bfout, int K)
{
  constexpr int BM = 64, BK = 64, LDK = 72;
  __shared__ __align__(16) float ftile[64 * 264];       // 67584 B (union w/ staging)
  u16* As = (u16*)ftile;
  u16* Bs = As + BM * LDK;
  const int tid  = threadIdx.x;
  const int lane = tid & 63;
  const int wid  = tid >> 6;
  const int wm = wid >> 2, wn = wid & 3;
  const int m0 = blockIdx.x * BM;

  f32x4 acc[2][4] = {};
  const int NT = K / BK;
  const int arow = tid >> 3, ach = (tid & 7) * 8;

  uint4 ra, rb[4];
  ra = *(const uint4*)(A + (size_t)(m0 + arow) * K + ach);
#pragma unroll
  for (int i = 0; i < 4; ++i)
    rb[i] = *(const uint4*)(Bt + (size_t)(arow + 64 * i) * K + ach);

  for (int t = 0; t < NT; ++t) {
    *(uint4*)(&As[arow * LDK + ach]) = ra;
#pragma unroll
    for (int i = 0; i < 4; ++i)
      *(uint4*)(&Bs[(arow + 64 * i) * LDK + ach]) = rb[i];
    __syncthreads();
    if (t + 1 < NT) {
      const int k0 = (t + 1) * BK;
      ra = *(const uint4*)(A + (size_t)(m0 + arow) * K + k0 + ach);
#pragma unroll
      for (int i = 0; i < 4; ++i)
        rb[i] = *(const uint4*)(Bt + (size_t)(arow + 64 * i) * K + k0 + ach);
    }
#pragma unroll
    for (int kk = 0; kk < 2; ++kk) {
      const int krd = kk * 32 + (lane >> 4) * 8;
      bf16x8 af[2], bf[4];
#pragma unroll
      for (int m = 0; m < 2; ++m)
        af[m] = *(const bf16x8*)(&As[(wm * 32 + m * 16 + (lane & 15)) * LDK + krd]);
#pragma unroll
      for (int n = 0; n < 4; ++n)
        bf[n] = *(const bf16x8*)(&Bs[(wn * 64 + n * 16 + (lane & 15)) * LDK + krd]);
#pragma unroll
      for (int m = 0; m < 2; ++m)
#pragma unroll
        for (int n = 0; n < 4; ++n)
          acc[m][n] = __builtin_amdgcn_mfma_f32_16x16x32_bf16(af[m], bf[n], acc[m][n], 0, 0, 0);
    }
    __syncthreads();
  }

  // acc -> ftile (f32, +bias)
  const int cr = (lane >> 4) * 4;
  const int cc = lane & 15;
#pragma unroll
  for (int n = 0; n < 4; ++n) {
    const int col = wn * 64 + n * 16 + cc;
    const float bv = bias[col];
#pragma unroll
    for (int m = 0; m < 2; ++m) {
      const int r0 = wm * 32 + m * 16 + cr;
#pragma unroll
      for (int r = 0; r < 4; ++r)
        ftile[(r0 + r) * 264 + col] = acc[m][n][r] + bv;
    }
  }
  __syncthreads();

  // LN over rows: thread -> row = tid>>3, 8-lane group per row.
  const int row = tid >> 3, s8 = tid & 7;
  const size_t grow = (size_t)(m0 + row) * 256;
  float vv[32];
  float sum = 0.f;
#pragma unroll
  for (int j = 0; j < 8; ++j) {
    const int col = s8 * 4 + j * 32;
    const float4 fv = *(const float4*)(&ftile[row * 264 + col]);
    const float4 rv = *(const float4*)(res + grow + col);
    vv[j * 4 + 0] = fv.x + rv.x; vv[j * 4 + 1] = fv.y + rv.y;
    vv[j * 4 + 2] = fv.z + rv.z; vv[j * 4 + 3] = fv.w + rv.w;
    sum += vv[j * 4 + 0] + vv[j * 4 + 1] + vv[j * 4 + 2] + vv[j * 4 + 3];
  }
  sum += __shfl_xor(sum, 1, 64);
  sum += __shfl_xor(sum, 2, 64);
  sum += __shfl_xor(sum, 4, 64);
  const float mean = sum * (1.f / 256.f);
  float sq = 0.f;
#pragma unroll
  for (int k = 0; k < 32; ++k) { const float d = vv[k] - mean; sq += d * d; }
  sq += __shfl_xor(sq, 1, 64);
  sq += __shfl_xor(sq, 2, 64);
  sq += __shfl_xor(sq, 4, 64);
  const float rstd = rsqrtf(sq * (1.f / 256.f) + 1e-5f);

#pragma unroll
  for (int j = 0; j < 8; ++j) {
    const int col = s8 * 4 + j * 32;
    const float4 gv = *(const float4*)(g + col);
    const float4 bv = *(const float4*)(be + col);
    float4 y;
    y.x = (vv[j * 4 + 0] - mean) * rstd * gv.x + bv.x;
    y.y = (vv[j * 4 + 1] - mean) * rstd * gv.y + bv.y;
    y.z = (vv[j * 4 + 2] - mean) * rstd * gv.z + bv.z;
    y.w = (vv[j * 4 + 3] - mean) * rstd * gv.w + bv.w;
    *(float4*)(fout + grow + col) = y;
    if constexpr (MODE == 0) {
      const float4 qv = *(const float4*)(qpos + grow + col);
      uint2 pk;
      pk.x = pk2(y.x + qv.x, y.y + qv.y);
      pk.y = pk2(y.z + qv.z, y.w + qv.w);
      *(uint2*)(bfout + grow + col) = pk;
    } else if constexpr (MODE == 1) {
      uint2 pk;
      pk.x = pk2(y.x, y.y);
      pk.y = pk2(y.z, y.w);
      *(uint2*)(bfout + grow + col) = pk;
    }
  }
}

// ---------------------------------------------------------------------------
// Batched weight transpose+convert: W(K,N) f32 -> Wt(N,K) bf16, 32x32 tiles.
// ---------------------------------------------------------------------------
struct WSpec { const float* w; u16* wt; int K, N, blk0; };
struct WPack { WSpec s[14]; };

__global__ __launch_bounds__(256) void wt_transpose(WPack p) {
  __shared__ float tile[32][33];
  const int b = blockIdx.x;
  int i = 0;
#pragma unroll
  for (int j = 1; j < 14; ++j) if (b >= p.s[j].blk0) i = j;
  const float* w = p.s[i].w;
  u16* wt = p.s[i].wt;
  const int K = p.s[i].K, N = p.s[i].N;
  const int lb = b - p.s[i].blk0;
  const int ntN = N >> 5;
  const int tk = lb / ntN, tn = lb - tk * ntN;
  const int r = threadIdx.x >> 5, c = threadIdx.x & 31;
#pragma unroll
  for (int j = 0; j < 4; ++j)
    tile[r + j * 8][c] = w[(size_t)(tk * 32 + r + j * 8) * N + tn * 32 + c];
  __syncthreads();
#pragma unroll
  for (int j = 0; j < 4; ++j)
    wt[(size_t)(tn * 32 + r + j * 8) * K + tk * 32 + c] = f2b(tile[c][r + j * 8]);
}

// tgtb = bf16(tgt); qbuf = bf16(tgt + qpos)
__global__ __launch_bounds__(256) void prep_tgt(
    const float* __restrict__ tgt, const float* __restrict__ qpos,
    u16* __restrict__ tgtb, u16* __restrict__ qbuf, int n4)
{
  int i = blockIdx.x * 256 + threadIdx.x;
  const int stride = gridDim.x * 256;
  for (; i < n4; i += stride) {
    const float4 t = ((const float4*)tgt)[i];
    const float4 q = ((const float4*)qpos)[i];
    uint2 a, b;
    a.x = pk2(t.x, t.y); a.y = pk2(t.z, t.w);
    b.x = pk2(t.x + q.x, t.y + q.y); b.y = pk2(t.z + q.z, t.w + q.w);
    ((uint2*)tgtb)[i] = a;
    ((uint2*)qbuf)[i] = b;
  }
}

// bias4 = [ca_off|ca_attn|se_off|se_attn], qkb = [sa_qb|sa_kb], valb = [ca|se]
__global__ __launch_bounds__(512) void concat_b3(
    const float* ca_off_b, const float* ca_attn_b,
    const float* se_off_b, const float* se_attn_b,
    const float* sa_qb, const float* sa_kb,
    const float* ca_val_b, const float* se_val_b,
    float* __restrict__ bias4, float* __restrict__ qkb, float* __restrict__ valb)
{
  const int t = threadIdx.x;
  bias4[t] = t < 128 ? ca_off_b[t] : t < 256 ? ca_attn_b[t - 128]
           : t < 384 ? se_off_b[t - 256] : se_attn_b[t - 384];
  qkb[t]  = t < 256 ? sa_qb[t] : sa_kb[t - 256];
  valb[t] = t < 256 ? ca_val_b[t] : se_val_b[t - 256];
}

// ---------------------------------------------------------------------------
// Self-attention: split-K softmax. qk layout (NQ,512): q cols 0-255, k 256-511.
// ---------------------------------------------------------------------------
__global__ __launch_bounds__(512) void mha_v2(
    const u16* __restrict__ qk, const u16* __restrict__ vh,
    u16* __restrict__ out)
{
  __shared__ __align__(16) float Ks[8 * 300 * 4];
  __shared__ __align__(16) float Vs[8 * 300 * 4];
  const int bh  = blockIdx.x & 255;
  const int seg = blockIdx.x >> 8;
  const int b = bh >> 3, h = bh & 7;
  const u16* kbase = qk + (size_t)b * LQ * 512 + 256 + h * DH;
  const u16* vbase = vh + (size_t)b * LQ * D + h * DH;
  for (int e = threadIdx.x; e < 300 * 8; e += 512) {
    const int r = e >> 3, j = e & 7;
    float4 f;
    const uint2 kv = *(const uint2*)(kbase + (size_t)r * 512 + j * 4);
    unpack2(kv.x, f.x, f.y);
    unpack2(kv.y, f.z, f.w);
    *(float4*)(&Ks[(j * 300 + r) * 4]) = f;
    const uint2 vv = *(const uint2*)(vbase + (size_t)r * D + j * 4);
    unpack2(vv.x, f.x, f.y);
    unpack2(vv.y, f.z, f.w);
    *(float4*)(&Vs[(j * 300 + r) * 4]) = f;
  }
  __syncthreads();

  const int lane = threadIdx.x & 63;
  const int lq = (threadIdx.x >> 6) * 16 + (lane >> 2);
  const int kc = lane & 3;
  const int q = seg * 128 + lq;
  if (q >= LQ) return;

  const u16* qrow = qk + (size_t)(b * LQ + q) * 512 + h * DH;
  float qv[DH];
#pragma unroll
  for (int c4 = 0; c4 < 4; ++c4) {
    const uint4 u = *(const uint4*)(qrow + c4 * 8);
    unpack2(u.x, qv[c4 * 8 + 0], qv[c4 * 8 + 1]);
    unpack2(u.y, qv[c4 * 8 + 2], qv[c4 * 8 + 3]);
    unpack2(u.z, qv[c4 * 8 + 4], qv[c4 * 8 + 5]);
    unpack2(u.w, qv[c4 * 8 + 6], qv[c4 * 8 + 7]);
  }
#pragma unroll
  for (int d = 0; d < DH; ++d) qv[d] *= 0.17677669529663689f;

  float o[DH] = {};
  float ssum = 0.f;
  const float* kp = &Ks[kc * 75 * 4];
  const float* vp = &Vs[kc * 75 * 4];
  for (int i = 0; i < 75; ++i) {
    float s = 0.f;
#pragma unroll
    for (int j = 0; j < 8; ++j) {
      const float4 kf = *(const float4*)(kp + i * 4 + j * 1200);
      s += qv[j * 4 + 0] * kf.x + qv[j * 4 + 1] * kf.y
         + qv[j * 4 + 2] * kf.z + qv[j * 4 + 3] * kf.w;
    }
    const float p = __expf(s);
    ssum += p;
#pragma unroll
    for (int j = 0; j < 8; ++j) {
      const float4 vf = *(const float4*)(vp + i * 4 + j * 1200);
      o[j * 4 + 0] += p * vf.x; o[j * 4 + 1] += p * vf.y;
      o[j * 4 + 2] += p * vf.z; o[j * 4 + 3] += p * vf.w;
    }
  }

  ssum += __shfl_xor(ssum, 1, 64);
  ssum += __shfl_xor(ssum, 2, 64);
#pragma unroll
  for (int d = 0; d < DH; ++d) {
    o[d] += __shfl_xor(o[d], 1, 64);
    o[d] += __shfl_xor(o[d], 2, 64);
  }
  const float inv = 1.f / ssum;

  u16* orow = out + (size_t)(b * LQ + q) * D + h * DH;
#pragma unroll
  for (int c = 0; c < 4; ++c) {
    if (kc == c) {
      uint4 w;
      w.x = pk2(o[c * 8 + 0] * inv, o[c * 8 + 1] * inv);
      w.y = pk2(o[c * 8 + 2] * inv, o[c * 8 + 3] * inv);
      w.z = pk2(o[c * 8 + 4] * inv, o[c * 8 + 5] * inv);
      w.w = pk2(o[c * 8 + 6] * inv, o[c * 8 + 7] * inv);
      *(uint4*)(orow + c * 8) = w;
    }
  }
}

// ---------------------------------------------------------------------------
// Deformable sampling v2.
// ---------------------------------------------------------------------------
template<bool BOUNDARY>
__global__ __launch_bounds__(128) void deform_v2(
    const float* __restrict__ oa, const float* __restrict__ ref,
    const u16* __restrict__ value, u16* __restrict__ out)
{
  __shared__ __align__(16) uint4 owt[128];
  const int bq = blockIdx.x;
  const int b = bq / LQ;
  const int t = threadIdx.x;
  const int h = t >> 4;
  const int l = (t >> 2) & 3;
  const int p = t & 3;

  const float off   = oa[(size_t)bq * 256 + t];
  const float logit = oa[(size_t)bq * 256 + 128 + t];
  const float center = ref[(size_t)bq * 8 + l * 2 + 0];
  const float width  = ref[(size_t)bq * 8 + l * 2 + 1];

  const float e = __expf(logit);
  float ssum = e;
  ssum += __shfl_xor(ssum, 1, 64);
  ssum += __shfl_xor(ssum, 2, 64);
  ssum += __shfl_xor(ssum, 4, 64);
  ssum += __shfl_xor(ssum, 8, 64);
  const float wa = e / ssum;

  const int T  = 2048 >> l;
  const int s0 = 4096 - (4096 >> l);
  float anchor = center;
  if (BOUNDARY) anchor += (p < 2 ? -0.5f : 0.5f) * width;
  const float loc = anchor + off * width * 0.125f;
  const float x = loc * (float)T - 0.5f;
  const float x0 = floorf(x);
  const float w = x - x0;
  const int i0 = (int)x0;
  const int i1 = i0 + 1;
  const float w0 = (i0 >= 0 && i0 < T) ? wa * (1.f - w) : 0.f;
  const float w1 = (i1 >= 0 && i1 < T) ? wa * w : 0.f;
  const int i0c = min(max(i0, 0), T - 1);
  const int i1c = min(max(i1, 0), T - 1);
  uint4 pack;
  pack.x = (u32)((s0 + i0c) * (D * 2) + h * (DH * 2));
  pack.y = __builtin_bit_cast(u32, w0);
  pack.z = (u32)((s0 + i1c) * (D * 2) + h * (DH * 2));
  pack.w = __builtin_bit_cast(u32, w1);
  owt[t] = pack;
  __syncthreads();

  const int g  = t >> 4;
  const int ln = t & 15;
  const char* vb = (const char*)(value + (size_t)b * S * D) + ln * 4;
  float o0 = 0.f, o1 = 0.f;
#pragma unroll
  for (int j = 0; j < 16; ++j) {
    const uint4 ow = owt[g * 16 + j];
    const u32 v0 = *(const u32*)(vb + ow.x);
    const u32 v1 = *(const u32*)(vb + ow.z);
    const float wt0 = __builtin_bit_cast(float, ow.y);
    const float wt1 = __builtin_bit_cast(float, ow.w);
    float a, c;
    unpack2(v0, a, c); o0 += wt0 * a; o1 += wt0 * c;
    unpack2(v1, a, c); o0 += wt1 * a; o1 += wt1 * c;
  }
  const u32 res = pk2(o0, o1);
  *(u32*)(out + (size_t)bq * D + g * DH + ln * 2) = res;
}

}  // namespace

extern "C" void kernel_launch(void* const* d_in, const int* in_sizes, int n_in,
                              void* d_out, int out_size, void* d_ws, size_t ws_size,
                              hipStream_t stream)
{
  const float* tgt   = (const float*)d_in[0];
  const float* qpos  = (const float*)d_in[1];
  const float* ref   = (const float*)d_in[2];
  const float* src   = (const float*)d_in[3];
  const float* sa_qw = (const float*)d_in[6];
  const float* sa_kw = (const float*)d_in[7];
  const float* sa_vw = (const float*)d_in[8];
  const float* sa_ow = (const float*)d_in[9];
  const float* ff1_w = (const float*)d_in[10];
  const float* ff2_w = (const float*)d_in[11];
  const float* sa_qb = (const float*)d_in[12];
  const float* sa_kb = (const float*)d_in[13];
  const float* sa_vb = (const float*)d_in[14];
  const float* sa_ob = (const float*)d_in[15];
  const float* ff1_b = (const float*)d_in[16];
  const float* ff2_b = (const float*)d_in[17];
  const float* ca_off_w  = (const float*)d_in[18];
  const float* ca_off_b  = (const float*)d_in[19];
  const float* ca_attn_w = (const float*)d_in[20];
  const float* ca_attn_b = (const float*)d_in[21];
  const float* ca_val_w  = (const float*)d_in[22];
  const float* ca_val_b  = (const float*)d_in[23];
  const float* ca_out_w  = (const float*)d_in[24];
  const float* ca_out_b  = (const float*)d_in[25];
  const float* se_off_w  = (const float*)d_in[26];
  const float* se_off_b  = (const float*)d_in[27];
  const float* se_attn_w = (const float*)d_in[28];
  const float* se_attn_b = (const float*)d_in[29];
  const float* se_val_w  = (const float*)d_in[30];
  const float* se_val_b  = (const float*)d_in[31];
  const float* se_out_w  = (const float*)d_in[32];
  const float* se_out_b  = (const float*)d_in[33];
  const float* ln1_g  = (const float*)d_in[34];
  const float* ln1_b  = (const float*)d_in[35];
  const float* lnse_g = (const float*)d_in[36];
  const float* lnse_b = (const float*)d_in[37];
  const float* ln2_g  = (const float*)d_in[38];
  const float* ln2_b  = (const float*)d_in[39];
  const float* ln3_g  = (const float*)d_in[40];
  const float* ln3_b  = (const float*)d_in[41];

  const size_t ND = (size_t)NQ * D;       // 2,457,600
  const size_t MD = (size_t)MS * D;       // 31,457,280

  char* base = (char*)d_ws;
  size_t off = 0;
  auto alloc = [&](size_t bytes) -> void* {
    void* p = base + off;
    off += (bytes + 255) & ~(size_t)255;
    return p;
  };
  u16*  Vca  = (u16*)alloc(MD * 2);       // aliased as ffh after ca-deform
  u16*  Vse  = (u16*)alloc(MD * 2);
  u16*  qkbuf = (u16*)alloc((size_t)NQ * 512 * 2);
  u16*  vh   = (u16*)alloc(ND * 2);
  u16*  qbuf = (u16*)alloc(ND * 2);
  u16*  smpb = (u16*)alloc(ND * 2);
  u16*  tgtb = (u16*)alloc(ND * 2);
  u16*  curb = (u16*)alloc(ND * 2);
  float* cur = (float*)alloc(ND * 4);
  float* oabuf = (float*)alloc((size_t)NQ * 256 * 4);
  float* bias4 = (float*)alloc(512 * 4);
  float* qkb   = (float*)alloc(512 * 4);
  float* valb  = (float*)alloc(512 * 4);

  u16* ffh = Vca;                          // (NQ,DFFN) bf16, after Vca dead

  // transposed bf16 weights; adjacency groups: [saq|sak], [caoff|caatt],
  // [seoff|seatt], [caval|seval]  (alloc sizes are 256B multiples)
  WPack pk;
  int wi = 0, blk = 0;
  auto addw = [&](const float* w, int K, int N) -> u16* {
    u16* wt = (u16*)alloc((size_t)K * N * 2);
    pk.s[wi].w = w; pk.s[wi].wt = wt; pk.s[wi].K = K; pk.s[wi].N = N; pk.s[wi].blk0 = blk;
    blk += (K / 32) * (N / 32);
    ++wi;
    return wt;
  };
  u16* saq_t = addw(sa_qw, D, D);
  u16* sak_t = addw(sa_kw, D, D);        (void)sak_t;
  u16* sav_t = addw(sa_vw, D, D);
  u16* sao_t = addw(sa_ow, D, D);
  u16* ff1_t = addw(ff1_w, D, DFFN);
  u16* ff2_t = addw(ff2_w, DFFN, D);
  u16* caoff_t = addw(ca_off_w, D, 128);
  u16* caatt_t = addw(ca_attn_w, D, 128);  (void)caatt_t;
  u16* seoff_t = addw(se_off_w, D, 128);
  u16* seatt_t = addw(se_attn_w, D, 128);  (void)seatt_t;
  u16* caval_t = addw(ca_val_w, D, D);
  u16* seval_t = addw(se_val_w, D, D);     (void)seval_t;
  u16* caout_t = addw(ca_out_w, D, D);
  u16* seout_t = addw(se_out_w, D, D);

  const int n4 = (int)(ND / 4);

  // ---- prep ----
  concat_b3<<<1, 512, 0, stream>>>(ca_off_b, ca_attn_b, se_off_b, se_attn_b,
                                   sa_qb, sa_kb, ca_val_b, se_val_b,
                                   bias4, qkb, valb);
  wt_transpose<<<blk, 256, 0, stream>>>(pk);
  gemm_val3<<<MS / 64, 512, 0, stream>>>(src, caval_t, valb, Vca, Vse);
  prep_tgt<<<1200, 256, 0, stream>>>(tgt, qpos, tgtb, qbuf, n4);

  // ---- self-attention ----
  gemm_sm<true,  false><<<dim3(8, 150), 256, 0, stream>>>(qbuf, saq_t, qkb, qkbuf, NQ, D, 512);
  gemm_sm<true,  false><<<dim3(4, 150), 256, 0, stream>>>(tgtb, sav_t, sa_vb, vh, NQ, D, D);
  mha_v2<<<B * H * 3, 512, 0, stream>>>(qkbuf, vh, smpb);
  gemm_ln<0><<<NQ / 64, 512, 0, stream>>>(smpb, sao_t, sa_ob, tgt, ln2_g, ln2_b, qpos, cur, qbuf, D);

  // ---- deformable cross-attn (ca, boundary=False) ----
  gemm_sm<false, false><<<dim3(4, 150), 256, 0, stream>>>(qbuf, caoff_t, bias4, oabuf, NQ, D, 256);
  deform_v2<false><<<NQ, 128, 0, stream>>>(oabuf, ref, Vca, smpb);
  gemm_ln<0><<<NQ / 64, 512, 0, stream>>>(smpb, caout_t, ca_out_b, cur, ln1_g, ln1_b, qpos, cur, qbuf, D);

  // ---- deformable cross-attn (se, boundary=True) ----
  gemm_sm<false, false><<<dim3(4, 150), 256, 0, stream>>>(qbuf, seoff_t, bias4 + 256, oabuf, NQ, D, 256);
  deform_v2<true><<<NQ, 128, 0, stream>>>(oabuf, ref, Vse, smpb);
  gemm_ln<1><<<NQ / 64, 512, 0, stream>>>(smpb, seout_t, se_out_b, cur, lnse_g, lnse_b, nullptr, cur, curb, D);

  // ---- FFN ----
  gemm_sm<true,  true ><<<dim3(16, 150), 256, 0, stream>>>(curb, ff1_t, ff1_b, ffh, NQ, D, DFFN);
  gemm_ln<2><<<NQ / 64, 512, 0, stream>>>(ffh, ff2_t, ff2_b, cur, ln3_g, ln3_b, nullptr, (float*)d_out, nullptr, DFFN);
}

// Round 8
// 474.044 us; speedup vs baseline: 2.9897x; 1.0096x over previous
//
#include <hip/hip_runtime.h>
#include <hip/hip_bf16.h>

namespace {

typedef unsigned short u16;
typedef unsigned int u32;

constexpr int D    = 256;
constexpr int H    = 8;
constexpr int DH   = 32;
constexpr int L    = 4;
constexpr int P    = 4;
constexpr int B    = 32;
constexpr int LQ   = 300;
constexpr int NQ   = B * LQ;      // 9600
constexpr int S    = 3840;
constexpr int MS   = B * S;       // 122880
constexpr int DFFN = 1024;

typedef __attribute__((ext_vector_type(8))) short bf16x8;
typedef __attribute__((ext_vector_type(4))) float f32x4;

__device__ inline u16 f2b(float x) {
  u32 u = __builtin_bit_cast(u32, x);
  u32 r = (u + 0x7FFFu + ((u >> 16) & 1u)) >> 16;
  return (u16)r;
}
__device__ inline u32 pk2(float a, float b) {
  return (u32)f2b(a) | ((u32)f2b(b) << 16);
}
__device__ inline void unpack2(u32 w, float& a, float& b) {
  a = __builtin_bit_cast(float, w << 16);
  b = __builtin_bit_cast(float, w & 0xffff0000u);
}

// ---------------------------------------------------------------------------
// Small-M GEMM: 64x64 tile, BK=64, 256 thr = 4 waves (2x2).
// ---------------------------------------------------------------------------
template<bool OUT_BF16, bool RELU>
__global__ __launch_bounds__(256) void gemm_sm(
    const u16* __restrict__ A, const u16* __restrict__ Bt,
    const float* __restrict__ bias, void* __restrict__ Cv,
    int M, int K, int N)
{
  constexpr int BM = 64, BN = 64, BK = 64, LDK = 72;
  __shared__ __align__(16) u16 sh[(BM + BN) * LDK];    // 18432 B
  u16* As = sh;
  u16* Bs = sh + BM * LDK;
  const int tid  = threadIdx.x;
  const int lane = tid & 63;
  const int wid  = tid >> 6;
  const int wm = wid >> 1, wn = wid & 1;
  const int m0 = blockIdx.y * BM, n0 = blockIdx.x * BN;

  f32x4 acc[2][2] = {};
  uint4 ra[2], rb[2];
  const int NT = K / BK;
  const int srow = tid >> 3, sch = (tid & 7) * 8;

#pragma unroll
  for (int i = 0; i < 2; ++i) {
    const int row = srow + i * 32;
    ra[i] = *(const uint4*)(A  + (size_t)(m0 + row) * K + sch);
    rb[i] = *(const uint4*)(Bt + (size_t)(n0 + row) * K + sch);
  }

  for (int t = 0; t < NT; ++t) {
#pragma unroll
    for (int i = 0; i < 2; ++i) {
      const int row = srow + i * 32;
      *(uint4*)(&As[row * LDK + sch]) = ra[i];
      *(uint4*)(&Bs[row * LDK + sch]) = rb[i];
    }
    __syncthreads();
    if (t + 1 < NT) {
      const int k0 = (t + 1) * BK;
#pragma unroll
      for (int i = 0; i < 2; ++i) {
        const int row = srow + i * 32;
        ra[i] = *(const uint4*)(A  + (size_t)(m0 + row) * K + k0 + sch);
        rb[i] = *(const uint4*)(Bt + (size_t)(n0 + row) * K + k0 + sch);
      }
    }
#pragma unroll
    for (int kk = 0; kk < 2; ++kk) {
      const int krd = kk * 32 + (lane >> 4) * 8;
      bf16x8 af[2], bf[2];
#pragma unroll
      for (int m = 0; m < 2; ++m)
        af[m] = *(const bf16x8*)(&As[(wm * 32 + (lane & 15) + 16 * m) * LDK + krd]);
#pragma unroll
      for (int n = 0; n < 2; ++n)
        bf[n] = *(const bf16x8*)(&Bs[(wn * 32 + (lane & 15) + 16 * n) * LDK + krd]);
#pragma unroll
      for (int m = 0; m < 2; ++m)
#pragma unroll
        for (int n = 0; n < 2; ++n)
          acc[m][n] = __builtin_amdgcn_mfma_f32_16x16x32_bf16(af[m], bf[n], acc[m][n], 0, 0, 0);
    }
    __syncthreads();
  }

  const int cr = (lane >> 4) * 4;
  const int cc = lane & 15;
  if constexpr (OUT_BF16) {
    u16* stg = sh;
#pragma unroll
    for (int n = 0; n < 2; ++n) {
      const int lc = wn * 32 + n * 16 + cc;
      const float bv = bias[n0 + lc];
#pragma unroll
      for (int m = 0; m < 2; ++m) {
        const int lr0 = wm * 32 + m * 16 + cr;
#pragma unroll
        for (int r = 0; r < 4; ++r) {
          float x = acc[m][n][r] + bv;
          if (RELU) x = fmaxf(x, 0.f);
          stg[(lr0 + r) * LDK + lc] = f2b(x);
        }
      }
    }
    __syncthreads();
    u16* Cb = (u16*)Cv;
#pragma unroll
    for (int i = 0; i < 2; ++i) {
      const int c = tid + 256 * i;
      const int row = c >> 3, ch = c & 7;
      *(uint4*)(Cb + (size_t)(m0 + row) * N + n0 + ch * 8) =
          *(const uint4*)(&stg[row * LDK + ch * 8]);
    }
  } else {
#pragma unroll
    for (int n = 0; n < 2; ++n) {
      const int gc = n0 + wn * 32 + n * 16 + cc;
      const float bv = bias[gc];
#pragma unroll
      for (int m = 0; m < 2; ++m) {
        const int gr0 = m0 + wm * 32 + m * 16 + cr;
#pragma unroll
        for (int r = 0; r < 4; ++r) {
          float x = acc[m][n][r] + bv;
          if (RELU) x = fmaxf(x, 0.f);
          ((float*)Cv)[(size_t)(gr0 + r) * N + gc] = x;
        }
      }
    }
  }
}

// ---------------------------------------------------------------------------
// Fused q|k + v projection: one dispatch, block role by blockIdx.x.
// x<8: C=qkbuf(N=512), A=qbuf, Bt=saqk_t. x>=8: C=vh(N=256), A=tgtb, Bt=sav_t.
// Same 64x64 tile structure as gemm_sm, K=256, bf16 out.
// ---------------------------------------------------------------------------
__global__ __launch_bounds__(256) void gemm_qkv(
    const u16* __restrict__ qbuf, const u16* __restrict__ tgtb,
    const u16* __restrict__ saqk_t, const u16* __restrict__ sav_t,
    const float* __restrict__ qkb, const float* __restrict__ vbias,
    u16* __restrict__ qkbuf, u16* __restrict__ vh)
{
  constexpr int K = 256, BK = 64, LDK = 72;
  __shared__ __align__(16) u16 sh[128 * LDK];
  u16* As = sh;
  u16* Bs = sh + 64 * LDK;
  const bool isv = blockIdx.x >= 8;
  const u16* A  = isv ? tgtb : qbuf;
  const u16* Bt = isv ? sav_t : saqk_t;
  const float* bias = isv ? vbias : qkb;
  u16* C = isv ? vh : qkbuf;
  const int N = isv ? 256 : 512;
  const int n0 = (isv ? (int)blockIdx.x - 8 : (int)blockIdx.x) * 64;
  const int m0 = blockIdx.y * 64;

  const int tid  = threadIdx.x;
  const int lane = tid & 63;
  const int wid  = tid >> 6;
  const int wm = wid >> 1, wn = wid & 1;

  f32x4 acc[2][2] = {};
  uint4 ra[2], rb[2];
  const int srow = tid >> 3, sch = (tid & 7) * 8;

#pragma unroll
  for (int i = 0; i < 2; ++i) {
    const int row = srow + i * 32;
    ra[i] = *(const uint4*)(A  + (size_t)(m0 + row) * K + sch);
    rb[i] = *(const uint4*)(Bt + (size_t)(n0 + row) * K + sch);
  }
  for (int t = 0; t < 4; ++t) {
#pragma unroll
    for (int i = 0; i < 2; ++i) {
      const int row = srow + i * 32;
      *(uint4*)(&As[row * LDK + sch]) = ra[i];
      *(uint4*)(&Bs[row * LDK + sch]) = rb[i];
    }
    __syncthreads();
    if (t + 1 < 4) {
      const int k0 = (t + 1) * BK;
#pragma unroll
      for (int i = 0; i < 2; ++i) {
        const int row = srow + i * 32;
        ra[i] = *(const uint4*)(A  + (size_t)(m0 + row) * K + k0 + sch);
        rb[i] = *(const uint4*)(Bt + (size_t)(n0 + row) * K + k0 + sch);
      }
    }
#pragma unroll
    for (int kk = 0; kk < 2; ++kk) {
      const int krd = kk * 32 + (lane >> 4) * 8;
      bf16x8 af[2], bf[2];
#pragma unroll
      for (int m = 0; m < 2; ++m)
        af[m] = *(const bf16x8*)(&As[(wm * 32 + (lane & 15) + 16 * m) * LDK + krd]);
#pragma unroll
      for (int n = 0; n < 2; ++n)
        bf[n] = *(const bf16x8*)(&Bs[(wn * 32 + (lane & 15) + 16 * n) * LDK + krd]);
#pragma unroll
      for (int m = 0; m < 2; ++m)
#pragma unroll
        for (int n = 0; n < 2; ++n)
          acc[m][n] = __builtin_amdgcn_mfma_f32_16x16x32_bf16(af[m], bf[n], acc[m][n], 0, 0, 0);
    }
    __syncthreads();
  }

  const int cr = (lane >> 4) * 4;
  const int cc = lane & 15;
  u16* stg = sh;
#pragma unroll
  for (int n = 0; n < 2; ++n) {
    const int lc = wn * 32 + n * 16 + cc;
    const float bv = bias[n0 + lc];
#pragma unroll
    for (int m = 0; m < 2; ++m) {
      const int lr0 = wm * 32 + m * 16 + cr;
#pragma unroll
      for (int r = 0; r < 4; ++r)
        stg[(lr0 + r) * LDK + lc] = f2b(acc[m][n][r] + bv);
    }
  }
  __syncthreads();
#pragma unroll
  for (int i = 0; i < 2; ++i) {
    const int c = tid + 256 * i;
    const int row = c >> 3, ch = c & 7;
    *(uint4*)(C + (size_t)(m0 + row) * N + n0 + ch * 8) =
        *(const uint4*)(&stg[row * LDK + ch * 8]);
  }
}

// ---------------------------------------------------------------------------
// Value projection v4: grid (MS/64)*2; blockIdx.x&1 selects output buffer
// (0 -> Vca, 1 -> Vse). 512 thr = 8 waves, wave = 64 rows x 32 cols
// (acc[4][2] = 32 AGPR -> ~5 waves/SIMD). A staged once in XOR-swizzled LDS,
// B software-pipelined from L2. Coalesced LDS-staged epilogue.
// ---------------------------------------------------------------------------
__global__ __launch_bounds__(512) void gemm_val4(
    const float* __restrict__ A, const u16* __restrict__ Bt2,
    const float* __restrict__ bias2, u16* __restrict__ Vca, u16* __restrict__ Vse)
{
  __shared__ __align__(16) char shraw[33792];   // max(A 32768, stg 33792)
  char* Asw = shraw;
  const int tid  = threadIdx.x;
  const int lane = tid & 63;
  const int w    = tid >> 6;                    // 0..7
  const int nh   = blockIdx.x & 1;
  const int m0   = (blockIdx.x >> 1) * 64;
  u16* dst = nh ? Vse : Vca;
  const u16* Bt = Bt2 + nh * 256 * 256;
  const float* bias = bias2 + nh * 256;

  // stage A: 64 rows x 256 f32 -> bf16, swizzled (byte ^= (row&7)<<4)
#pragma unroll
  for (int i = 0; i < 4; ++i) {
    const int idx = tid + 512 * i;              // 0..2047
    const int row = idx >> 5, ch = idx & 31;
    const float* ap = A + (size_t)(m0 + row) * 256 + ch * 8;
    const float4 f0 = *(const float4*)(ap);
    const float4 f1 = *(const float4*)(ap + 4);
    uint4 pk;
    pk.x = pk2(f0.x, f0.y); pk.y = pk2(f0.z, f0.w);
    pk.z = pk2(f1.x, f1.y); pk.w = pk2(f1.z, f1.w);
    *(uint4*)(Asw + row * 512 + ((ch * 16) ^ ((row & 7) << 4))) = pk;
  }
  __syncthreads();

  f32x4 acc[4][2] = {};
  const u16* bb = Bt + (size_t)(w * 32 + (lane & 15)) * 256 + (lane >> 4) * 8;
  bf16x8 bcur[2], bnxt[2];
#pragma unroll
  for (int n = 0; n < 2; ++n) bcur[n] = *(const bf16x8*)(bb + n * 4096);

#pragma unroll
  for (int kk = 0; kk < 8; ++kk) {
    bf16x8 af[4];
    const int kb = kk * 64 + (lane >> 4) * 16;
#pragma unroll
    for (int m = 0; m < 4; ++m) {
      const int row = m * 16 + (lane & 15);
      af[m] = *(const bf16x8*)(Asw + row * 512 + (kb ^ ((row & 7) << 4)));
    }
    if (kk < 7) {
#pragma unroll
      for (int n = 0; n < 2; ++n)
        bnxt[n] = *(const bf16x8*)(bb + n * 4096 + (kk + 1) * 32);
    }
#pragma unroll
    for (int m = 0; m < 4; ++m)
#pragma unroll
      for (int n = 0; n < 2; ++n)
        acc[m][n] = __builtin_amdgcn_mfma_f32_16x16x32_bf16(af[m], bcur[n], acc[m][n], 0, 0, 0);
#pragma unroll
    for (int n = 0; n < 2; ++n) bcur[n] = bnxt[n];
  }
  __syncthreads();

  // epilogue: stage 64x256 bf16 (stride 264), coalesced stores
  constexpr int STC = 264;
  u16* stg = (u16*)shraw;
  const int cr = (lane >> 4) * 4;
  const int cc = lane & 15;
#pragma unroll
  for (int n = 0; n < 2; ++n) {
    const int col = w * 32 + n * 16 + cc;
    const float bv = bias[col];
#pragma unroll
    for (int m = 0; m < 4; ++m) {
      const int r0 = m * 16 + cr;
#pragma unroll
      for (int r = 0; r < 4; ++r)
        stg[(r0 + r) * STC + col] = f2b(acc[m][n][r] + bv);
    }
  }
  __syncthreads();
#pragma unroll
  for (int i = 0; i < 4; ++i) {
    const int c = tid + 512 * i;                // 0..2047
    const int row = c >> 5, ch = c & 31;
    *(uint4*)(dst + (size_t)(m0 + row) * 256 + ch * 8) =
        *(const uint4*)(&stg[row * STC + ch * 8]);
  }
}

// ---------------------------------------------------------------------------
// Fused GEMM + bias + residual + LayerNorm, 1024 thr = 16 waves (4m x 4n).
// BM=64, BN=256(=N), runtime K. MODE: 0 = fout+bf16(y+qpos), 1 = fout+bf16(y),
// 2 = fout only.
// ---------------------------------------------------------------------------
template<int MODE>
__global__ __launch_bounds__(1024) void gemm_ln(
    const u16* __restrict__ A, const u16* __restrict__ Bt,
    const float* __restrict__ bias, const float* __restrict__ res,
    const float* __restrict__ g, const float* __restrict__ be,
    const float* __restrict__ qpos,
    float* __restrict__ fout, u16* __restrict__ bfout, int K)
{
  constexpr int BK = 64, LDK = 72;
  __shared__ __align__(16) float ftile[64 * 264];       // 67584 B (union)
  u16* As = (u16*)ftile;
  u16* Bs = As + 64 * LDK;
  const int tid  = threadIdx.x;
  const int lane = tid & 63;
  const int wid  = tid >> 6;                    // 0..15
  const int wm = wid >> 2, wn = wid & 3;
  const int m0 = blockIdx.x * 64;

  f32x4 acc[4] = {};
  const int NT = K / BK;
  const bool am = tid < 512;
  const int arow = tid >> 3, ach = (tid & 7) * 8;   // A: tid<512

  uint4 ra = {};
  uint4 rb[2];
  if (am) ra = *(const uint4*)(A + (size_t)(m0 + arow) * K + ach);
#pragma unroll
  for (int i = 0; i < 2; ++i) {
    const int idx = tid + 1024 * i;
    const int brow = idx >> 3, bch = (idx & 7) * 8;
    rb[i] = *(const uint4*)(Bt + (size_t)brow * K + bch);
  }

  for (int t = 0; t < NT; ++t) {
    if (am) *(uint4*)(&As[arow * LDK + ach]) = ra;
#pragma unroll
    for (int i = 0; i < 2; ++i) {
      const int idx = tid + 1024 * i;
      const int brow = idx >> 3, bch = (idx & 7) * 8;
      *(uint4*)(&Bs[brow * LDK + bch]) = rb[i];
    }
    __syncthreads();
    if (t + 1 < NT) {
      const int k0 = (t + 1) * BK;
      if (am) ra = *(const uint4*)(A + (size_t)(m0 + arow) * K + k0 + ach);
#pragma unroll
      for (int i = 0; i < 2; ++i) {
        const int idx = tid + 1024 * i;
        const int brow = idx >> 3, bch = (idx & 7) * 8;
        rb[i] = *(const uint4*)(Bt + (size_t)brow * K + k0 + bch);
      }
    }
#pragma unroll
    for (int kk = 0; kk < 2; ++kk) {
      const int krd = kk * 32 + (lane >> 4) * 8;
      bf16x8 af, bf[4];
      af = *(const bf16x8*)(&As[(wm * 16 + (lane & 15)) * LDK + krd]);
#pragma unroll
      for (int n = 0; n < 4; ++n)
        bf[n] = *(const bf16x8*)(&Bs[(wn * 64 + n * 16 + (lane & 15)) * LDK + krd]);
#pragma unroll
      for (int n = 0; n < 4; ++n)
        acc[n] = __builtin_amdgcn_mfma_f32_16x16x32_bf16(af, bf[n], acc[n], 0, 0, 0);
    }
    __syncthreads();
  }

  // acc -> ftile (f32, +bias)
  const int cr = (lane >> 4) * 4;
  const int cc = lane & 15;
#pragma unroll
  for (int n = 0; n < 4; ++n) {
    const int col = wn * 64 + n * 16 + cc;
    const float bv = bias[col];
#pragma unroll
    for (int r = 0; r < 4; ++r)
      ftile[(wm * 16 + cr + r) * 264 + col] = acc[n][r] + bv;
  }
  __syncthreads();

  // LN: 16 threads per row, 16 cols each.
  const int row = tid >> 4, s16 = tid & 15;
  const size_t grow = (size_t)(m0 + row) * 256;
  float vv[16];
  float sum = 0.f;
#pragma unroll
  for (int j = 0; j < 4; ++j) {
    const int col = s16 * 4 + j * 64;
    const float4 fv = *(const float4*)(&ftile[row * 264 + col]);
    const float4 rv = *(const float4*)(res + grow + col);
    vv[j * 4 + 0] = fv.x + rv.x; vv[j * 4 + 1] = fv.y + rv.y;
    vv[j * 4 + 2] = fv.z + rv.z; vv[j * 4 + 3] = fv.w + rv.w;
    sum += vv[j * 4 + 0] + vv[j * 4 + 1] + vv[j * 4 + 2] + vv[j * 4 + 3];
  }
  sum += __shfl_xor(sum, 1, 64);
  sum += __shfl_xor(sum, 2, 64);
  sum += __shfl_xor(sum, 4, 64);
  sum += __shfl_xor(sum, 8, 64);
  const float mean = sum * (1.f / 256.f);
  float sq = 0.f;
#pragma unroll
  for (int k = 0; k < 16; ++k) { const float d = vv[k] - mean; sq += d * d; }
  sq += __shfl_xor(sq, 1, 64);
  sq += __shfl_xor(sq, 2, 64);
  sq += __shfl_xor(sq, 4, 64);
  sq += __shfl_xor(sq, 8, 64);
  const float rstd = rsqrtf(sq * (1.f / 256.f) + 1e-5f);

#pragma unroll
  for (int j = 0; j < 4; ++j) {
    const int col = s16 * 4 + j * 64;
    const float4 gv = *(const float4*)(g + col);
    const float4 bv = *(const float4*)(be + col);
    float4 y;
    y.x = (vv[j * 4 + 0] - mean) * rstd * gv.x + bv.x;
    y.y = (vv[j * 4 + 1] - mean) * rstd * gv.y + bv.y;
    y.z = (vv[j * 4 + 2] - mean) * rstd * gv.z + bv.z;
    y.w = (vv[j * 4 + 3] - mean) * rstd * gv.w + bv.w;
    *(float4*)(fout + grow + col) = y;
    if constexpr (MODE == 0) {
      const float4 qv = *(const float4*)(qpos + grow + col);
      uint2 pk;
      pk.x = pk2(y.x + qv.x, y.y + qv.y);
      pk.y = pk2(y.z + qv.z, y.w + qv.w);
      *(uint2*)(bfout + grow + col) = pk;
    } else if constexpr (MODE == 1) {
      uint2 pk;
      pk.x = pk2(y.x, y.y);
      pk.y = pk2(y.z, y.w);
      *(uint2*)(bfout + grow + col) = pk;
    }
  }
}

// ---------------------------------------------------------------------------
// prep_all: blocks [0,nwt) = weight transpose; nwt = bias concat;
// (nwt, nwt+2400] = tgt/qpos bf16 prep. 256 threads.
// ---------------------------------------------------------------------------
struct WSpec { const float* w; u16* wt; int K, N, blk0; };
struct WPack { WSpec s[14]; };

struct PrepArgs {
  const float *ca_off_b, *ca_attn_b, *se_off_b, *se_attn_b;
  const float *sa_qb, *sa_kb, *ca_val_b, *se_val_b;
  float *bias4, *qkb, *valb;
  const float *tgt, *qpos;
  u16 *tgtb, *qbuf;
  int n4, nwt;
};

__global__ __launch_bounds__(256) void prep_all(WPack p, PrepArgs a) {
  __shared__ float tile[32][33];
  const int b = blockIdx.x;
  if (b < a.nwt) {
    int i = 0;
#pragma unroll
    for (int j = 1; j < 14; ++j) if (b >= p.s[j].blk0) i = j;
    const float* w = p.s[i].w;
    u16* wt = p.s[i].wt;
    const int K = p.s[i].K, N = p.s[i].N;
    const int lb = b - p.s[i].blk0;
    const int ntN = N >> 5;
    const int tk = lb / ntN, tn = lb - tk * ntN;
    const int r = threadIdx.x >> 5, c = threadIdx.x & 31;
#pragma unroll
    for (int j = 0; j < 4; ++j)
      tile[r + j * 8][c] = w[(size_t)(tk * 32 + r + j * 8) * N + tn * 32 + c];
    __syncthreads();
#pragma unroll
    for (int j = 0; j < 4; ++j)
      wt[(size_t)(tn * 32 + r + j * 8) * K + tk * 32 + c] = f2b(tile[c][r + j * 8]);
  } else if (b == a.nwt) {
#pragma unroll
    for (int u = 0; u < 2; ++u) {
      const int t = threadIdx.x + 256 * u;
      a.bias4[t] = t < 128 ? a.ca_off_b[t] : t < 256 ? a.ca_attn_b[t - 128]
                 : t < 384 ? a.se_off_b[t - 256] : a.se_attn_b[t - 384];
      a.qkb[t]  = t < 256 ? a.sa_qb[t] : a.sa_kb[t - 256];
      a.valb[t] = t < 256 ? a.ca_val_b[t] : a.se_val_b[t - 256];
    }
  } else {
    const int i = (b - a.nwt - 1) * 256 + threadIdx.x;
    if (i < a.n4) {
      const float4 t = ((const float4*)a.tgt)[i];
      const float4 q = ((const float4*)a.qpos)[i];
      uint2 x, y;
      x.x = pk2(t.x, t.y); x.y = pk2(t.z, t.w);
      y.x = pk2(t.x + q.x, t.y + q.y); y.y = pk2(t.z + q.z, t.w + q.w);
      ((uint2*)a.tgtb)[i] = x;
      ((uint2*)a.qbuf)[i] = y;
    }
  }
}

// ---------------------------------------------------------------------------
// Self-attention: split-K softmax. qk layout (NQ,512): q cols 0-255, k 256-511.
// ---------------------------------------------------------------------------
__global__ __launch_bounds__(512) void mha_v2(
    const u16* __restrict__ qk, const u16* __restrict__ vh,
    u16* __restrict__ out)
{
  __shared__ __align__(16) float Ks[8 * 300 * 4];
  __shared__ __align__(16) float Vs[8 * 300 * 4];
  const int bh  = blockIdx.x & 255;
  const int seg = blockIdx.x >> 8;
  const int b = bh >> 3, h = bh & 7;
  const u16* kbase = qk + (size_t)b * LQ * 512 + 256 + h * DH;
  const u16* vbase = vh + (size_t)b * LQ * D + h * DH;
  for (int e = threadIdx.x; e < 300 * 8; e += 512) {
    const int r = e >> 3, j = e & 7;
    float4 f;
    const uint2 kv = *(const uint2*)(kbase + (size_t)r * 512 + j * 4);
    unpack2(kv.x, f.x, f.y);
    unpack2(kv.y, f.z, f.w);
    *(float4*)(&Ks[(j * 300 + r) * 4]) = f;
    const uint2 vv = *(const uint2*)(vbase + (size_t)r * D + j * 4);
    unpack2(vv.x, f.x, f.y);
    unpack2(vv.y, f.z, f.w);
    *(float4*)(&Vs[(j * 300 + r) * 4]) = f;
  }
  __syncthreads();

  const int lane = threadIdx.x & 63;
  const int lq = (threadIdx.x >> 6) * 16 + (lane >> 2);
  const int kc = lane & 3;
  const int q = seg * 128 + lq;
  if (q >= LQ) return;

  const u16* qrow = qk + (size_t)(b * LQ + q) * 512 + h * DH;
  float qv[DH];
#pragma unroll
  for (int c4 = 0; c4 < 4; ++c4) {
    const uint4 u = *(const uint4*)(qrow + c4 * 8);
    unpack2(u.x, qv[c4 * 8 + 0], qv[c4 * 8 + 1]);
    unpack2(u.y, qv[c4 * 8 + 2], qv[c4 * 8 + 3]);
    unpack2(u.z, qv[c4 * 8 + 4], qv[c4 * 8 + 5]);
    unpack2(u.w, qv[c4 * 8 + 6], qv[c4 * 8 + 7]);
  }
#pragma unroll
  for (int d = 0; d < DH; ++d) qv[d] *= 0.17677669529663689f;

  float o[DH] = {};
  float ssum = 0.f;
  const float* kp = &Ks[kc * 75 * 4];
  const float* vp = &Vs[kc * 75 * 4];
  for (int i = 0; i < 75; ++i) {
    float s = 0.f;
#pragma unroll
    for (int j = 0; j < 8; ++j) {
      const float4 kf = *(const float4*)(kp + i * 4 + j * 1200);
      s += qv[j * 4 + 0] * kf.x + qv[j * 4 + 1] * kf.y
         + qv[j * 4 + 2] * kf.z + qv[j * 4 + 3] * kf.w;
    }
    const float p = __expf(s);
    ssum += p;
#pragma unroll
    for (int j = 0; j < 8; ++j) {
      const float4 vf = *(const float4*)(vp + i * 4 + j * 1200);
      o[j * 4 + 0] += p * vf.x; o[j * 4 + 1] += p * vf.y;
      o[j * 4 + 2] += p * vf.z; o[j * 4 + 3] += p * vf.w;
    }
  }

  ssum += __shfl_xor(ssum, 1, 64);
  ssum += __shfl_xor(ssum, 2, 64);
#pragma unroll
  for (int d = 0; d < DH; ++d) {
    o[d] += __shfl_xor(o[d], 1, 64);
    o[d] += __shfl_xor(o[d], 2, 64);
  }
  const float inv = 1.f / ssum;

  u16* orow = out + (size_t)(b * LQ + q) * D + h * DH;
#pragma unroll
  for (int c = 0; c < 4; ++c) {
    if (kc == c) {
      uint4 w;
      w.x = pk2(o[c * 8 + 0] * inv, o[c * 8 + 1] * inv);
      w.y = pk2(o[c * 8 + 2] * inv, o[c * 8 + 3] * inv);
      w.z = pk2(o[c * 8 + 4] * inv, o[c * 8 + 5] * inv);
      w.w = pk2(o[c * 8 + 6] * inv, o[c * 8 + 7] * inv);
      *(uint4*)(orow + c * 8) = w;
    }
  }
}

// ---------------------------------------------------------------------------
// Deformable sampling: 512 thr = 4 query-units of 128 threads each.
// ---------------------------------------------------------------------------
template<bool BOUNDARY>
__global__ __launch_bounds__(512) void deform_v2(
    const float* __restrict__ oa, const float* __restrict__ ref,
    const u16* __restrict__ value, u16* __restrict__ out)
{
  __shared__ __align__(16) uint4 owt[4][128];
  const int unit = threadIdx.x >> 7;
  const int bq = blockIdx.x * 4 + unit;
  const int b = bq / LQ;
  const int t = threadIdx.x & 127;
  const int h = t >> 4;
  const int l = (t >> 2) & 3;
  const int p = t & 3;

  const float off   = oa[(size_t)bq * 256 + t];
  const float logit = oa[(size_t)bq * 256 + 128 + t];
  const float center = ref[(size_t)bq * 8 + l * 2 + 0];
  const float width  = ref[(size_t)bq * 8 + l * 2 + 1];

  const float e = __expf(logit);
  float ssum = e;
  ssum += __shfl_xor(ssum, 1, 64);
  ssum += __shfl_xor(ssum, 2, 64);
  ssum += __shfl_xor(ssum, 4, 64);
  ssum += __shfl_xor(ssum, 8, 64);
  const float wa = e / ssum;

  const int T  = 2048 >> l;
  const int s0 = 4096 - (4096 >> l);
  float anchor = center;
  if (BOUNDARY) anchor += (p < 2 ? -0.5f : 0.5f) * width;
  const float loc = anchor + off * width * 0.125f;
  const float x = loc * (float)T - 0.5f;
  const float x0 = floorf(x);
  const float w = x - x0;
  const int i0 = (int)x0;
  const int i1 = i0 + 1;
  const float w0 = (i0 >= 0 && i0 < T) ? wa * (1.f - w) : 0.f;
  const float w1 = (i1 >= 0 && i1 < T) ? wa * w : 0.f;
  const int i0c = min(max(i0, 0), T - 1);
  const int i1c = min(max(i1, 0), T - 1);
  uint4 pack;
  pack.x = (u32)((s0 + i0c) * (D * 2) + h * (DH * 2));
  pack.y = __builtin_bit_cast(u32, w0);
  pack.z = (u32)((s0 + i1c) * (D * 2) + h * (DH * 2));
  pack.w = __builtin_bit_cast(u32, w1);
  owt[unit][t] = pack;
  __syncthreads();

  const int g  = t >> 4;
  const int ln = t & 15;
  const char* vb = (const char*)(value + (size_t)b * S * D) + ln * 4;
  float o0 = 0.f, o1 = 0.f;
#pragma unroll
  for (int j = 0; j < 16; ++j) {
    const uint4 ow = owt[unit][g * 16 + j];
    const u32 v0 = *(const u32*)(vb + ow.x);
    const u32 v1 = *(const u32*)(vb + ow.z);
    const float wt0 = __builtin_bit_cast(float, ow.y);
    const float wt1 = __builtin_bit_cast(float, ow.w);
    float a, c;
    unpack2(v0, a, c); o0 += wt0 * a; o1 += wt0 * c;
    unpack2(v1, a, c); o0 += wt1 * a; o1 += wt1 * c;
  }
  const u32 res = pk2(o0, o1);
  *(u32*)(out + (size_t)bq * D + g * DH + ln * 2) = res;
}

}  // namespace

extern "C" void kernel_launch(void* const* d_in, const int* in_sizes, int n_in,
                              void* d_out, int out_size, void* d_ws, size_t ws_size,
                              hipStream_t stream)
{
  const float* tgt   = (const float*)d_in[0];
  const float* qpos  = (const float*)d_in[1];
  const float* ref   = (const float*)d_in[2];
  const float* src   = (const float*)d_in[3];
  const float* sa_qw = (const float*)d_in[6];
  const float* sa_kw = (const float*)d_in[7];
  const float* sa_vw = (const float*)d_in[8];
  const float* sa_ow = (const float*)d_in[9];
  const float* ff1_w = (const float*)d_in[10];
  const float* ff2_w = (const float*)d_in[11];
  const float* sa_qb = (const float*)d_in[12];
  const float* sa_kb = (const float*)d_in[13];
  const float* sa_vb = (const float*)d_in[14];
  const float* sa_ob = (const float*)d_in[15];
  const float* ff1_b = (const float*)d_in[16];
  const float* ff2_b = (const float*)d_in[17];
  const float* ca_off_w  = (const float*)d_in[18];
  const float* ca_off_b  = (const float*)d_in[19];
  const float* ca_attn_w = (const float*)d_in[20];
  const float* ca_attn_b = (const float*)d_in[21];
  const float* ca_val_w  = (const float*)d_in[22];
  const float* ca_val_b  = (const float*)d_in[23];
  const float* ca_out_w  = (const float*)d_in[24];
  const float* ca_out_b  = (const float*)d_in[25];
  const float* se_off_w  = (const float*)d_in[26];
  const float* se_off_b  = (const float*)d_in[27];
  const float* se_attn_w = (const float*)d_in[28];
  const float* se_attn_b = (const float*)d_in[29];
  const float* se_val_w  = (const float*)d_in[30];
  const float* se_val_b  = (const float*)d_in[31];
  const float* se_out_w  = (const float*)d_in[32];
  const float* se_out_b  = (const float*)d_in[33];
  const float* ln1_g  = (const float*)d_in[34];
  const float* ln1_b  = (const float*)d_in[35];
  const float* lnse_g = (const float*)d_in[36];
  const float* lnse_b = (const float*)d_in[37];
  const float* ln2_g  = (const float*)d_in[38];
  const float* ln2_b  = (const float*)d_in[39];
  const float* ln3_g  = (const float*)d_in[40];
  const float* ln3_b  = (const float*)d_in[41];

  const size_t ND = (size_t)NQ * D;       // 2,457,600
  const size_t MD = (size_t)MS * D;       // 31,457,280

  char* base = (char*)d_ws;
  size_t off = 0;
  auto alloc = [&](size_t bytes) -> void* {
    void* p = base + off;
    off += (bytes + 255) & ~(size_t)255;
    return p;
  };
  u16*  Vca  = (u16*)alloc(MD * 2);       // aliased as ffh after ca-deform
  u16*  Vse  = (u16*)alloc(MD * 2);
  u16*  qkbuf = (u16*)alloc((size_t)NQ * 512 * 2);
  u16*  vh   = (u16*)alloc(ND * 2);
  u16*  qbuf = (u16*)alloc(ND * 2);
  u16*  smpb = (u16*)alloc(ND * 2);
  u16*  tgtb = (u16*)alloc(ND * 2);
  u16*  curb = (u16*)alloc(ND * 2);
  float* cur = (float*)alloc(ND * 4);
  float* oabuf = (float*)alloc((size_t)NQ * 256 * 4);
  float* bias4 = (float*)alloc(512 * 4);
  float* qkb   = (float*)alloc(512 * 4);
  float* valb  = (float*)alloc(512 * 4);

  u16* ffh = Vca;                          // (NQ,DFFN) bf16, after Vca dead

  WPack pk;
  int wi = 0, blk = 0;
  auto addw = [&](const float* w, int K, int N) -> u16* {
    u16* wt = (u16*)alloc((size_t)K * N * 2);
    pk.s[wi].w = w; pk.s[wi].wt = wt; pk.s[wi].K = K; pk.s[wi].N = N; pk.s[wi].blk0 = blk;
    blk += (K / 32) * (N / 32);
    ++wi;
    return wt;
  };
  u16* saq_t = addw(sa_qw, D, D);
  u16* sak_t = addw(sa_kw, D, D);        (void)sak_t;
  u16* sav_t = addw(sa_vw, D, D);
  u16* sao_t = addw(sa_ow, D, D);
  u16* ff1_t = addw(ff1_w, D, DFFN);
  u16* ff2_t = addw(ff2_w, DFFN, D);
  u16* caoff_t = addw(ca_off_w, D, 128);
  u16* caatt_t = addw(ca_attn_w, D, 128);  (void)caatt_t;
  u16* seoff_t = addw(se_off_w, D, 128);
  u16* seatt_t = addw(se_attn_w, D, 128);  (void)seatt_t;
  u16* caval_t = addw(ca_val_w, D, D);
  u16* seval_t = addw(se_val_w, D, D);     (void)seval_t;
  u16* caout_t = addw(ca_out_w, D, D);
  u16* seout_t = addw(se_out_w, D, D);

  const int n4 = (int)(ND / 4);            // 614400

  // ---- prep (weights + biases + tgt/qpos) in ONE dispatch ----
  PrepArgs pa;
  pa.ca_off_b = ca_off_b; pa.ca_attn_b = ca_attn_b;
  pa.se_off_b = se_off_b; pa.se_attn_b = se_attn_b;
  pa.sa_qb = sa_qb; pa.sa_kb = sa_kb; pa.ca_val_b = ca_val_b; pa.se_val_b = se_val_b;
  pa.bias4 = bias4; pa.qkb = qkb; pa.valb = valb;
  pa.tgt = tgt; pa.qpos = qpos; pa.tgtb = tgtb; pa.qbuf = qbuf;
  pa.n4 = n4; pa.nwt = blk;
  prep_all<<<blk + 1 + 2400, 256, 0, stream>>>(pk, pa);

  gemm_val4<<<(MS / 64) * 2, 512, 0, stream>>>(src, caval_t, valb, Vca, Vse);

  // ---- self-attention ----
  gemm_qkv<<<dim3(12, 150), 256, 0, stream>>>(qbuf, tgtb, saq_t, sav_t, qkb, sa_vb, qkbuf, vh);
  mha_v2<<<B * H * 3, 512, 0, stream>>>(qkbuf, vh, smpb);
  gemm_ln<0><<<NQ / 64, 1024, 0, stream>>>(smpb, sao_t, sa_ob, tgt, ln2_g, ln2_b, qpos, cur, qbuf, D);

  // ---- deformable cross-attn (ca, boundary=False) ----
  gemm_sm<false, false><<<dim3(4, 150), 256, 0, stream>>>(qbuf, caoff_t, bias4, oabuf, NQ, D, 256);
  deform_v2<false><<<NQ / 4, 512, 0, stream>>>(oabuf, ref, Vca, smpb);
  gemm_ln<0><<<NQ / 64, 1024, 0, stream>>>(smpb, caout_t, ca_out_b, cur, ln1_g, ln1_b, qpos, cur, qbuf, D);

  // ---- deformable cross-attn (se, boundary=True) ----
  gemm_sm<false, false><<<dim3(4, 150), 256, 0, stream>>>(qbuf, seoff_t, bias4 + 256, oabuf, NQ, D, 256);
  deform_v2<true><<<NQ / 4, 512, 0, stream>>>(oabuf, ref, Vse, smpb);
  gemm_ln<1><<<NQ / 64, 1024, 0, stream>>>(smpb, seout_t, se_out_b, cur, lnse_g, lnse_b, nullptr, cur, curb, D);

  // ---- FFN ----
  gemm_sm<true,  true ><<<dim3(16, 150), 256, 0, stream>>>(curb, ff1_t, ff1_b, ffh, NQ, D, DFFN);
  gemm_ln<2><<<NQ / 64, 1024, 0, stream>>>(ffh, ff2_t, ff2_b, cur, ln3_g, ln3_b, nullptr, (float*)d_out, nullptr, DFFN);
}